// Round 1
// baseline (3914.724 us; speedup 1.0000x reference)
//
#include <hip/hip_runtime.h>
#include <cstddef>

#define DEVI __device__ __forceinline__

typedef __attribute__((ext_vector_type(8))) __bf16 bf16x8;
typedef __attribute__((ext_vector_type(8))) unsigned short us8;
typedef __attribute__((ext_vector_type(4))) unsigned short us4;
typedef __attribute__((ext_vector_type(4))) float f32x4;

constexpr int B0_ = 1, T_ = 8, N_ = 1024, M_ = 4096, D_ = 256;
constexpr int BT_ = 8, NW_ = 128, WQ_ = 32, HK_ = 128, SIDE_ = 48;
constexpr int R_ = BT_ * M_;          // 32768 rows
constexpr size_t Fq = 8388608;        // R_*256 floats

DEVI unsigned short f2b(float f) {
  unsigned u = __float_as_uint(f);
  u = (u + 0x7FFFu + ((u >> 16) & 1u)) >> 16;
  return (unsigned short)u;
}
DEVI float b2f(unsigned short s) { return __uint_as_float(((unsigned)s) << 16); }
DEVI float sigm(float x) { return 1.0f / (1.0f + __expf(-x)); }
DEVI bf16x8 ld_bf8(const unsigned short* p) {
  return __builtin_bit_cast(bf16x8, *(const us8*)p);
}
DEVI bf16x8 pack_f8(float4 v0, float4 v1) {
  us8 t;
  t[0] = f2b(v0.x); t[1] = f2b(v0.y); t[2] = f2b(v0.z); t[3] = f2b(v0.w);
  t[4] = f2b(v1.x); t[5] = f2b(v1.y); t[6] = f2b(v1.z); t[7] = f2b(v1.w);
  return __builtin_bit_cast(bf16x8, t);
}
DEVI void mfma_bf16(f32x4& c, bf16x8 a, bf16x8 b) {
  c = __builtin_amdgcn_mfma_f32_16x16x32_bf16(a, b, c, 0, 0, 0);
}

// ---------------- weight transpose-convert (fp32 [K][N] -> bf16 Wt[N][K]) ----
struct ConvArgs {
  const float* src[64];
  int doff[64];
  int Kd[64];
  int Nd[64];
  int n;
};

__global__ __launch_bounds__(256) void conv_k(ConvArgs ca, unsigned short* __restrict__ wbf) {
  int e = blockIdx.x;
  int K = ca.Kd[e], N = ca.Nd[e];
  int nx = N >> 6, nk = K >> 6;
  int t = blockIdx.y;
  if (t >= nx * nk) return;
  int tx = t % nx, tk = t / nx;
  const float* s = ca.src[e];
  unsigned short* d = wbf + ca.doff[e];
  int n = tx * 64 + (threadIdx.x & 63);
  int k0 = tk * 64 + (threadIdx.x >> 6) * 16;
  for (int r = 0; r < 16; r++) {
    int k = k0 + r;
    d[(size_t)n * K + k] = f2b(s[(size_t)k * N + n]);
  }
}

// ---------------- bias concat prep ----------------
__global__ __launch_bounds__(256) void bias_prep_k(
    const float* __restrict__ bq, const float* __restrict__ sb1,
    const float* __restrict__ sb2, const float* __restrict__ ogb,
    const float* __restrict__ trb, float* __restrict__ bias) {
  int t = threadIdx.x;
  for (int i = t; i < 1024 + 3 * 2560; i += 256) bias[i] = 0.f;
  __syncthreads();
  for (int i = 0; i < 3; i++) {
    float* B = bias + 1024 + i * 2560;
    B[t]        = bq[i * 256 + t];    // attn concat: [bq | 0,0,0]
    B[1024 + t] = sb1[i * 256 + t];   // ada1: [sb | 0]
    B[1536 + t] = sb2[i * 256 + t];   // ada2: [sb | 0]
    B[2048 + t] = ogb[i * 256 + t];   // ogtrg: [og_b | tr_gb]
    B[2304 + t] = trb[i * 256 + t];
  }
}

// ---------------- tok idx from one-hot ----------------
__global__ __launch_bounds__(256) void tokidx_k(const float* __restrict__ a2t,
                                                int* __restrict__ idx) {
  int m = blockIdx.x * 4 + (threadIdx.x >> 6);
  int lane = threadIdx.x & 63;
  int best = -1;
  for (int j = 0; j < 16; j++) {
    int col = lane * 16 + j;
    if (a2t[(size_t)m * 1024 + col] > 0.5f) best = col;
  }
#pragma unroll
  for (int off = 1; off < 64; off <<= 1) best = max(best, __shfl_xor(best, off));
  if (lane == 0) idx[m] = best;
}

// ---------------- qf = q + tokfeat[gather] ----------------
__global__ __launch_bounds__(256) void qfinit_k(const float* __restrict__ q,
                                                const float* __restrict__ tokf,
                                                const int* __restrict__ idx,
                                                float* __restrict__ qf) {
  size_t e = ((size_t)blockIdx.x * 256 + threadIdx.x) * 4;
  size_t row = e >> 8;
  int col = (int)(e & 255);
  int m = (int)(row & 4095);
  int bt = (int)(row >> 12);
  float4 qv = *(const float4*)(q + row * 256 + col);
  float4 tv = *(const float4*)(tokf + ((size_t)bt * 1024 + idx[m]) * 256 + col);
  float4 r;
  r.x = qv.x + tv.x; r.y = qv.y + tv.y; r.z = qv.z + tv.z; r.w = qv.w + tv.w;
  *(float4*)(qf + row * 256 + col) = r;
}

// ---------------- rowwise LayerNorm over 256 ----------------
__global__ __launch_bounds__(256) void ln_k(const float* __restrict__ src,
                                            float* __restrict__ dst,
                                            const float* __restrict__ g,
                                            const float* __restrict__ b) {
  size_t row = (size_t)blockIdx.x * 4 + (threadIdx.x >> 6);
  int lane = threadIdx.x & 63;
  float4 v = ((const float4*)(src + row * 256))[lane];
  float s = v.x + v.y + v.z + v.w;
#pragma unroll
  for (int o = 1; o < 64; o <<= 1) s += __shfl_xor(s, o);
  float mu = s * 0.00390625f;
  float dx = v.x - mu, dy = v.y - mu, dz = v.z - mu, dw = v.w - mu;
  float qv = dx * dx + dy * dy + dz * dz + dw * dw;
#pragma unroll
  for (int o = 1; o < 64; o <<= 1) qv += __shfl_xor(qv, o);
  float rs = rsqrtf(qv * 0.00390625f + 1e-5f);
  float4 ov;
  ov.x = dx * rs; ov.y = dy * rs; ov.z = dz * rs; ov.w = dw * rs;
  if (g) {
    int d = lane * 4;
    ov.x = ov.x * g[d] + b[d];
    ov.y = ov.y * g[d + 1] + b[d + 1];
    ov.z = ov.z * g[d + 2] + b[d + 2];
    ov.w = ov.w * g[d + 3] + b[d + 3];
  }
  ((float4*)(dst + row * 256))[lane] = ov;
}

// ---------------- adaLN elementwise: b = sigmoid(t1)*ln_q + t2 (bf16) ----
__global__ __launch_bounds__(256) void ew_adaln_k(const float* __restrict__ tmp,
                                                  const float* __restrict__ lnq,
                                                  unsigned short* __restrict__ bo) {
  size_t e = ((size_t)blockIdx.x * 256 + threadIdx.x) * 4;
  size_t row = e >> 8;
  int col = (int)(e & 255);
  float4 sv = *(const float4*)(tmp + row * 512 + col);
  float4 kv = *(const float4*)(tmp + row * 512 + 256 + col);
  float4 qv = *(const float4*)(lnq + row * 256 + col);
  us4 r;
  r[0] = f2b(sigm(sv.x) * qv.x + kv.x);
  r[1] = f2b(sigm(sv.y) * qv.y + kv.y);
  r[2] = f2b(sigm(sv.z) * qv.z + kv.z);
  r[3] = f2b(sigm(sv.w) * qv.w + kv.w);
  *(us4*)(bo + row * 256 + col) = r;
}

// ---------------- transition elementwise: x = silu(t1)*t2 (bf16) ----------
__global__ __launch_bounds__(256) void ew_silu_k(const unsigned short* __restrict__ big1,
                                                 unsigned short* __restrict__ x) {
  size_t e = ((size_t)blockIdx.x * 256 + threadIdx.x) * 4;
  size_t row = e >> 9;
  int col = (int)(e & 511);
  us4 av = *(const us4*)(big1 + row * 1024 + col);
  us4 bv = *(const us4*)(big1 + row * 1024 + 512 + col);
  us4 r;
#pragma unroll
  for (int j = 0; j < 4; j++) {
    float xx = b2f(av[j]);
    float yy = b2f(bv[j]);
    r[j] = f2b(xx * sigm(xx) * yy);
  }
  *(us4*)(x + row * 512 + col) = r;
}

// ---------------- GEMM: C[rows x NOUT] = ep(A[rows x K] @ Wt[NOUT][K]^T + bias)
// EP0: store fp32; EP1: store bf16; EP2: qf += sigmoid(gate)*acc; EP3: qf += acc
template <int K, int EP, bool ABF>
__global__ __launch_bounds__(256) void gemm_k(
    const void* __restrict__ Av, const unsigned short* __restrict__ Wt,
    const float* __restrict__ bias, void* __restrict__ out,
    float* __restrict__ qf, const unsigned short* __restrict__ gate,
    int gate_stride, int gate_off, int NOUT) {
  int tid = threadIdx.x;
  int lane = tid & 63, wid = tid >> 6;
  int lg = lane >> 4, lr = lane & 15;
  int m0 = blockIdx.x * 64 + (wid >> 1) * 32;
  int n0 = blockIdx.y * 64 + (wid & 1) * 32;
  f32x4 acc[2][2] = {};
  const float* Af = (const float*)Av;
  const unsigned short* Ab = (const unsigned short*)Av;
#pragma unroll 8
  for (int kk = 0; kk < K; kk += 32) {
    bf16x8 a[2], b[2];
#pragma unroll
    for (int mi = 0; mi < 2; mi++) {
      size_t row = (size_t)(m0 + mi * 16 + lr);
      if (ABF) {
        a[mi] = ld_bf8(Ab + row * K + kk + lg * 8);
      } else {
        const float* p = Af + row * K + kk + lg * 8;
        a[mi] = pack_f8(*(const float4*)p, *(const float4*)(p + 4));
      }
    }
#pragma unroll
    for (int ni = 0; ni < 2; ni++) {
      size_t nrow = (size_t)(n0 + ni * 16 + lr);
      b[ni] = ld_bf8(Wt + nrow * K + kk + lg * 8);
    }
#pragma unroll
    for (int mi = 0; mi < 2; mi++)
#pragma unroll
      for (int ni = 0; ni < 2; ni++) mfma_bf16(acc[mi][ni], a[mi], b[ni]);
  }
#pragma unroll
  for (int mi = 0; mi < 2; mi++)
#pragma unroll
    for (int ni = 0; ni < 2; ni++)
#pragma unroll
      for (int r = 0; r < 4; r++) {
        size_t row = (size_t)(m0 + mi * 16 + lg * 4 + r);
        int col = n0 + ni * 16 + lr;
        float v = acc[mi][ni][r] + bias[col];
        if constexpr (EP == 0) {
          ((float*)out)[row * NOUT + col] = v;
        } else if constexpr (EP == 1) {
          ((unsigned short*)out)[row * NOUT + col] = f2b(v);
        } else if constexpr (EP == 2) {
          float g = sigm(b2f(gate[row * gate_stride + gate_off + col]));
          qf[row * 256 + col] += g * v;
        } else {
          qf[row * 256 + col] += v;
        }
      }
}

// ---------------- windowed spatial attention ----------------
// big1 rows = [qh(+bias) | k | v | g_pre], per (bt, window w): q atoms w*32..+32,
// key atoms w*32-48..+128 (bounds-masked). Output o = sigmoid(g)*(softmax(QK^T*s+bias)V)
__global__ __launch_bounds__(128) void attn_k(const unsigned short* __restrict__ big1,
                                              const float* __restrict__ adb,
                                              unsigned short* __restrict__ o, int layer) {
  __shared__ __align__(16) unsigned short p_lds[2][32 * 128];
  __shared__ __align__(16) unsigned short vt_lds[2][32 * 128];
  const int w = blockIdx.x, bt = blockIdx.y;
  const int tid = threadIdx.x, wid = tid >> 6, lane = tid & 63;
  const int lg = lane >> 4, lr = lane & 15;
  unsigned short* pl = p_lds[wid];
  unsigned short* vt = vt_lds[wid];
  const size_t base = (size_t)bt * M_;
  const float inv_s = 0.17677669529663687f;
  for (int hh = 0; hh < 4; hh++) {
    const int h = wid * 4 + hh;
    // stage v^T: vt[d][kidx]
    for (int it = 0; it < 64; it++) {
      int idx = it * 64 + lane;
      int d = idx & 31, kidx = idx >> 5;
      int ak = w * 32 - SIDE_ + kidx;
      int akc = ak < 0 ? 0 : (ak > M_ - 1 ? M_ - 1 : ak);
      vt[d * 128 + kidx] = big1[(base + akc) * 1024 + 512 + h * 32 + d];
    }
    // QK^T via MFMA (K-dim = dh = 32, single step)
    bf16x8 aq[2];
#pragma unroll
    for (int mi = 0; mi < 2; mi++)
      aq[mi] = ld_bf8(big1 + (base + w * 32 + mi * 16 + lr) * 1024 + h * 32 + lg * 8);
    f32x4 lac[2][8] = {};
#pragma unroll
    for (int ni = 0; ni < 8; ni++) {
      int kidx = ni * 16 + lr;
      int ak = w * 32 - SIDE_ + kidx;
      int akc = ak < 0 ? 0 : (ak > M_ - 1 ? M_ - 1 : ak);
      bf16x8 bk = ld_bf8(big1 + (base + akc) * 1024 + 256 + h * 32 + lg * 8);
      mfma_bf16(lac[0][ni], aq[0], bk);
      mfma_bf16(lac[1][ni], aq[1], bk);
    }
    // bias + mask + softmax (rows live in 16-lane groups sharing lg)
#pragma unroll
    for (int mi = 0; mi < 2; mi++)
#pragma unroll
      for (int r = 0; r < 4; r++) {
        int qrow = mi * 16 + lg * 4 + r;
        float lv[8];
        float mx = -3e38f;
#pragma unroll
        for (int ni = 0; ni < 8; ni++) {
          int kidx = ni * 16 + lr;
          int ak = w * 32 - SIDE_ + kidx;
          float bb = adb[((size_t)(w * 32 + qrow) * 128 + kidx) * 24 + layer * 8 + h];
          float x = lac[mi][ni][r] * inv_s + bb +
                    ((unsigned)ak < (unsigned)M_ ? 0.f : -1e9f);
          lv[ni] = x;
          mx = fmaxf(mx, x);
        }
#pragma unroll
        for (int off = 1; off < 16; off <<= 1) mx = fmaxf(mx, __shfl_xor(mx, off));
        float sum = 0.f;
#pragma unroll
        for (int ni = 0; ni < 8; ni++) {
          float e = __expf(lv[ni] - mx);
          lv[ni] = e;
          sum += e;
        }
#pragma unroll
        for (int off = 1; off < 16; off <<= 1) sum += __shfl_xor(sum, off);
        float inv = 1.f / sum;
#pragma unroll
        for (int ni = 0; ni < 8; ni++)
          pl[qrow * 128 + ni * 16 + lr] = f2b(lv[ni] * inv);
      }
    __syncthreads();
    // PV via MFMA over K=128 keys
    f32x4 oc[2][2] = {};
#pragma unroll
    for (int ks = 0; ks < 4; ks++) {
      bf16x8 ap0 = ld_bf8(pl + lr * 128 + ks * 32 + lg * 8);
      bf16x8 ap1 = ld_bf8(pl + (16 + lr) * 128 + ks * 32 + lg * 8);
      bf16x8 bv0 = ld_bf8(vt + lr * 128 + ks * 32 + lg * 8);
      bf16x8 bv1 = ld_bf8(vt + (16 + lr) * 128 + ks * 32 + lg * 8);
      mfma_bf16(oc[0][0], ap0, bv0);
      mfma_bf16(oc[0][1], ap0, bv1);
      mfma_bf16(oc[1][0], ap1, bv0);
      mfma_bf16(oc[1][1], ap1, bv1);
    }
#pragma unroll
    for (int mi = 0; mi < 2; mi++)
#pragma unroll
      for (int nd = 0; nd < 2; nd++)
#pragma unroll
        for (int r = 0; r < 4; r++) {
          int qrow = mi * 16 + lg * 4 + r;
          int d = nd * 16 + lr;
          size_t rowi = base + w * 32 + qrow;
          float gv = sigm(b2f(big1[rowi * 1024 + 768 + h * 32 + d]));
          o[rowi * 256 + h * 32 + d] = f2b(oc[mi][nd][r] * gv);
        }
    __syncthreads();
  }
}

// ---------------- temporal attention (T=8 per atom) ----------------
// big1 rows (t*M+m) = [tq | tk | tv | tg_pre]; out o = sigmoid(tg)*to
__global__ __launch_bounds__(256) void tattn_k(const unsigned short* __restrict__ big1,
                                               const float* __restrict__ ts,
                                               const float* __restrict__ tdec,
                                               unsigned short* __restrict__ o, int layer) {
  __shared__ __align__(16) unsigned short lds[4][8 * 768];
  int wid = threadIdx.x >> 6, lane = threadIdx.x & 63;
  int m = blockIdx.x * 4 + wid;
  unsigned short* Lp = lds[wid];
  for (int it = 0; it < 12; it++) {
    int u = it * 64 + lane;
    int t = u / 96, pos = (u % 96) * 8;
    *(uint4*)(Lp + t * 768 + pos) =
        *(const uint4*)(big1 + ((size_t)(t * M_ + m)) * 1024 + pos);
  }
  __syncthreads();
  int th = lane >> 3, qt = lane & 7;
  float decay = log1pf(__expf(tdec[layer * 8 + th]));
  float tsq = ts[qt];
  const float inv_t = 0.17677669529663687f;
  float tqv[32];
#pragma unroll
  for (int d = 0; d < 32; d++) tqv[d] = b2f(Lp[qt * 768 + th * 32 + d]);
  float lv[8];
  float mx = -3e38f;
#pragma unroll
  for (int kt = 0; kt < 8; kt++) {
    float dot = 0.f;
#pragma unroll
    for (int d = 0; d < 32; d++) dot += tqv[d] * b2f(Lp[kt * 768 + 256 + th * 32 + d]);
    float x = dot * inv_t - decay * fabsf(tsq - ts[kt]);
    lv[kt] = x;
    mx = fmaxf(mx, x);
  }
  float s = 0.f;
#pragma unroll
  for (int kt = 0; kt < 8; kt++) {
    float e = __expf(lv[kt] - mx);
    lv[kt] = e;
    s += e;
  }
  float inv = 1.f / s;
  float tov[32];
#pragma unroll
  for (int d = 0; d < 32; d++) tov[d] = 0.f;
#pragma unroll
  for (int kt = 0; kt < 8; kt++) {
    float p = lv[kt] * inv;
#pragma unroll
    for (int d = 0; d < 32; d++) tov[d] += p * b2f(Lp[kt * 768 + 512 + th * 32 + d]);
  }
  size_t orow = (size_t)qt * M_ + m;
#pragma unroll
  for (int d = 0; d < 32; d++) {
    float tg = sigm(b2f(big1[orow * 1024 + 768 + th * 32 + d]));
    o[orow * 256 + th * 32 + d] = f2b(tov[d] * tg);
  }
}

// ---------------- final: out = LN(qf, pos_g, pos_b) @ pos_w ----------------
__global__ __launch_bounds__(256) void final_k(const float* __restrict__ qf,
                                               const float* __restrict__ pg,
                                               const float* __restrict__ pb,
                                               const float* __restrict__ pw,
                                               float* __restrict__ out) {
  size_t row = (size_t)blockIdx.x * 4 + (threadIdx.x >> 6);
  int lane = threadIdx.x & 63;
  float4 v = ((const float4*)(qf + row * 256))[lane];
  float s = v.x + v.y + v.z + v.w;
#pragma unroll
  for (int o = 1; o < 64; o <<= 1) s += __shfl_xor(s, o);
  float mu = s * 0.00390625f;
  float dx = v.x - mu, dy = v.y - mu, dz = v.z - mu, dw = v.w - mu;
  float qv = dx * dx + dy * dy + dz * dz + dw * dw;
#pragma unroll
  for (int o = 1; o < 64; o <<= 1) qv += __shfl_xor(qv, o);
  float rs = rsqrtf(qv * 0.00390625f + 1e-5f);
  int d = lane * 4;
  float xn[4];
  xn[0] = dx * rs * pg[d] + pb[d];
  xn[1] = dy * rs * pg[d + 1] + pb[d + 1];
  xn[2] = dz * rs * pg[d + 2] + pb[d + 2];
  xn[3] = dw * rs * pg[d + 3] + pb[d + 3];
  float p0 = 0.f, p1 = 0.f, p2 = 0.f;
#pragma unroll
  for (int dd = 0; dd < 4; dd++) {
    const float* wr = pw + (size_t)(d + dd) * 3;
    p0 += xn[dd] * wr[0];
    p1 += xn[dd] * wr[1];
    p2 += xn[dd] * wr[2];
  }
#pragma unroll
  for (int o = 1; o < 64; o <<= 1) {
    p0 += __shfl_xor(p0, o);
    p1 += __shfl_xor(p1, o);
    p2 += __shfl_xor(p2, o);
  }
  if (lane == 0) {
    out[row * 3 + 0] = p0;
    out[row * 3 + 1] = p1;
    out[row * 3 + 2] = p2;
  }
}

extern "C" void kernel_launch(void* const* d_in, const int* in_sizes, int n_in,
                              void* d_out, int out_size, void* d_ws, size_t ws_size,
                              hipStream_t stream) {
  const float* a       = (const float*)d_in[0];
  const float* q_in    = (const float*)d_in[1];
  const float* c_in    = (const float*)d_in[2];
  const float* adb     = (const float*)d_in[3];
  const float* a2t     = (const float*)d_in[4];
  const float* ts      = (const float*)d_in[6];
  const float* W_a2q   = (const float*)d_in[7];
  const float* ada1_sw = (const float*)d_in[8];
  const float* ada1_sb = (const float*)d_in[9];
  const float* ada1_kw = (const float*)d_in[10];
  const float* attn_wq = (const float*)d_in[11];
  const float* attn_bq = (const float*)d_in[12];
  const float* attn_wk = (const float*)d_in[13];
  const float* attn_wv = (const float*)d_in[14];
  const float* attn_wg = (const float*)d_in[15];
  const float* attn_wo = (const float*)d_in[16];
  const float* og_w    = (const float*)d_in[17];
  const float* og_b    = (const float*)d_in[18];
  const float* ada2_sw = (const float*)d_in[19];
  const float* ada2_sb = (const float*)d_in[20];
  const float* ada2_kw = (const float*)d_in[21];
  const float* tr_w1   = (const float*)d_in[22];
  const float* tr_w2   = (const float*)d_in[23];
  const float* tr_w3   = (const float*)d_in[24];
  const float* tr_gw   = (const float*)d_in[25];
  const float* tr_gb   = (const float*)d_in[26];
  const float* t_ln_g  = (const float*)d_in[27];
  const float* t_ln_b  = (const float*)d_in[28];
  const float* t_wq    = (const float*)d_in[29];
  const float* t_wk    = (const float*)d_in[30];
  const float* t_wv    = (const float*)d_in[31];
  const float* t_wg    = (const float*)d_in[32];
  const float* t_wo    = (const float*)d_in[33];
  const float* t_dec   = (const float*)d_in[34];
  const float* pos_g   = (const float*)d_in[35];
  const float* pos_b   = (const float*)d_in[36];
  const float* pos_w   = (const float*)d_in[37];

  // workspace layout (floats), total ~233 MiB
  float* W = (float*)d_ws;
  float* qf   = W;                  // [F]   fp32 residual stream
  float* ln_c = W + Fq;             // [F]   LN(c), computed once
  float* ln_q = W + 2 * Fq;         // [F]   LN(qf); also reused as bf16 x-buffer
  float* tmp  = W + 3 * Fq;         // [2F]  adaLN GEMM out (fp32 R x 512); aliases big1
  unsigned short* big1 = (unsigned short*)(W + 3 * Fq);   // [4F bf16] concat GEMM out
  float* tokf = W + 3 * Fq;         // [2.1M] a@W_a2q (aliases big1, dead before layer 0)
  unsigned short* bbuf  = (unsigned short*)(W + 5 * Fq);            // [F bf16]
  unsigned short* gates = (unsigned short*)(W + 5 * Fq + Fq / 2);   // [2F bf16]
  unsigned short* obuf  = (unsigned short*)(W + 6 * Fq + Fq / 2);   // [F bf16]
  int* tokidx = (int*)(W + 7 * Fq);                                  // [4096]
  unsigned short* wbf = (unsigned short*)(W + 7 * Fq + 4096);        // [4718592 bf16]
  float* biasr = W + 7 * Fq + 4096 + 2359296;                        // [8704]
  unsigned short* xbuf = (unsigned short*)ln_q;

  // weight transpose-convert descriptors
  ConvArgs ca;
  int ne = 0;
  auto add = [&](const float* s, size_t doff, int K, int N) {
    ca.src[ne] = s; ca.doff[ne] = (int)doff; ca.Kd[ne] = K; ca.Nd[ne] = N; ne++;
  };
  constexpr size_t LW = 1441792;
  for (int i = 0; i < 3; i++) {
    size_t LB = (size_t)i * LW;
    add(ada1_sw + i * 65536, LB + 0, 256, 256);
    add(ada1_kw + i * 65536, LB + 65536, 256, 256);
    add(attn_wq + i * 65536, LB + 131072, 256, 256);
    add(attn_wk + i * 65536, LB + 196608, 256, 256);
    add(attn_wv + i * 65536, LB + 262144, 256, 256);
    add(attn_wg + i * 65536, LB + 327680, 256, 256);
    add(attn_wo + i * 65536, LB + 393216, 256, 256);
    add(og_w + i * 65536, LB + 458752, 256, 256);
    add(tr_gw + i * 65536, LB + 524288, 256, 256);
    add(ada2_sw + i * 65536, LB + 589824, 256, 256);
    add(ada2_kw + i * 65536, LB + 655360, 256, 256);
    add(tr_w1 + i * 131072, LB + 720896, 256, 512);
    add(tr_w2 + i * 131072, LB + 851968, 256, 512);
    add(tr_w3 + i * 131072, LB + 983040, 512, 256);
    add(t_wq + i * 65536, LB + 1114112, 256, 256);
    add(t_wk + i * 65536, LB + 1179648, 256, 256);
    add(t_wv + i * 65536, LB + 1245184, 256, 256);
    add(t_wg + i * 65536, LB + 1310720, 256, 256);
    add(t_wo + i * 65536, LB + 1376256, 256, 256);
  }
  add(W_a2q, 3 * LW, 1536, 256);
  ca.n = ne;

  conv_k<<<dim3(ne, 96), 256, 0, stream>>>(ca, wbf);
  bias_prep_k<<<1, 256, 0, stream>>>(attn_bq, ada1_sb, ada2_sb, og_b, tr_gb, biasr);
  tokidx_k<<<1024, 256, 0, stream>>>(a2t, tokidx);
  gemm_k<1536, 0, false><<<dim3(128, 4), 256, 0, stream>>>(
      a, wbf + 3 * LW, biasr, tokf, nullptr, nullptr, 0, 0, 256);
  qfinit_k<<<8192, 256, 0, stream>>>(q_in, tokf, tokidx, qf);
  ln_k<<<8192, 256, 0, stream>>>(c_in, ln_c, nullptr, nullptr);

  for (int i = 0; i < 3; i++) {
    size_t LB = (size_t)i * LW;
    const float* b_attn = biasr + 1024 + (size_t)i * 2560;
    const float* b_ada1 = b_attn + 1024;
    const float* b_ada2 = b_attn + 1536;
    const float* b_ogtr = b_attn + 2048;

    // adaLN 1 -> b
    ln_k<<<8192, 256, 0, stream>>>(qf, ln_q, nullptr, nullptr);
    gemm_k<256, 0, false><<<dim3(512, 8), 256, 0, stream>>>(
        ln_c, wbf + LB, b_ada1, tmp, nullptr, nullptr, 0, 0, 512);
    ew_adaln_k<<<8192, 256, 0, stream>>>(tmp, ln_q, bbuf);
    // qkvg projections + spatial attention
    gemm_k<256, 1, true><<<dim3(512, 16), 256, 0, stream>>>(
        bbuf, wbf + LB + 131072, b_attn, big1, nullptr, nullptr, 0, 0, 1024);
    attn_k<<<dim3(128, 8), 128, 0, stream>>>(big1, adb, obuf, i);
    // og | trg gates (A = c)
    gemm_k<256, 1, false><<<dim3(512, 8), 256, 0, stream>>>(
        c_in, wbf + LB + 458752, b_ogtr, gates, nullptr, nullptr, 0, 0, 512);
    // qf += sigmoid(og) * (o @ wo)
    gemm_k<256, 2, true><<<dim3(512, 4), 256, 0, stream>>>(
        obuf, wbf + LB + 393216, biasr, nullptr, qf, gates, 512, 0, 256);
    // adaLN 2 -> t
    ln_k<<<8192, 256, 0, stream>>>(qf, ln_q, nullptr, nullptr);
    gemm_k<256, 0, false><<<dim3(512, 8), 256, 0, stream>>>(
        ln_c, wbf + LB + 589824, b_ada2, tmp, nullptr, nullptr, 0, 0, 512);
    ew_adaln_k<<<8192, 256, 0, stream>>>(tmp, ln_q, bbuf);
    // transition
    gemm_k<256, 1, true><<<dim3(512, 16), 256, 0, stream>>>(
        bbuf, wbf + LB + 720896, biasr, big1, nullptr, nullptr, 0, 0, 1024);
    ew_silu_k<<<16384, 256, 0, stream>>>(big1, xbuf);
    gemm_k<512, 2, true><<<dim3(512, 4), 256, 0, stream>>>(
        xbuf, wbf + LB + 983040, biasr, nullptr, qf, gates, 512, 256, 256);
    // temporal attention
    ln_k<<<8192, 256, 0, stream>>>(qf, ln_q, t_ln_g + (size_t)i * 256,
                                   t_ln_b + (size_t)i * 256);
    gemm_k<256, 1, false><<<dim3(512, 16), 256, 0, stream>>>(
        ln_q, wbf + LB + 1114112, biasr, big1, nullptr, nullptr, 0, 0, 1024);
    tattn_k<<<1024, 256, 0, stream>>>(big1, ts, t_dec, obuf, i);
    gemm_k<256, 3, true><<<dim3(512, 4), 256, 0, stream>>>(
        obuf, wbf + LB + 1376256, biasr, nullptr, qf, nullptr, 0, 0, 256);
  }
  final_k<<<8192, 256, 0, stream>>>(qf, pos_g, pos_b, pos_w, (float*)d_out);
}

// Round 2
// 1570.818 us; speedup vs baseline: 2.4922x; 2.4922x over previous
//
#include <hip/hip_runtime.h>
#include <cstddef>
#include <cstdint>

#define DEVI __device__ __forceinline__

typedef __attribute__((ext_vector_type(8))) __bf16 bf16x8;
typedef __attribute__((ext_vector_type(8))) unsigned short us8;
typedef __attribute__((ext_vector_type(4))) unsigned short us4;
typedef __attribute__((ext_vector_type(4))) float f32x4;

constexpr int B0_ = 1, T_ = 8, N_ = 1024, M_ = 4096, D_ = 256;
constexpr int BT_ = 8, NW_ = 128, WQ_ = 32, HK_ = 128, SIDE_ = 48;
constexpr int R_ = BT_ * M_;          // 32768 rows
constexpr size_t Fq = 8388608;        // R_*256 elements

DEVI unsigned short f2b(float f) {
  unsigned u = __float_as_uint(f);
  u = (u + 0x7FFFu + ((u >> 16) & 1u)) >> 16;
  return (unsigned short)u;
}
DEVI float b2f(unsigned short s) { return __uint_as_float(((unsigned)s) << 16); }
DEVI float sigm(float x) { return 1.0f / (1.0f + __expf(-x)); }
DEVI bf16x8 ld_bf8(const unsigned short* p) {
  return __builtin_bit_cast(bf16x8, *(const us8*)p);
}
DEVI bf16x8 pack_f8(float4 v0, float4 v1) {
  us8 t;
  t[0] = f2b(v0.x); t[1] = f2b(v0.y); t[2] = f2b(v0.z); t[3] = f2b(v0.w);
  t[4] = f2b(v1.x); t[5] = f2b(v1.y); t[6] = f2b(v1.z); t[7] = f2b(v1.w);
  return __builtin_bit_cast(bf16x8, t);
}
DEVI void mfma_bf16(f32x4& c, bf16x8 a, bf16x8 b) {
  c = __builtin_amdgcn_mfma_f32_16x16x32_bf16(a, b, c, 0, 0, 0);
}
// async global->LDS, 16B per lane; lds dest = wave-uniform base + lane*16
DEVI void gload16(const void* g, void* l) {
  __builtin_amdgcn_global_load_lds((__attribute__((address_space(1))) void*)g,
                                   (__attribute__((address_space(3))) void*)l, 16, 0, 0);
}

// ---------------- weight transpose-convert (fp32 [K][N] -> bf16 Wt[N][K]) ----
struct ConvArgs {
  const float* src[64];
  int doff[64];
  int Kd[64];
  int Nd[64];
  int n;
};

__global__ __launch_bounds__(256) void conv_k(ConvArgs ca, unsigned short* __restrict__ wbf) {
  int e = blockIdx.x;
  int K = ca.Kd[e], N = ca.Nd[e];
  int nx = N >> 6, nk = K >> 6;
  int t = blockIdx.y;
  if (t >= nx * nk) return;
  int tx = t % nx, tk = t / nx;
  const float* s = ca.src[e];
  unsigned short* d = wbf + ca.doff[e];
  int n = tx * 64 + (threadIdx.x & 63);
  int k0 = tk * 64 + (threadIdx.x >> 6) * 16;
  for (int r = 0; r < 16; r++) {
    int k = k0 + r;
    d[(size_t)n * K + k] = f2b(s[(size_t)k * N + n]);
  }
}

// ---------------- fp32 -> bf16 flat convert ----------------
__global__ __launch_bounds__(256) void cvt_k(const float* __restrict__ s,
                                             unsigned short* __restrict__ d, int n8) {
  int i = blockIdx.x * 256 + threadIdx.x;
  if (i >= n8) return;
  float4 v0 = *(const float4*)(s + (size_t)i * 8);
  float4 v1 = *(const float4*)(s + (size_t)i * 8 + 4);
  *(us8*)(d + (size_t)i * 8) = __builtin_bit_cast(us8, pack_f8(v0, v1));
}

// ---------------- bias concat prep ----------------
__global__ __launch_bounds__(256) void bias_prep_k(
    const float* __restrict__ bq, const float* __restrict__ sb1,
    const float* __restrict__ sb2, const float* __restrict__ ogb,
    const float* __restrict__ trb, float* __restrict__ bias) {
  int t = threadIdx.x;
  for (int i = t; i < 1024 + 3 * 2560; i += 256) bias[i] = 0.f;
  __syncthreads();
  for (int i = 0; i < 3; i++) {
    float* B = bias + 1024 + i * 2560;
    B[t]        = bq[i * 256 + t];
    B[1024 + t] = sb1[i * 256 + t];
    B[1536 + t] = sb2[i * 256 + t];
    B[2048 + t] = ogb[i * 256 + t];
    B[2304 + t] = trb[i * 256 + t];
  }
}

// ---------------- attn bias relayout: adb[(w*32+q)*128+k][l*8+h] -> biasb[(l*8+h)][row][k] bf16
__global__ __launch_bounds__(256) void biasb_k(const float* __restrict__ adb,
                                               unsigned short* __restrict__ biasb) {
  __shared__ float ld[3072];
  int rq = blockIdx.x;  // 0..4095
  int t = threadIdx.x;
  const float* src = adb + (size_t)rq * 3072;
  for (int i = t; i < 3072; i += 256) ld[i] = src[i];
  __syncthreads();
  int k = t & 127;
  for (int lh = t >> 7; lh < 24; lh += 2)
    biasb[((size_t)lh * 4096 + rq) * 128 + k] = f2b(ld[k * 24 + lh]);
}

// ---------------- tok idx from one-hot ----------------
__global__ __launch_bounds__(256) void tokidx_k(const float* __restrict__ a2t,
                                                int* __restrict__ idx) {
  int m = blockIdx.x * 4 + (threadIdx.x >> 6);
  int lane = threadIdx.x & 63;
  int best = -1;
  for (int j = 0; j < 16; j++) {
    int col = lane * 16 + j;
    if (a2t[(size_t)m * 1024 + col] > 0.5f) best = col;
  }
#pragma unroll
  for (int off = 1; off < 64; off <<= 1) best = max(best, __shfl_xor(best, off));
  if (lane == 0) idx[m] = best;
}

// ---------------- qf = q + tokfeat[gather] (tokf bf16) ----------------
__global__ __launch_bounds__(256) void qfinit_k(const float* __restrict__ q,
                                                const unsigned short* __restrict__ tokf,
                                                const int* __restrict__ idx,
                                                float* __restrict__ qf) {
  size_t e = ((size_t)blockIdx.x * 256 + threadIdx.x) * 4;
  size_t row = e >> 8;
  int col = (int)(e & 255);
  int m = (int)(row & 4095);
  int bt = (int)(row >> 12);
  float4 qv = *(const float4*)(q + row * 256 + col);
  us4 tv = *(const us4*)(tokf + ((size_t)bt * 1024 + idx[m]) * 256 + col);
  float4 r;
  r.x = qv.x + b2f(tv[0]); r.y = qv.y + b2f(tv[1]);
  r.z = qv.z + b2f(tv[2]); r.w = qv.w + b2f(tv[3]);
  *(float4*)(qf + row * 256 + col) = r;
}

// ---------------- rowwise LayerNorm over 256, fp32 in -> bf16 out ----------
__global__ __launch_bounds__(256) void ln_k(const float* __restrict__ src,
                                            unsigned short* __restrict__ dst,
                                            const float* __restrict__ g,
                                            const float* __restrict__ b) {
  size_t row = (size_t)blockIdx.x * 4 + (threadIdx.x >> 6);
  int lane = threadIdx.x & 63;
  float4 v = ((const float4*)(src + row * 256))[lane];
  float s = v.x + v.y + v.z + v.w;
#pragma unroll
  for (int o = 1; o < 64; o <<= 1) s += __shfl_xor(s, o);
  float mu = s * 0.00390625f;
  float dx = v.x - mu, dy = v.y - mu, dz = v.z - mu, dw = v.w - mu;
  float qv = dx * dx + dy * dy + dz * dz + dw * dw;
#pragma unroll
  for (int o = 1; o < 64; o <<= 1) qv += __shfl_xor(qv, o);
  float rs = rsqrtf(qv * 0.00390625f + 1e-5f);
  float ov[4] = {dx * rs, dy * rs, dz * rs, dw * rs};
  if (g) {
    int d = lane * 4;
#pragma unroll
    for (int j = 0; j < 4; j++) ov[j] = ov[j] * g[d + j] + b[d + j];
  }
  us4 r;
#pragma unroll
  for (int j = 0; j < 4; j++) r[j] = f2b(ov[j]);
  *(us4*)(dst + row * 256 + lane * 4) = r;
}

// ---------------- adaLN elementwise: b = sigmoid(t1)*ln_q + t2 (all bf16) ----
__global__ __launch_bounds__(256) void ew_adaln_k(const unsigned short* __restrict__ tmp,
                                                  const unsigned short* __restrict__ lnq,
                                                  unsigned short* __restrict__ bo) {
  size_t e = ((size_t)blockIdx.x * 256 + threadIdx.x) * 4;
  size_t row = e >> 8;
  int col = (int)(e & 255);
  us4 sv = *(const us4*)(tmp + row * 512 + col);
  us4 kv = *(const us4*)(tmp + row * 512 + 256 + col);
  us4 qv = *(const us4*)(lnq + row * 256 + col);
  us4 r;
#pragma unroll
  for (int j = 0; j < 4; j++)
    r[j] = f2b(sigm(b2f(sv[j])) * b2f(qv[j]) + b2f(kv[j]));
  *(us4*)(bo + row * 256 + col) = r;
}

// ---------------- transition elementwise: x = silu(t1)*t2 (bf16) ----------
__global__ __launch_bounds__(256) void ew_silu_k(const unsigned short* __restrict__ big1,
                                                 unsigned short* __restrict__ x) {
  size_t e = ((size_t)blockIdx.x * 256 + threadIdx.x) * 4;
  size_t row = e >> 9;
  int col = (int)(e & 511);
  us4 av = *(const us4*)(big1 + row * 1024 + col);
  us4 bv = *(const us4*)(big1 + row * 1024 + 512 + col);
  us4 r;
#pragma unroll
  for (int j = 0; j < 4; j++) {
    float xx = b2f(av[j]);
    float yy = b2f(bv[j]);
    r[j] = f2b(xx * sigm(xx) * yy);
  }
  *(us4*)(x + row * 512 + col) = r;
}

// ---------------- staged GEMM (m97 structure): 128x128 tile, BK=32 ----------
// C[rows x NOUT] = ep(A[rows x K](bf16) @ Wt[NOUT][K]^T + bias)
// EP1: store bf16; EP2: qf += sigmoid(gate)*acc; EP3: qf += acc
template <int K, int EP>
__global__ __launch_bounds__(256) void gemm2_k(
    const unsigned short* __restrict__ A, const unsigned short* __restrict__ Wt,
    const float* __restrict__ bias, unsigned short* __restrict__ out,
    float* __restrict__ qf, const unsigned short* __restrict__ gate,
    int gate_stride, int gate_off, int NOUT) {
  __shared__ __align__(16) unsigned short As[128 * 32];
  __shared__ __align__(16) unsigned short Bs[128 * 32];
  const int tid = threadIdx.x;
  const int lane = tid & 63, w = tid >> 6;
  const int lg = lane >> 4, lr = lane & 15;
  const int wr = w >> 1, wc = w & 1;
  const size_t m_base = (size_t)blockIdx.x * 128;
  const size_t n_base = (size_t)blockIdx.y * 128;
  const int srow = lane >> 2;
  const int scol = (lane & 3) * 8;
  const unsigned short* gA0 = A + (m_base + w * 16 + srow) * K + scol;
  const unsigned short* gA1 = gA0 + (size_t)64 * K;
  const unsigned short* gB0 = Wt + (n_base + w * 16 + srow) * K + scol;
  const unsigned short* gB1 = gB0 + (size_t)64 * K;
  unsigned short* lA0 = As + (w * 16) * 32;
  unsigned short* lA1 = lA0 + 64 * 32;
  unsigned short* lB0 = Bs + (w * 16) * 32;
  unsigned short* lB1 = lB0 + 64 * 32;
  const unsigned short* pa = As + ((size_t)wr * 64 + lr) * 32 + lg * 8;
  const unsigned short* pb = Bs + ((size_t)wc * 64 + lr) * 32 + lg * 8;
  f32x4 acc[4][4] = {};
  for (int kk = 0; kk < K; kk += 32) {
    gload16(gA0 + kk, lA0);
    gload16(gA1 + kk, lA1);
    gload16(gB0 + kk, lB0);
    gload16(gB1 + kk, lB1);
    __syncthreads();
    bf16x8 af[4], bfr[4];
#pragma unroll
    for (int i = 0; i < 4; i++) {
      af[i] = ld_bf8(pa + i * 16 * 32);
      bfr[i] = ld_bf8(pb + i * 16 * 32);
    }
#pragma unroll
    for (int mi = 0; mi < 4; mi++)
#pragma unroll
      for (int ni = 0; ni < 4; ni++) mfma_bf16(acc[mi][ni], af[mi], bfr[ni]);
    __syncthreads();
  }
#pragma unroll
  for (int mi = 0; mi < 4; mi++)
#pragma unroll
    for (int ni = 0; ni < 4; ni++)
#pragma unroll
      for (int r = 0; r < 4; r++) {
        size_t row = m_base + wr * 64 + mi * 16 + lg * 4 + r;
        int col = (int)n_base + wc * 64 + ni * 16 + lr;
        float v = acc[mi][ni][r] + bias[col];
        if constexpr (EP == 1) {
          out[row * NOUT + col] = f2b(v);
        } else if constexpr (EP == 2) {
          float g = sigm(b2f(gate[row * gate_stride + gate_off + col]));
          qf[row * 256 + col] += g * v;
        } else {
          qf[row * 256 + col] += v;
        }
      }
}

// ---------------- direct GEMM (fp32 A), kept for gates only ----------------
__global__ __launch_bounds__(256) void gemmf_k(
    const float* __restrict__ A, const unsigned short* __restrict__ Wt,
    const float* __restrict__ bias, unsigned short* __restrict__ out, int NOUT) {
  int tid = threadIdx.x;
  int lane = tid & 63, wid = tid >> 6;
  int lg = lane >> 4, lr = lane & 15;
  int m0 = blockIdx.x * 64 + (wid >> 1) * 32;
  int n0 = blockIdx.y * 64 + (wid & 1) * 32;
  f32x4 acc[2][2] = {};
#pragma unroll 8
  for (int kk = 0; kk < 256; kk += 32) {
    bf16x8 a[2], b[2];
#pragma unroll
    for (int mi = 0; mi < 2; mi++) {
      const float* p = A + (size_t)(m0 + mi * 16 + lr) * 256 + kk + lg * 8;
      a[mi] = pack_f8(*(const float4*)p, *(const float4*)(p + 4));
    }
#pragma unroll
    for (int ni = 0; ni < 2; ni++)
      b[ni] = ld_bf8(Wt + (size_t)(n0 + ni * 16 + lr) * 256 + kk + lg * 8);
#pragma unroll
    for (int mi = 0; mi < 2; mi++)
#pragma unroll
      for (int ni = 0; ni < 2; ni++) mfma_bf16(acc[mi][ni], a[mi], b[ni]);
  }
#pragma unroll
  for (int mi = 0; mi < 2; mi++)
#pragma unroll
    for (int ni = 0; ni < 2; ni++)
#pragma unroll
      for (int r = 0; r < 4; r++) {
        size_t row = (size_t)(m0 + mi * 16 + lg * 4 + r);
        int col = n0 + ni * 16 + lr;
        out[row * NOUT + col] = f2b(acc[mi][ni][r] + bias[col]);
      }
}

// ---------------- windowed spatial attention ----------------
// 4 waves/block, head-per-wave; grid (NW, BT, 2). LDS: per-wave swizzled p, v^T.
// swizzle: element (row, k) -> base + row*128 + (k ^ ((row&7)<<3))
__global__ __launch_bounds__(256) void attn_k(const unsigned short* __restrict__ big1,
                                              const unsigned short* __restrict__ biasb,
                                              unsigned short* __restrict__ o, int layer) {
  __shared__ __align__(16) unsigned short pl_s[4][32 * 128];
  __shared__ __align__(16) unsigned short vt_s[4][32 * 128];
  const int w = blockIdx.x, bt = blockIdx.y, hg = blockIdx.z;
  const int tid = threadIdx.x, wid = tid >> 6, lane = tid & 63;
  const int lg = lane >> 4, lr = lane & 15;
  const int h = hg * 4 + wid;
  unsigned short* pl = pl_s[wid];
  unsigned short* vt = vt_s[wid];
  const size_t base = (size_t)bt * M_;
  const float inv_s = 0.17677669529663687f;

  // stage V^T (coalesced 16B global reads, swizzled LDS writes)
  {
    const int chunk = lane & 3;
    const int krow = lane >> 2;
#pragma unroll
    for (int it = 0; it < 8; it++) {
      int key = it * 16 + krow;
      int ak = w * 32 - SIDE_ + key;
      int akc = ak < 0 ? 0 : (ak > M_ - 1 ? M_ - 1 : ak);
      us8 v = *(const us8*)(big1 + (base + akc) * 1024 + 512 + h * 32 + chunk * 8);
#pragma unroll
      for (int e = 0; e < 8; e++) {
        int d = chunk * 8 + e;
        vt[d * 128 + (key ^ ((d & 7) << 3))] = v[e];
      }
    }
  }
  // QK^T via MFMA (K-dim = dh = 32)
  bf16x8 aq[2];
#pragma unroll
  for (int mi = 0; mi < 2; mi++)
    aq[mi] = ld_bf8(big1 + (base + w * 32 + mi * 16 + lr) * 1024 + h * 32 + lg * 8);
  f32x4 lac[2][8] = {};
#pragma unroll
  for (int ni = 0; ni < 8; ni++) {
    int kidx = ni * 16 + lr;
    int ak = w * 32 - SIDE_ + kidx;
    int akc = ak < 0 ? 0 : (ak > M_ - 1 ? M_ - 1 : ak);
    bf16x8 bk = ld_bf8(big1 + (base + akc) * 1024 + 256 + h * 32 + lg * 8);
    mfma_bf16(lac[0][ni], aq[0], bk);
    mfma_bf16(lac[1][ni], aq[1], bk);
  }
  // bias + mask + softmax; p -> swizzled LDS
  const unsigned short* brow0 =
      biasb + (((size_t)(layer * 8 + h)) * 4096 + w * 32) * 128;
#pragma unroll
  for (int mi = 0; mi < 2; mi++)
#pragma unroll
    for (int r = 0; r < 4; r++) {
      int qrow = mi * 16 + lg * 4 + r;
      const unsigned short* brow = brow0 + (size_t)qrow * 128;
      float lv[8];
      float mx = -3e38f;
#pragma unroll
      for (int ni = 0; ni < 8; ni++) {
        int kidx = ni * 16 + lr;
        int ak = w * 32 - SIDE_ + kidx;
        float x = lac[mi][ni][r] * inv_s + b2f(brow[kidx]) +
                  ((unsigned)ak < (unsigned)M_ ? 0.f : -1e9f);
        lv[ni] = x;
        mx = fmaxf(mx, x);
      }
#pragma unroll
      for (int off = 1; off < 16; off <<= 1) mx = fmaxf(mx, __shfl_xor(mx, off));
      float sum = 0.f;
#pragma unroll
      for (int ni = 0; ni < 8; ni++) {
        float e = __expf(lv[ni] - mx);
        lv[ni] = e;
        sum += e;
      }
#pragma unroll
      for (int off = 1; off < 16; off <<= 1) sum += __shfl_xor(sum, off);
      float inv = 1.f / sum;
      int sw = (qrow & 7) << 3;
#pragma unroll
      for (int ni = 0; ni < 8; ni++)
        pl[qrow * 128 + ((ni * 16 + lr) ^ sw)] = f2b(lv[ni] * inv);
    }
  // PV via MFMA over 128 keys (wave-private LDS: no barrier needed)
  f32x4 oc[2][2] = {};
#pragma unroll
  for (int ks = 0; ks < 4; ks++) {
    int kbase = ks * 32 + lg * 8;
    int kswz = kbase ^ ((lr & 7) << 3);
    bf16x8 ap0 = ld_bf8(pl + lr * 128 + kswz);
    bf16x8 ap1 = ld_bf8(pl + (16 + lr) * 128 + kswz);
    bf16x8 bv0 = ld_bf8(vt + lr * 128 + kswz);
    bf16x8 bv1 = ld_bf8(vt + (16 + lr) * 128 + kswz);
    mfma_bf16(oc[0][0], ap0, bv0);
    mfma_bf16(oc[0][1], ap0, bv1);
    mfma_bf16(oc[1][0], ap1, bv0);
    mfma_bf16(oc[1][1], ap1, bv1);
  }
#pragma unroll
  for (int mi = 0; mi < 2; mi++)
#pragma unroll
    for (int nd = 0; nd < 2; nd++)
#pragma unroll
      for (int r = 0; r < 4; r++) {
        int qrow = mi * 16 + lg * 4 + r;
        int d = nd * 16 + lr;
        size_t rowi = base + w * 32 + qrow;
        float gv = sigm(b2f(big1[rowi * 1024 + 768 + h * 32 + d]));
        o[rowi * 256 + h * 32 + d] = f2b(oc[mi][nd][r] * gv);
      }
}

// ---------------- temporal attention (T=8 per atom) ----------------
__global__ __launch_bounds__(256) void tattn_k(const unsigned short* __restrict__ big1,
                                               const float* __restrict__ ts,
                                               const float* __restrict__ tdec,
                                               unsigned short* __restrict__ o, int layer) {
  __shared__ __align__(16) unsigned short lds[4][8 * 768];
  int wid = threadIdx.x >> 6, lane = threadIdx.x & 63;
  int m = blockIdx.x * 4 + wid;
  unsigned short* Lp = lds[wid];
  for (int it = 0; it < 12; it++) {
    int u = it * 64 + lane;
    int t = u / 96, pos = (u % 96) * 8;
    *(uint4*)(Lp + t * 768 + pos) =
        *(const uint4*)(big1 + ((size_t)(t * M_ + m)) * 1024 + pos);
  }
  __syncthreads();
  int th = lane >> 3, qt = lane & 7;
  float decay = log1pf(__expf(tdec[layer * 8 + th]));
  float tsq = ts[qt];
  const float inv_t = 0.17677669529663687f;
  float tqv[32];
#pragma unroll
  for (int d = 0; d < 32; d++) tqv[d] = b2f(Lp[qt * 768 + th * 32 + d]);
  float lv[8];
  float mx = -3e38f;
#pragma unroll
  for (int kt = 0; kt < 8; kt++) {
    float dot = 0.f;
#pragma unroll
    for (int d = 0; d < 32; d++) dot += tqv[d] * b2f(Lp[kt * 768 + 256 + th * 32 + d]);
    float x = dot * inv_t - decay * fabsf(tsq - ts[kt]);
    lv[kt] = x;
    mx = fmaxf(mx, x);
  }
  float s = 0.f;
#pragma unroll
  for (int kt = 0; kt < 8; kt++) {
    float e = __expf(lv[kt] - mx);
    lv[kt] = e;
    s += e;
  }
  float inv = 1.f / s;
  float tov[32];
#pragma unroll
  for (int d = 0; d < 32; d++) tov[d] = 0.f;
#pragma unroll
  for (int kt = 0; kt < 8; kt++) {
    float p = lv[kt] * inv;
#pragma unroll
    for (int d = 0; d < 32; d++) tov[d] += p * b2f(Lp[kt * 768 + 512 + th * 32 + d]);
  }
  size_t orow = (size_t)qt * M_ + m;
#pragma unroll
  for (int d = 0; d < 32; d++) {
    float tg = sigm(b2f(big1[orow * 1024 + 768 + th * 32 + d]));
    o[orow * 256 + th * 32 + d] = f2b(tov[d] * tg);
  }
}

// ---------------- final: out = LN(qf, pos_g, pos_b) @ pos_w ----------------
__global__ __launch_bounds__(256) void final_k(const float* __restrict__ qf,
                                               const float* __restrict__ pg,
                                               const float* __restrict__ pb,
                                               const float* __restrict__ pw,
                                               float* __restrict__ out) {
  size_t row = (size_t)blockIdx.x * 4 + (threadIdx.x >> 6);
  int lane = threadIdx.x & 63;
  float4 v = ((const float4*)(qf + row * 256))[lane];
  float s = v.x + v.y + v.z + v.w;
#pragma unroll
  for (int o = 1; o < 64; o <<= 1) s += __shfl_xor(s, o);
  float mu = s * 0.00390625f;
  float dx = v.x - mu, dy = v.y - mu, dz = v.z - mu, dw = v.w - mu;
  float qv = dx * dx + dy * dy + dz * dz + dw * dw;
#pragma unroll
  for (int o = 1; o < 64; o <<= 1) qv += __shfl_xor(qv, o);
  float rs = rsqrtf(qv * 0.00390625f + 1e-5f);
  int d = lane * 4;
  float xn[4];
  xn[0] = dx * rs * pg[d] + pb[d];
  xn[1] = dy * rs * pg[d + 1] + pb[d + 1];
  xn[2] = dz * rs * pg[d + 2] + pb[d + 2];
  xn[3] = dw * rs * pg[d + 3] + pb[d + 3];
  float p0 = 0.f, p1 = 0.f, p2 = 0.f;
#pragma unroll
  for (int dd = 0; dd < 4; dd++) {
    const float* wr = pw + (size_t)(d + dd) * 3;
    p0 += xn[dd] * wr[0];
    p1 += xn[dd] * wr[1];
    p2 += xn[dd] * wr[2];
  }
#pragma unroll
  for (int o = 1; o < 64; o <<= 1) {
    p0 += __shfl_xor(p0, o);
    p1 += __shfl_xor(p1, o);
    p2 += __shfl_xor(p2, o);
  }
  if (lane == 0) {
    out[row * 3 + 0] = p0;
    out[row * 3 + 1] = p1;
    out[row * 3 + 2] = p2;
  }
}

extern "C" void kernel_launch(void* const* d_in, const int* in_sizes, int n_in,
                              void* d_out, int out_size, void* d_ws, size_t ws_size,
                              hipStream_t stream) {
  const float* a       = (const float*)d_in[0];
  const float* q_in    = (const float*)d_in[1];
  const float* c_in    = (const float*)d_in[2];
  const float* adb     = (const float*)d_in[3];
  const float* a2t     = (const float*)d_in[4];
  const float* ts      = (const float*)d_in[6];
  const float* W_a2q   = (const float*)d_in[7];
  const float* ada1_sw = (const float*)d_in[8];
  const float* ada1_sb = (const float*)d_in[9];
  const float* ada1_kw = (const float*)d_in[10];
  const float* attn_wq = (const float*)d_in[11];
  const float* attn_bq = (const float*)d_in[12];
  const float* attn_wk = (const float*)d_in[13];
  const float* attn_wv = (const float*)d_in[14];
  const float* attn_wg = (const float*)d_in[15];
  const float* attn_wo = (const float*)d_in[16];
  const float* og_w    = (const float*)d_in[17];
  const float* og_b    = (const float*)d_in[18];
  const float* ada2_sw = (const float*)d_in[19];
  const float* ada2_sb = (const float*)d_in[20];
  const float* ada2_kw = (const float*)d_in[21];
  const float* tr_w1   = (const float*)d_in[22];
  const float* tr_w2   = (const float*)d_in[23];
  const float* tr_w3   = (const float*)d_in[24];
  const float* tr_gw   = (const float*)d_in[25];
  const float* tr_gb   = (const float*)d_in[26];
  const float* t_ln_g  = (const float*)d_in[27];
  const float* t_ln_b  = (const float*)d_in[28];
  const float* t_wq    = (const float*)d_in[29];
  const float* t_wk    = (const float*)d_in[30];
  const float* t_wv    = (const float*)d_in[31];
  const float* t_wg    = (const float*)d_in[32];
  const float* t_wo    = (const float*)d_in[33];
  const float* t_dec   = (const float*)d_in[34];
  const float* pos_g   = (const float*)d_in[35];
  const float* pos_b   = (const float*)d_in[36];
  const float* pos_w   = (const float*)d_in[37];

  // ---- workspace layout (bytes), total ~236 MB ----
  char* base = (char*)d_ws;
  size_t off = 0;
  auto alloc = [&](size_t bytes) {
    void* p = base + off;
    off += (bytes + 255) & ~(size_t)255;
    return p;
  };
  float* qf            = (float*)alloc(Fq * 4);              // 32 MiB
  unsigned short* lncb = (unsigned short*)alloc(Fq * 2);     // 16 MiB
  unsigned short* Cb   = (unsigned short*)alloc(Fq * 4);     // 32 MiB: lnq|obuf / xbuf
  unsigned short* big1 = (unsigned short*)alloc(Fq * 8);     // 64 MiB: also tmpb/abf/tokf
  unsigned short* bbuf = (unsigned short*)alloc(Fq * 2);     // 16 MiB
  unsigned short* gates= (unsigned short*)alloc(Fq * 4);     // 32 MiB
  unsigned short* biasb= (unsigned short*)alloc((size_t)24 * 4096 * 128 * 2);  // 24 MiB
  unsigned short* wbf  = (unsigned short*)alloc((size_t)4718592 * 2);          // 9 MiB
  float* biasr         = (float*)alloc(8704 * 4);
  int* tokidx          = (int*)alloc(4096 * 4);

  unsigned short* lnqb = Cb;                 // R*256
  unsigned short* obuf = Cb + Fq;            // R*256
  unsigned short* xbuf = Cb;                 // R*512 (aliases lnq+obuf, disjoint in time)
  unsigned short* tmpb = big1;               // R*512 (dead before big1 written)
  unsigned short* abf  = big1;               // 8192*1536 (dead before layer 0)
  unsigned short* tokf = big1 + 2 * Fq;      // 8192*256

  // ---- weight transpose-convert descriptors ----
  ConvArgs ca;
  int ne = 0;
  auto add = [&](const float* s, size_t doff, int K, int N) {
    ca.src[ne] = s; ca.doff[ne] = (int)doff; ca.Kd[ne] = K; ca.Nd[ne] = N; ne++;
  };
  constexpr size_t LW = 1441792;
  for (int i = 0; i < 3; i++) {
    size_t LB = (size_t)i * LW;
    add(ada1_sw + i * 65536, LB + 0, 256, 256);
    add(ada1_kw + i * 65536, LB + 65536, 256, 256);
    add(attn_wq + i * 65536, LB + 131072, 256, 256);
    add(attn_wk + i * 65536, LB + 196608, 256, 256);
    add(attn_wv + i * 65536, LB + 262144, 256, 256);
    add(attn_wg + i * 65536, LB + 327680, 256, 256);
    add(attn_wo + i * 65536, LB + 393216, 256, 256);
    add(og_w + i * 65536, LB + 458752, 256, 256);
    add(tr_gw + i * 65536, LB + 524288, 256, 256);
    add(ada2_sw + i * 65536, LB + 589824, 256, 256);
    add(ada2_kw + i * 65536, LB + 655360, 256, 256);
    add(tr_w1 + i * 131072, LB + 720896, 256, 512);
    add(tr_w2 + i * 131072, LB + 851968, 256, 512);
    add(tr_w3 + i * 131072, LB + 983040, 512, 256);
    add(t_wq + i * 65536, LB + 1114112, 256, 256);
    add(t_wk + i * 65536, LB + 1179648, 256, 256);
    add(t_wv + i * 65536, LB + 1245184, 256, 256);
    add(t_wg + i * 65536, LB + 1310720, 256, 256);
    add(t_wo + i * 65536, LB + 1376256, 256, 256);
  }
  add(W_a2q, 3 * LW, 1536, 256);
  ca.n = ne;

  conv_k<<<dim3(ne, 96), 256, 0, stream>>>(ca, wbf);
  bias_prep_k<<<1, 256, 0, stream>>>(attn_bq, ada1_sb, ada2_sb, og_b, tr_gb, biasr);
  tokidx_k<<<1024, 256, 0, stream>>>(a2t, tokidx);
  biasb_k<<<4096, 256, 0, stream>>>(adb, biasb);
  cvt_k<<<6144, 256, 0, stream>>>(a, abf, 1572864);
  gemm2_k<1536, 1><<<dim3(64, 2), 256, 0, stream>>>(
      abf, wbf + 3 * LW, biasr, tokf, nullptr, nullptr, 0, 0, 256);
  qfinit_k<<<8192, 256, 0, stream>>>(q_in, tokf, tokidx, qf);
  ln_k<<<8192, 256, 0, stream>>>(c_in, lncb, nullptr, nullptr);

  for (int i = 0; i < 3; i++) {
    size_t LB = (size_t)i * LW;
    const float* b_attn = biasr + 1024 + (size_t)i * 2560;
    const float* b_ada1 = b_attn + 1024;
    const float* b_ada2 = b_attn + 1536;
    const float* b_ogtr = b_attn + 2048;

    // adaLN 1 -> b
    ln_k<<<8192, 256, 0, stream>>>(qf, lnqb, nullptr, nullptr);
    gemm2_k<256, 1><<<dim3(256, 4), 256, 0, stream>>>(
        lncb, wbf + LB, b_ada1, tmpb, nullptr, nullptr, 0, 0, 512);
    ew_adaln_k<<<8192, 256, 0, stream>>>(tmpb, lnqb, bbuf);
    // qkvg projections + spatial attention
    gemm2_k<256, 1><<<dim3(256, 8), 256, 0, stream>>>(
        bbuf, wbf + LB + 131072, b_attn, big1, nullptr, nullptr, 0, 0, 1024);
    attn_k<<<dim3(128, 8, 2), 256, 0, stream>>>(big1, biasb, obuf, i);
    // og | trg gates (A = c, fp32 direct path)
    gemmf_k<<<dim3(512, 8), 256, 0, stream>>>(
        c_in, wbf + LB + 458752, b_ogtr, gates, 512);
    // qf += sigmoid(og) * (o @ wo)
    gemm2_k<256, 2><<<dim3(256, 2), 256, 0, stream>>>(
        obuf, wbf + LB + 393216, biasr, nullptr, qf, gates, 512, 0, 256);
    // adaLN 2 -> t
    ln_k<<<8192, 256, 0, stream>>>(qf, lnqb, nullptr, nullptr);
    gemm2_k<256, 1><<<dim3(256, 4), 256, 0, stream>>>(
        lncb, wbf + LB + 589824, b_ada2, tmpb, nullptr, nullptr, 0, 0, 512);
    ew_adaln_k<<<8192, 256, 0, stream>>>(tmpb, lnqb, bbuf);
    // transition
    gemm2_k<256, 1><<<dim3(256, 8), 256, 0, stream>>>(
        bbuf, wbf + LB + 720896, biasr, big1, nullptr, nullptr, 0, 0, 1024);
    ew_silu_k<<<16384, 256, 0, stream>>>(big1, xbuf);
    gemm2_k<512, 2><<<dim3(256, 2), 256, 0, stream>>>(
        xbuf, wbf + LB + 983040, biasr, nullptr, qf, gates, 512, 256, 256);
    // temporal attention
    ln_k<<<8192, 256, 0, stream>>>(qf, lnqb, t_ln_g + (size_t)i * 256,
                                   t_ln_b + (size_t)i * 256);
    gemm2_k<256, 1><<<dim3(256, 8), 256, 0, stream>>>(
        lnqb, wbf + LB + 1114112, biasr, big1, nullptr, nullptr, 0, 0, 1024);
    tattn_k<<<1024, 256, 0, stream>>>(big1, ts, t_dec, obuf, i);
    gemm2_k<256, 3><<<dim3(256, 2), 256, 0, stream>>>(
        obuf, wbf + LB + 1376256, biasr, nullptr, qf, nullptr, 0, 0, 256);
  }
  final_k<<<8192, 256, 0, stream>>>(qf, pos_g, pos_b, pos_w, (float*)d_out);
}

// Round 3
// 1374.679 us; speedup vs baseline: 2.8477x; 1.1427x over previous
//
#include <hip/hip_runtime.h>
#include <cstddef>
#include <cstdint>

#define DEVI __device__ __forceinline__

typedef __attribute__((ext_vector_type(8))) __bf16 bf16x8;
typedef __attribute__((ext_vector_type(8))) unsigned short us8;
typedef __attribute__((ext_vector_type(4))) unsigned short us4;
typedef __attribute__((ext_vector_type(4))) float f32x4;

constexpr int B0_ = 1, T_ = 8, N_ = 1024, M_ = 4096, D_ = 256;
constexpr int BT_ = 8, NW_ = 128, WQ_ = 32, HK_ = 128, SIDE_ = 48;
constexpr int R_ = BT_ * M_;          // 32768 rows
constexpr size_t Fq = 8388608;        // R_*256 elements

DEVI unsigned short f2b(float f) {
  unsigned u = __float_as_uint(f);
  u = (u + 0x7FFFu + ((u >> 16) & 1u)) >> 16;
  return (unsigned short)u;
}
DEVI float b2f(unsigned short s) { return __uint_as_float(((unsigned)s) << 16); }
DEVI float sigm(float x) { return 1.0f / (1.0f + __expf(-x)); }
DEVI bf16x8 ld_bf8(const unsigned short* p) {
  return __builtin_bit_cast(bf16x8, *(const us8*)p);
}
DEVI bf16x8 pack_f8(float4 v0, float4 v1) {
  us8 t;
  t[0] = f2b(v0.x); t[1] = f2b(v0.y); t[2] = f2b(v0.z); t[3] = f2b(v0.w);
  t[4] = f2b(v1.x); t[5] = f2b(v1.y); t[6] = f2b(v1.z); t[7] = f2b(v1.w);
  return __builtin_bit_cast(bf16x8, t);
}
DEVI void mfma_bf16(f32x4& c, bf16x8 a, bf16x8 b) {
  c = __builtin_amdgcn_mfma_f32_16x16x32_bf16(a, b, c, 0, 0, 0);
}
// async global->LDS, 16B per lane; lds dest = wave-uniform base + lane*16
DEVI void gload16(const void* g, void* l) {
  __builtin_amdgcn_global_load_lds((__attribute__((address_space(1))) void*)g,
                                   (__attribute__((address_space(3))) void*)l, 16, 0, 0);
}

// ---------------- weight transpose-convert (fp32 [K][N] -> bf16 Wt[N][K]) ----
struct ConvArgs {
  const float* src[64];
  int doff[64];
  int Kd[64];
  int Nd[64];
  int n;
};

__global__ __launch_bounds__(256) void conv_k(ConvArgs ca, unsigned short* __restrict__ wbf) {
  int e = blockIdx.x;
  int K = ca.Kd[e], N = ca.Nd[e];
  int nx = N >> 6, nk = K >> 6;
  int t = blockIdx.y;
  if (t >= nx * nk) return;
  int tx = t % nx, tk = t / nx;
  const float* s = ca.src[e];
  unsigned short* d = wbf + ca.doff[e];
  int n = tx * 64 + (threadIdx.x & 63);
  int k0 = tk * 64 + (threadIdx.x >> 6) * 16;
  for (int r = 0; r < 16; r++) {
    int k = k0 + r;
    d[(size_t)n * K + k] = f2b(s[(size_t)k * N + n]);
  }
}

// ---------------- fp32 -> bf16 flat convert ----------------
__global__ __launch_bounds__(256) void cvt_k(const float* __restrict__ s,
                                             unsigned short* __restrict__ d, int n8) {
  int i = blockIdx.x * 256 + threadIdx.x;
  if (i >= n8) return;
  float4 v0 = *(const float4*)(s + (size_t)i * 8);
  float4 v1 = *(const float4*)(s + (size_t)i * 8 + 4);
  *(us8*)(d + (size_t)i * 8) = __builtin_bit_cast(us8, pack_f8(v0, v1));
}

// ---------------- bias concat prep ----------------
__global__ __launch_bounds__(256) void bias_prep_k(
    const float* __restrict__ bq, const float* __restrict__ sb1,
    const float* __restrict__ sb2, const float* __restrict__ ogb,
    const float* __restrict__ trb, float* __restrict__ bias) {
  int t = threadIdx.x;
  for (int i = t; i < 1024 + 3 * 2560; i += 256) bias[i] = 0.f;
  __syncthreads();
  for (int i = 0; i < 3; i++) {
    float* B = bias + 1024 + i * 2560;
    B[t]        = bq[i * 256 + t];
    B[1024 + t] = sb1[i * 256 + t];
    B[1536 + t] = sb2[i * 256 + t];
    B[2048 + t] = ogb[i * 256 + t];
    B[2304 + t] = trb[i * 256 + t];
  }
}

// ---------------- attn bias relayout -> biasb[(l*8+h)][row][k] bf16 ----------
__global__ __launch_bounds__(256) void biasb_k(const float* __restrict__ adb,
                                               unsigned short* __restrict__ biasb) {
  __shared__ float ld[3072];
  int rq = blockIdx.x;  // 0..4095
  int t = threadIdx.x;
  const float* src = adb + (size_t)rq * 3072;
  for (int i = t; i < 3072; i += 256) ld[i] = src[i];
  __syncthreads();
  int k = t & 127;
  for (int lh = t >> 7; lh < 24; lh += 2)
    biasb[((size_t)lh * 4096 + rq) * 128 + k] = f2b(ld[k * 24 + lh]);
}

// ---------------- tok idx from one-hot ----------------
__global__ __launch_bounds__(256) void tokidx_k(const float* __restrict__ a2t,
                                                int* __restrict__ idx) {
  int m = blockIdx.x * 4 + (threadIdx.x >> 6);
  int lane = threadIdx.x & 63;
  int best = -1;
  for (int j = 0; j < 16; j++) {
    int col = lane * 16 + j;
    if (a2t[(size_t)m * 1024 + col] > 0.5f) best = col;
  }
#pragma unroll
  for (int off = 1; off < 64; off <<= 1) best = max(best, __shfl_xor(best, off));
  if (lane == 0) idx[m] = best;
}

// ---------------- qf = q + tokfeat[gather] (tokf bf16) ----------------
__global__ __launch_bounds__(256) void qfinit_k(const float* __restrict__ q,
                                                const unsigned short* __restrict__ tokf,
                                                const int* __restrict__ idx,
                                                float* __restrict__ qf) {
  size_t e = ((size_t)blockIdx.x * 256 + threadIdx.x) * 4;
  size_t row = e >> 8;
  int col = (int)(e & 255);
  int m = (int)(row & 4095);
  int bt = (int)(row >> 12);
  float4 qv = *(const float4*)(q + row * 256 + col);
  us4 tv = *(const us4*)(tokf + ((size_t)bt * 1024 + idx[m]) * 256 + col);
  float4 r;
  r.x = qv.x + b2f(tv[0]); r.y = qv.y + b2f(tv[1]);
  r.z = qv.z + b2f(tv[2]); r.w = qv.w + b2f(tv[3]);
  *(float4*)(qf + row * 256 + col) = r;
}

// ---------------- rowwise LayerNorm over 256, fp32 in -> bf16 out ----------
__global__ __launch_bounds__(256) void ln_k(const float* __restrict__ src,
                                            unsigned short* __restrict__ dst,
                                            const float* __restrict__ g,
                                            const float* __restrict__ b) {
  size_t row = (size_t)blockIdx.x * 4 + (threadIdx.x >> 6);
  int lane = threadIdx.x & 63;
  float4 v = ((const float4*)(src + row * 256))[lane];
  float s = v.x + v.y + v.z + v.w;
#pragma unroll
  for (int o = 1; o < 64; o <<= 1) s += __shfl_xor(s, o);
  float mu = s * 0.00390625f;
  float dx = v.x - mu, dy = v.y - mu, dz = v.z - mu, dw = v.w - mu;
  float qv = dx * dx + dy * dy + dz * dz + dw * dw;
#pragma unroll
  for (int o = 1; o < 64; o <<= 1) qv += __shfl_xor(qv, o);
  float rs = rsqrtf(qv * 0.00390625f + 1e-5f);
  float ov[4] = {dx * rs, dy * rs, dz * rs, dw * rs};
  if (g) {
    int d = lane * 4;
#pragma unroll
    for (int j = 0; j < 4; j++) ov[j] = ov[j] * g[d + j] + b[d + j];
  }
  us4 r;
#pragma unroll
  for (int j = 0; j < 4; j++) r[j] = f2b(ov[j]);
  *(us4*)(dst + row * 256 + lane * 4) = r;
}

// ---------------- staged GEMM: 128x128 tile, BK=64, XOR-swizzled LDS --------
// EP1: out=bf16(acc+bias); EP2: qf += sigmoid(gate)*acc; EP3: qf += acc
// EP4: bbuf = sigmoid(acc_s+bias)*lnq + (acc_k+bias2)    [dual tile, PAIR=256]
// EP5: xbuf = silu(acc_1+bias)*(acc_2+bias2)             [dual tile, PAIR=512]
// Swizzle: LDS slot (row, chunk c) holds global chunk c ^ (row&7); stage
// pre-permutes the per-lane GLOBAL column, dest stays linear (gload_lds rule).
template <int K, int EP>
__global__ __launch_bounds__(256) void gemm3_k(
    const unsigned short* __restrict__ A, const unsigned short* __restrict__ Wt,
    const float* __restrict__ bias, unsigned short* __restrict__ out,
    float* __restrict__ qf, const unsigned short* __restrict__ gate,
    int gstride, int goff, int NOUT, const unsigned short* __restrict__ lnq) {
  constexpr bool DUAL = (EP == 4 || EP == 5);
  constexpr int PAIR = (EP == 4) ? 256 : (EP == 5 ? 512 : 0);
  __shared__ __align__(16) unsigned short As[128 * 64];
  __shared__ __align__(16) unsigned short Bs[128 * 64];
  __shared__ __align__(16) unsigned short Bs2[DUAL ? 128 * 64 : 8];
  const int tid = threadIdx.x;
  const int lane = tid & 63, w = tid >> 6;
  const int lg = lane >> 4, lr = lane & 15;
  const int wr = w >> 1, wc = w & 1;
  const size_t m_base = (size_t)blockIdx.x * 128;
  const size_t n_base = (size_t)blockIdx.y * 128;
  // staging: wave w covers rows w*8..w*8+7 (+j*32); global col pre-swizzled
  const int srow = w * 8 + (lane >> 3);
  const int scol = ((lane & 7) ^ (lane >> 3)) * 8;
  const unsigned short* gA = A + (m_base + srow) * K + scol;
  const unsigned short* gB = Wt + (n_base + srow) * K + scol;
  const unsigned short* gB2 = Wt + (n_base + PAIR + srow) * K + scol;
  f32x4 acc[4][4] = {};
  f32x4 acc2[DUAL ? 4 : 1][DUAL ? 4 : 1] = {};
  const int swz = (lr & 7);
  for (int kk = 0; kk < K; kk += 64) {
#pragma unroll
    for (int j = 0; j < 4; j++) gload16(gA + (size_t)j * 32 * K + kk, As + w * 512 + j * 2048);
#pragma unroll
    for (int j = 0; j < 4; j++) gload16(gB + (size_t)j * 32 * K + kk, Bs + w * 512 + j * 2048);
    if constexpr (DUAL) {
#pragma unroll
      for (int j = 0; j < 4; j++) gload16(gB2 + (size_t)j * 32 * K + kk, Bs2 + w * 512 + j * 2048);
    }
    __syncthreads();
#pragma unroll
    for (int ks = 0; ks < 2; ks++) {
      const int co = ((ks * 4 + lg) ^ swz) << 3;
      bf16x8 af[4], bf1[4], bf2[4];
#pragma unroll
      for (int i = 0; i < 4; i++) {
        af[i] = ld_bf8(As + (wr * 64 + i * 16 + lr) * 64 + co);
        bf1[i] = ld_bf8(Bs + (wc * 64 + i * 16 + lr) * 64 + co);
        if constexpr (DUAL) bf2[i] = ld_bf8(Bs2 + (wc * 64 + i * 16 + lr) * 64 + co);
      }
#pragma unroll
      for (int mi = 0; mi < 4; mi++)
#pragma unroll
        for (int ni = 0; ni < 4; ni++) {
          mfma_bf16(acc[mi][ni], af[mi], bf1[ni]);
          if constexpr (DUAL) mfma_bf16(acc2[mi][ni], af[mi], bf2[ni]);
        }
    }
    __syncthreads();
  }
#pragma unroll
  for (int mi = 0; mi < 4; mi++)
#pragma unroll
    for (int ni = 0; ni < 4; ni++)
#pragma unroll
      for (int r = 0; r < 4; r++) {
        size_t row = m_base + wr * 64 + mi * 16 + lg * 4 + r;
        int col = (int)n_base + wc * 64 + ni * 16 + lr;
        if constexpr (EP == 1) {
          out[row * NOUT + col] = f2b(acc[mi][ni][r] + bias[col]);
        } else if constexpr (EP == 2) {
          float v = acc[mi][ni][r] + bias[col];
          float g = sigm(b2f(gate[row * gstride + goff + col]));
          qf[row * 256 + col] += g * v;
        } else if constexpr (EP == 3) {
          qf[row * 256 + col] += acc[mi][ni][r] + bias[col];
        } else if constexpr (EP == 4) {
          float vs = acc[mi][ni][r] + bias[col];
          float vk = acc2[mi][ni][r] + bias[col + 256];
          out[row * 256 + col] = f2b(sigm(vs) * b2f(lnq[row * 256 + col]) + vk);
        } else {  // EP5
          float v1 = acc[mi][ni][r] + bias[col];
          float v2 = acc2[mi][ni][r] + bias[col + 512];
          out[row * 512 + col] = f2b(v1 * sigm(v1) * v2);
        }
      }
}

// ---------------- windowed spatial attention ----------------
__global__ __launch_bounds__(256) void attn_k(const unsigned short* __restrict__ big1,
                                              const unsigned short* __restrict__ biasb,
                                              unsigned short* __restrict__ o, int layer) {
  __shared__ __align__(16) unsigned short pl_s[4][32 * 128];
  __shared__ __align__(16) unsigned short vt_s[4][32 * 128];
  const int w = blockIdx.x, bt = blockIdx.y, hg = blockIdx.z;
  const int tid = threadIdx.x, wid = tid >> 6, lane = tid & 63;
  const int lg = lane >> 4, lr = lane & 15;
  const int h = hg * 4 + wid;
  unsigned short* pl = pl_s[wid];
  unsigned short* vt = vt_s[wid];
  const size_t base = (size_t)bt * M_;
  const float inv_s = 0.17677669529663687f;

  // stage V^T (coalesced 16B global reads, swizzled LDS writes)
  {
    const int chunk = lane & 3;
    const int krow = lane >> 2;
#pragma unroll
    for (int it = 0; it < 8; it++) {
      int key = it * 16 + krow;
      int ak = w * 32 - SIDE_ + key;
      int akc = ak < 0 ? 0 : (ak > M_ - 1 ? M_ - 1 : ak);
      us8 v = *(const us8*)(big1 + (base + akc) * 1024 + 512 + h * 32 + chunk * 8);
#pragma unroll
      for (int e = 0; e < 8; e++) {
        int d = chunk * 8 + e;
        vt[d * 128 + (key ^ ((d & 7) << 3))] = v[e];
      }
    }
  }
  // QK^T via MFMA (K-dim = dh = 32)
  bf16x8 aq[2];
#pragma unroll
  for (int mi = 0; mi < 2; mi++)
    aq[mi] = ld_bf8(big1 + (base + w * 32 + mi * 16 + lr) * 1024 + h * 32 + lg * 8);
  f32x4 lac[2][8] = {};
#pragma unroll
  for (int ni = 0; ni < 8; ni++) {
    int kidx = ni * 16 + lr;
    int ak = w * 32 - SIDE_ + kidx;
    int akc = ak < 0 ? 0 : (ak > M_ - 1 ? M_ - 1 : ak);
    bf16x8 bk = ld_bf8(big1 + (base + akc) * 1024 + 256 + h * 32 + lg * 8);
    mfma_bf16(lac[0][ni], aq[0], bk);
    mfma_bf16(lac[1][ni], aq[1], bk);
  }
  // bias + mask + softmax; p -> swizzled LDS
  const unsigned short* brow0 =
      biasb + (((size_t)(layer * 8 + h)) * 4096 + w * 32) * 128;
#pragma unroll
  for (int mi = 0; mi < 2; mi++)
#pragma unroll
    for (int r = 0; r < 4; r++) {
      int qrow = mi * 16 + lg * 4 + r;
      const unsigned short* brow = brow0 + (size_t)qrow * 128;
      float lv[8];
      float mx = -3e38f;
#pragma unroll
      for (int ni = 0; ni < 8; ni++) {
        int kidx = ni * 16 + lr;
        int ak = w * 32 - SIDE_ + kidx;
        float x = lac[mi][ni][r] * inv_s + b2f(brow[kidx]) +
                  ((unsigned)ak < (unsigned)M_ ? 0.f : -1e9f);
        lv[ni] = x;
        mx = fmaxf(mx, x);
      }
#pragma unroll
      for (int off = 1; off < 16; off <<= 1) mx = fmaxf(mx, __shfl_xor(mx, off));
      float sum = 0.f;
#pragma unroll
      for (int ni = 0; ni < 8; ni++) {
        float e = __expf(lv[ni] - mx);
        lv[ni] = e;
        sum += e;
      }
#pragma unroll
      for (int off = 1; off < 16; off <<= 1) sum += __shfl_xor(sum, off);
      float inv = 1.f / sum;
      int sw = (qrow & 7) << 3;
#pragma unroll
      for (int ni = 0; ni < 8; ni++)
        pl[qrow * 128 + ((ni * 16 + lr) ^ sw)] = f2b(lv[ni] * inv);
    }
  // PV via MFMA over 128 keys (wave-private LDS: no barrier needed)
  f32x4 oc[2][2] = {};
#pragma unroll
  for (int ks = 0; ks < 4; ks++) {
    int kbase = ks * 32 + lg * 8;
    int kswz = kbase ^ ((lr & 7) << 3);
    bf16x8 ap0 = ld_bf8(pl + lr * 128 + kswz);
    bf16x8 ap1 = ld_bf8(pl + (16 + lr) * 128 + kswz);
    bf16x8 bv0 = ld_bf8(vt + lr * 128 + kswz);
    bf16x8 bv1 = ld_bf8(vt + (16 + lr) * 128 + kswz);
    mfma_bf16(oc[0][0], ap0, bv0);
    mfma_bf16(oc[0][1], ap0, bv1);
    mfma_bf16(oc[1][0], ap1, bv0);
    mfma_bf16(oc[1][1], ap1, bv1);
  }
#pragma unroll
  for (int mi = 0; mi < 2; mi++)
#pragma unroll
    for (int nd = 0; nd < 2; nd++)
#pragma unroll
      for (int r = 0; r < 4; r++) {
        int qrow = mi * 16 + lg * 4 + r;
        int d = nd * 16 + lr;
        size_t rowi = base + w * 32 + qrow;
        float gv = sigm(b2f(big1[rowi * 1024 + 768 + h * 32 + d]));
        o[rowi * 256 + h * 32 + d] = f2b(oc[mi][nd][r] * gv);
      }
}

// ---------------- temporal attention (T=8 per atom) ----------------
__global__ __launch_bounds__(256) void tattn_k(const unsigned short* __restrict__ big1,
                                               const float* __restrict__ ts,
                                               const float* __restrict__ tdec,
                                               unsigned short* __restrict__ o, int layer) {
  __shared__ __align__(16) unsigned short lds[4][8 * 768];
  int wid = threadIdx.x >> 6, lane = threadIdx.x & 63;
  int m = blockIdx.x * 4 + wid;
  unsigned short* Lp = lds[wid];
  for (int it = 0; it < 12; it++) {
    int u = it * 64 + lane;
    int t = u / 96, pos = (u % 96) * 8;
    *(uint4*)(Lp + t * 768 + pos) =
        *(const uint4*)(big1 + ((size_t)(t * M_ + m)) * 1024 + pos);
  }
  __syncthreads();
  int th = lane >> 3, qt = lane & 7;
  float decay = log1pf(__expf(tdec[layer * 8 + th]));
  float tsq = ts[qt];
  const float inv_t = 0.17677669529663687f;
  float tqv[32];
#pragma unroll
  for (int d = 0; d < 32; d++) tqv[d] = b2f(Lp[qt * 768 + th * 32 + d]);
  float lv[8];
  float mx = -3e38f;
#pragma unroll
  for (int kt = 0; kt < 8; kt++) {
    float dot = 0.f;
#pragma unroll
    for (int d = 0; d < 32; d++) dot += tqv[d] * b2f(Lp[kt * 768 + 256 + th * 32 + d]);
    float x = dot * inv_t - decay * fabsf(tsq - ts[kt]);
    lv[kt] = x;
    mx = fmaxf(mx, x);
  }
  float s = 0.f;
#pragma unroll
  for (int kt = 0; kt < 8; kt++) {
    float e = __expf(lv[kt] - mx);
    lv[kt] = e;
    s += e;
  }
  float inv = 1.f / s;
  float tov[32];
#pragma unroll
  for (int d = 0; d < 32; d++) tov[d] = 0.f;
#pragma unroll
  for (int kt = 0; kt < 8; kt++) {
    float p = lv[kt] * inv;
#pragma unroll
    for (int d = 0; d < 32; d++) tov[d] += p * b2f(Lp[kt * 768 + 512 + th * 32 + d]);
  }
  size_t orow = (size_t)qt * M_ + m;
#pragma unroll
  for (int d = 0; d < 32; d++) {
    float tg = sigm(b2f(big1[orow * 1024 + 768 + th * 32 + d]));
    o[orow * 256 + th * 32 + d] = f2b(tov[d] * tg);
  }
}

// ---------------- final: out = LN(qf, pos_g, pos_b) @ pos_w ----------------
__global__ __launch_bounds__(256) void final_k(const float* __restrict__ qf,
                                               const float* __restrict__ pg,
                                               const float* __restrict__ pb,
                                               const float* __restrict__ pw,
                                               float* __restrict__ out) {
  size_t row = (size_t)blockIdx.x * 4 + (threadIdx.x >> 6);
  int lane = threadIdx.x & 63;
  float4 v = ((const float4*)(qf + row * 256))[lane];
  float s = v.x + v.y + v.z + v.w;
#pragma unroll
  for (int o = 1; o < 64; o <<= 1) s += __shfl_xor(s, o);
  float mu = s * 0.00390625f;
  float dx = v.x - mu, dy = v.y - mu, dz = v.z - mu, dw = v.w - mu;
  float qv = dx * dx + dy * dy + dz * dz + dw * dw;
#pragma unroll
  for (int o = 1; o < 64; o <<= 1) qv += __shfl_xor(qv, o);
  float rs = rsqrtf(qv * 0.00390625f + 1e-5f);
  int d = lane * 4;
  float xn[4];
  xn[0] = dx * rs * pg[d] + pb[d];
  xn[1] = dy * rs * pg[d + 1] + pb[d + 1];
  xn[2] = dz * rs * pg[d + 2] + pb[d + 2];
  xn[3] = dw * rs * pg[d + 3] + pb[d + 3];
  float p0 = 0.f, p1 = 0.f, p2 = 0.f;
#pragma unroll
  for (int dd = 0; dd < 4; dd++) {
    const float* wr = pw + (size_t)(d + dd) * 3;
    p0 += xn[dd] * wr[0];
    p1 += xn[dd] * wr[1];
    p2 += xn[dd] * wr[2];
  }
#pragma unroll
  for (int o = 1; o < 64; o <<= 1) {
    p0 += __shfl_xor(p0, o);
    p1 += __shfl_xor(p1, o);
    p2 += __shfl_xor(p2, o);
  }
  if (lane == 0) {
    out[row * 3 + 0] = p0;
    out[row * 3 + 1] = p1;
    out[row * 3 + 2] = p2;
  }
}

extern "C" void kernel_launch(void* const* d_in, const int* in_sizes, int n_in,
                              void* d_out, int out_size, void* d_ws, size_t ws_size,
                              hipStream_t stream) {
  const float* a       = (const float*)d_in[0];
  const float* q_in    = (const float*)d_in[1];
  const float* c_in    = (const float*)d_in[2];
  const float* adb     = (const float*)d_in[3];
  const float* a2t     = (const float*)d_in[4];
  const float* ts      = (const float*)d_in[6];
  const float* W_a2q   = (const float*)d_in[7];
  const float* ada1_sw = (const float*)d_in[8];
  const float* ada1_sb = (const float*)d_in[9];
  const float* ada1_kw = (const float*)d_in[10];
  const float* attn_wq = (const float*)d_in[11];
  const float* attn_bq = (const float*)d_in[12];
  const float* attn_wk = (const float*)d_in[13];
  const float* attn_wv = (const float*)d_in[14];
  const float* attn_wg = (const float*)d_in[15];
  const float* attn_wo = (const float*)d_in[16];
  const float* og_w    = (const float*)d_in[17];
  const float* og_b    = (const float*)d_in[18];
  const float* ada2_sw = (const float*)d_in[19];
  const float* ada2_sb = (const float*)d_in[20];
  const float* ada2_kw = (const float*)d_in[21];
  const float* tr_w1   = (const float*)d_in[22];
  const float* tr_w2   = (const float*)d_in[23];
  const float* tr_w3   = (const float*)d_in[24];
  const float* tr_gw   = (const float*)d_in[25];
  const float* tr_gb   = (const float*)d_in[26];
  const float* t_ln_g  = (const float*)d_in[27];
  const float* t_ln_b  = (const float*)d_in[28];
  const float* t_wq    = (const float*)d_in[29];
  const float* t_wk    = (const float*)d_in[30];
  const float* t_wv    = (const float*)d_in[31];
  const float* t_wg    = (const float*)d_in[32];
  const float* t_wo    = (const float*)d_in[33];
  const float* t_dec   = (const float*)d_in[34];
  const float* pos_g   = (const float*)d_in[35];
  const float* pos_b   = (const float*)d_in[36];
  const float* pos_w   = (const float*)d_in[37];

  // ---- workspace layout (same footprint as round 2, ~225 MB) ----
  char* base = (char*)d_ws;
  size_t off = 0;
  auto alloc = [&](size_t bytes) {
    void* p = base + off;
    off += (bytes + 255) & ~(size_t)255;
    return p;
  };
  float* qf            = (float*)alloc(Fq * 4);              // 32 MiB
  unsigned short* lncb = (unsigned short*)alloc(Fq * 2);     // 16 MiB
  unsigned short* Cb   = (unsigned short*)alloc(Fq * 4);     // 32 MiB: lnq|obuf / xbuf
  unsigned short* big1 = (unsigned short*)alloc(Fq * 8);     // 64 MiB: also abf/tokf
  unsigned short* bbuf = (unsigned short*)alloc(Fq * 2);     // 16 MiB: cbf / adaln-out
  unsigned short* gates= (unsigned short*)alloc(Fq * 4);     // 32 MiB
  unsigned short* biasb= (unsigned short*)alloc((size_t)24 * 4096 * 128 * 2);  // 24 MiB
  unsigned short* wbf  = (unsigned short*)alloc((size_t)4718592 * 2);          // 9 MiB
  float* biasr         = (float*)alloc(8704 * 4);
  int* tokidx          = (int*)alloc(4096 * 4);

  unsigned short* lnqb = Cb;                 // R*256
  unsigned short* obuf = Cb + Fq;            // R*256
  unsigned short* xbuf = Cb;                 // R*512 (aliases lnq+obuf, disjoint in time)
  unsigned short* abf  = big1;               // 8192*1536 (dead before layer 0)
  unsigned short* tokf = big1 + 2 * Fq;      // 8192*256

  // ---- weight transpose-convert descriptors ----
  ConvArgs ca;
  int ne = 0;
  auto add = [&](const float* s, size_t doff, int K, int N) {
    ca.src[ne] = s; ca.doff[ne] = (int)doff; ca.Kd[ne] = K; ca.Nd[ne] = N; ne++;
  };
  constexpr size_t LW = 1441792;
  for (int i = 0; i < 3; i++) {
    size_t LB = (size_t)i * LW;
    add(ada1_sw + i * 65536, LB + 0, 256, 256);
    add(ada1_kw + i * 65536, LB + 65536, 256, 256);
    add(attn_wq + i * 65536, LB + 131072, 256, 256);
    add(attn_wk + i * 65536, LB + 196608, 256, 256);
    add(attn_wv + i * 65536, LB + 262144, 256, 256);
    add(attn_wg + i * 65536, LB + 327680, 256, 256);
    add(attn_wo + i * 65536, LB + 393216, 256, 256);
    add(og_w + i * 65536, LB + 458752, 256, 256);
    add(tr_gw + i * 65536, LB + 524288, 256, 256);
    add(ada2_sw + i * 65536, LB + 589824, 256, 256);
    add(ada2_kw + i * 65536, LB + 655360, 256, 256);
    add(tr_w1 + i * 131072, LB + 720896, 256, 512);
    add(tr_w2 + i * 131072, LB + 851968, 256, 512);
    add(tr_w3 + i * 131072, LB + 983040, 512, 256);
    add(t_wq + i * 65536, LB + 1114112, 256, 256);
    add(t_wk + i * 65536, LB + 1179648, 256, 256);
    add(t_wv + i * 65536, LB + 1245184, 256, 256);
    add(t_wg + i * 65536, LB + 1310720, 256, 256);
    add(t_wo + i * 65536, LB + 1376256, 256, 256);
  }
  add(W_a2q, 3 * LW, 1536, 256);
  ca.n = ne;

  conv_k<<<dim3(ne, 96), 256, 0, stream>>>(ca, wbf);
  bias_prep_k<<<1, 256, 0, stream>>>(attn_bq, ada1_sb, ada2_sb, og_b, tr_gb, biasr);
  tokidx_k<<<1024, 256, 0, stream>>>(a2t, tokidx);
  biasb_k<<<4096, 256, 0, stream>>>(adb, biasb);
  cvt_k<<<6144, 256, 0, stream>>>(a, abf, 1572864);
  gemm3_k<1536, 1><<<dim3(64, 2), 256, 0, stream>>>(
      abf, wbf + 3 * LW, biasr, tokf, nullptr, nullptr, 0, 0, 256, nullptr);
  qfinit_k<<<8192, 256, 0, stream>>>(q_in, tokf, tokidx, qf);
  ln_k<<<8192, 256, 0, stream>>>(c_in, lncb, nullptr, nullptr);

  for (int i = 0; i < 3; i++) {
    size_t LB = (size_t)i * LW;
    const float* b_attn = biasr + 1024 + (size_t)i * 2560;
    const float* b_ada1 = b_attn + 1024;
    const float* b_ada2 = b_attn + 1536;
    const float* b_ogtr = b_attn + 2048;

    // gates = sigmoid-pre of [c@og_w+og_b | c@tr_gw+tr_gb]  (c -> bf16 first)
    cvt_k<<<4096, 256, 0, stream>>>(c_in, bbuf, 1048576);
    gemm3_k<256, 1><<<dim3(256, 4), 256, 0, stream>>>(
        bbuf, wbf + LB + 458752, b_ogtr, gates, nullptr, nullptr, 0, 0, 512, nullptr);
    // adaLN 1 -> bbuf (fused combine)
    ln_k<<<8192, 256, 0, stream>>>(qf, lnqb, nullptr, nullptr);
    gemm3_k<256, 4><<<dim3(256, 2), 256, 0, stream>>>(
        lncb, wbf + LB, b_ada1, bbuf, nullptr, nullptr, 0, 0, 256, lnqb);
    // qkvg projections + spatial attention
    gemm3_k<256, 1><<<dim3(256, 8), 256, 0, stream>>>(
        bbuf, wbf + LB + 131072, b_attn, big1, nullptr, nullptr, 0, 0, 1024, nullptr);
    attn_k<<<dim3(128, 8, 2), 256, 0, stream>>>(big1, biasb, obuf, i);
    // qf += sigmoid(og) * (o @ wo)
    gemm3_k<256, 2><<<dim3(256, 2), 256, 0, stream>>>(
        obuf, wbf + LB + 393216, biasr, nullptr, qf, gates, 512, 0, 256, nullptr);
    // adaLN 2 -> bbuf
    ln_k<<<8192, 256, 0, stream>>>(qf, lnqb, nullptr, nullptr);
    gemm3_k<256, 4><<<dim3(256, 2), 256, 0, stream>>>(
        lncb, wbf + LB + 589824, b_ada2, bbuf, nullptr, nullptr, 0, 0, 256, lnqb);
    // transition: xbuf = silu(t@w1)*(t@w2) fused, then qf += sig(trg)*(x@w3)
    gemm3_k<256, 5><<<dim3(256, 4), 256, 0, stream>>>(
        bbuf, wbf + LB + 720896, biasr, xbuf, nullptr, nullptr, 0, 0, 512, nullptr);
    gemm3_k<512, 2><<<dim3(256, 2), 256, 0, stream>>>(
        xbuf, wbf + LB + 983040, biasr, nullptr, qf, gates, 512, 256, 256, nullptr);
    // temporal attention
    ln_k<<<8192, 256, 0, stream>>>(qf, lnqb, t_ln_g + (size_t)i * 256,
                                   t_ln_b + (size_t)i * 256);
    gemm3_k<256, 1><<<dim3(256, 8), 256, 0, stream>>>(
        lnqb, wbf + LB + 1114112, biasr, big1, nullptr, nullptr, 0, 0, 1024, nullptr);
    tattn_k<<<1024, 256, 0, stream>>>(big1, ts, t_dec, obuf, i);
    gemm3_k<256, 3><<<dim3(256, 2), 256, 0, stream>>>(
        obuf, wbf + LB + 1376256, biasr, nullptr, qf, nullptr, 0, 0, 256, nullptr);
  }
  final_k<<<8192, 256, 0, stream>>>(qf, pos_g, pos_b, pos_w, (float*)d_out);
}

// Round 4
// 1318.771 us; speedup vs baseline: 2.9685x; 1.0424x over previous
//
#include <hip/hip_runtime.h>
#include <cstddef>
#include <cstdint>

#define DEVI __device__ __forceinline__

typedef __attribute__((ext_vector_type(8))) __bf16 bf16x8;
typedef __attribute__((ext_vector_type(8))) unsigned short us8;
typedef __attribute__((ext_vector_type(4))) unsigned short us4;
typedef __attribute__((ext_vector_type(4))) float f32x4;

constexpr int B0_ = 1, T_ = 8, N_ = 1024, M_ = 4096, D_ = 256;
constexpr int BT_ = 8, NW_ = 128, WQ_ = 32, HK_ = 128, SIDE_ = 48;
constexpr int R_ = BT_ * M_;          // 32768 rows
constexpr size_t Fq = 8388608;        // R_*256 elements

DEVI unsigned short f2b(float f) {
  return __builtin_bit_cast(unsigned short, static_cast<__bf16>(f));
}
DEVI float b2f(unsigned short s) { return __uint_as_float(((unsigned)s) << 16); }
DEVI float sigm(float x) { return 1.0f / (1.0f + __expf(-x)); }
DEVI bf16x8 ld_bf8(const unsigned short* p) {
  return __builtin_bit_cast(bf16x8, *(const us8*)p);
}
DEVI bf16x8 pack_f8(float4 v0, float4 v1) {
  bf16x8 r;
  r[0] = (__bf16)v0.x; r[1] = (__bf16)v0.y; r[2] = (__bf16)v0.z; r[3] = (__bf16)v0.w;
  r[4] = (__bf16)v1.x; r[5] = (__bf16)v1.y; r[6] = (__bf16)v1.z; r[7] = (__bf16)v1.w;
  return r;
}
DEVI void mfma_bf16(f32x4& c, bf16x8 a, bf16x8 b) {
  c = __builtin_amdgcn_mfma_f32_16x16x32_bf16(a, b, c, 0, 0, 0);
}
// async global->LDS, 16B per lane; lds dest = wave-uniform base + lane*16
DEVI void gload16(const void* g, void* l) {
  __builtin_amdgcn_global_load_lds((__attribute__((address_space(1))) void*)g,
                                   (__attribute__((address_space(3))) void*)l, 16, 0, 0);
}

// ---------------- weight transpose-convert (fp32 [K][N] -> bf16 Wt[N][K]) ----
struct ConvArgs {
  const float* src[64];
  int doff[64];
  int Kd[64];
  int Nd[64];
  int n;
};

__global__ __launch_bounds__(256) void conv_k(ConvArgs ca, unsigned short* __restrict__ wbf) {
  int e = blockIdx.x;
  int K = ca.Kd[e], N = ca.Nd[e];
  int nx = N >> 6, nk = K >> 6;
  int t = blockIdx.y;
  if (t >= nx * nk) return;
  int tx = t % nx, tk = t / nx;
  const float* s = ca.src[e];
  unsigned short* d = wbf + ca.doff[e];
  int n = tx * 64 + (threadIdx.x & 63);
  int k0 = tk * 64 + (threadIdx.x >> 6) * 16;
  for (int r = 0; r < 16; r++) {
    int k = k0 + r;
    d[(size_t)n * K + k] = f2b(s[(size_t)k * N + n]);
  }
}

// ---------------- fp32 -> bf16 flat convert ----------------
__global__ __launch_bounds__(256) void cvt_k(const float* __restrict__ s,
                                             unsigned short* __restrict__ d, int n8) {
  int i = blockIdx.x * 256 + threadIdx.x;
  if (i >= n8) return;
  float4 v0 = *(const float4*)(s + (size_t)i * 8);
  float4 v1 = *(const float4*)(s + (size_t)i * 8 + 4);
  *(us8*)(d + (size_t)i * 8) = __builtin_bit_cast(us8, pack_f8(v0, v1));
}

// ---------------- bias concat prep ----------------
__global__ __launch_bounds__(256) void bias_prep_k(
    const float* __restrict__ bq, const float* __restrict__ sb1,
    const float* __restrict__ sb2, const float* __restrict__ ogb,
    const float* __restrict__ trb, float* __restrict__ bias) {
  int t = threadIdx.x;
  for (int i = t; i < 1024 + 3 * 2560; i += 256) bias[i] = 0.f;
  __syncthreads();
  for (int i = 0; i < 3; i++) {
    float* B = bias + 1024 + i * 2560;
    B[t]        = bq[i * 256 + t];
    B[1024 + t] = sb1[i * 256 + t];
    B[1536 + t] = sb2[i * 256 + t];
    B[2048 + t] = ogb[i * 256 + t];
    B[2304 + t] = trb[i * 256 + t];
  }
}

// ---------------- attn bias relayout -> biasb[(l*8+h)][row][k] bf16 ----------
__global__ __launch_bounds__(256) void biasb_k(const float* __restrict__ adb,
                                               unsigned short* __restrict__ biasb) {
  __shared__ float ld[3072];
  int rq = blockIdx.x;  // 0..4095
  int t = threadIdx.x;
  const float* src = adb + (size_t)rq * 3072;
  for (int i = t; i < 3072; i += 256) ld[i] = src[i];
  __syncthreads();
  int k = t & 127;
  for (int lh = t >> 7; lh < 24; lh += 2)
    biasb[((size_t)lh * 4096 + rq) * 128 + k] = f2b(ld[k * 24 + lh]);
}

// ---------------- tok idx from one-hot ----------------
__global__ __launch_bounds__(256) void tokidx_k(const float* __restrict__ a2t,
                                                int* __restrict__ idx) {
  int m = blockIdx.x * 4 + (threadIdx.x >> 6);
  int lane = threadIdx.x & 63;
  int best = -1;
  for (int j = 0; j < 16; j++) {
    int col = lane * 16 + j;
    if (a2t[(size_t)m * 1024 + col] > 0.5f) best = col;
  }
#pragma unroll
  for (int off = 1; off < 64; off <<= 1) best = max(best, __shfl_xor(best, off));
  if (lane == 0) idx[m] = best;
}

// ---------------- qf = q + tokfeat[gather], fused LN -> lnqb ----------------
__global__ __launch_bounds__(256) void qfinitln_k(const float* __restrict__ q,
                                                  const unsigned short* __restrict__ tokf,
                                                  const int* __restrict__ idx,
                                                  float* __restrict__ qf,
                                                  unsigned short* __restrict__ lnout) {
  int wid = threadIdx.x >> 6, lane = threadIdx.x & 63;
  size_t row = (size_t)blockIdx.x * 4 + wid;
  int m = (int)(row & 4095);
  int bt = (int)(row >> 12);
  float4 qv = *(const float4*)(q + row * 256 + lane * 4);
  us4 tv = *(const us4*)(tokf + ((size_t)bt * 1024 + idx[m]) * 256 + lane * 4);
  float x[4];
  x[0] = qv.x + b2f(tv[0]); x[1] = qv.y + b2f(tv[1]);
  x[2] = qv.z + b2f(tv[2]); x[3] = qv.w + b2f(tv[3]);
  *(float4*)(qf + row * 256 + lane * 4) = make_float4(x[0], x[1], x[2], x[3]);
  float s = x[0] + x[1] + x[2] + x[3];
  float sq = x[0] * x[0] + x[1] * x[1] + x[2] * x[2] + x[3] * x[3];
#pragma unroll
  for (int o = 1; o < 64; o <<= 1) {
    s += __shfl_xor(s, o);
    sq += __shfl_xor(sq, o);
  }
  float mu = s * 0.00390625f;
  float rs = rsqrtf(sq * 0.00390625f - mu * mu + 1e-5f);
  us4 r;
#pragma unroll
  for (int j = 0; j < 4; j++) r[j] = f2b((x[j] - mu) * rs);
  *(us4*)(lnout + row * 256 + lane * 4) = r;
}

// ---------------- rowwise LayerNorm over 256, fp32 in -> bf16 out ----------
__global__ __launch_bounds__(256) void ln_k(const float* __restrict__ src,
                                            unsigned short* __restrict__ dst) {
  size_t row = (size_t)blockIdx.x * 4 + (threadIdx.x >> 6);
  int lane = threadIdx.x & 63;
  float4 v = ((const float4*)(src + row * 256))[lane];
  float s = v.x + v.y + v.z + v.w;
#pragma unroll
  for (int o = 1; o < 64; o <<= 1) s += __shfl_xor(s, o);
  float mu = s * 0.00390625f;
  float dx = v.x - mu, dy = v.y - mu, dz = v.z - mu, dw = v.w - mu;
  float qv = dx * dx + dy * dy + dz * dz + dw * dw;
#pragma unroll
  for (int o = 1; o < 64; o <<= 1) qv += __shfl_xor(qv, o);
  float rs = rsqrtf(qv * 0.00390625f + 1e-5f);
  us4 r;
  r[0] = f2b(dx * rs); r[1] = f2b(dy * rs); r[2] = f2b(dz * rs); r[3] = f2b(dw * rs);
  *(us4*)(dst + row * 256 + lane * 4) = r;
}

// ---------------- staged GEMM: 128xBN tile, BK=64, swizzled LDS, coalesced C -
// EP1: out=bf16(acc+bias); EP4: out = sigmoid(s+b)*lnq + (k+0)  [dual]
// EP5: out = silu(x1)*x2 [dual].  NI = BN/32 (4 -> BN=128, 2 -> BN=64)
template <int K, int EP, int NI>
__global__ __launch_bounds__(256) void gemm3_k(
    const unsigned short* __restrict__ A, const unsigned short* __restrict__ Wt,
    const float* __restrict__ bias, unsigned short* __restrict__ out,
    const unsigned short* __restrict__ lnq, int NOUT) {
  constexpr bool DUAL = (EP == 4 || EP == 5);
  constexpr int PAIR = (EP == 4) ? 256 : 512;
  constexpr int BN = NI * 32;
  constexpr int BSZ = BN * 64;
  __shared__ __align__(16) unsigned short S[128 * 64 + BSZ + (DUAL ? BSZ : 0)];
  unsigned short* As = S;
  unsigned short* Bs = S + 128 * 64;
  unsigned short* Bs2 = Bs + BSZ;
  const int tid = threadIdx.x;
  const int lane = tid & 63, w = tid >> 6;
  const int lg = lane >> 4, lr = lane & 15;
  const int wr = w >> 1, wc = w & 1;
  const size_t m_base = (size_t)blockIdx.x * 128;
  const size_t n_base = (size_t)blockIdx.y * BN;
  const int srow = w * 8 + (lane >> 3);
  const int scol = ((lane & 7) ^ (lane >> 3)) * 8;
  const unsigned short* gA = A + (m_base + srow) * K + scol;
  const unsigned short* gB = Wt + (n_base + srow) * K + scol;
  const unsigned short* gB2 = Wt + (n_base + PAIR + srow) * K + scol;
  f32x4 acc[4][NI] = {};
  f32x4 acc2[DUAL ? 4 : 1][DUAL ? NI : 1] = {};
  const int swz = lr & 7;
  for (int kk = 0; kk < K; kk += 64) {
#pragma unroll
    for (int j = 0; j < 4; j++)
      gload16(gA + (size_t)(j * 32) * K + kk, As + w * 512 + j * 2048);
#pragma unroll
    for (int j = 0; j < NI; j++)
      gload16(gB + (size_t)(j * 32) * K + kk, Bs + w * 512 + j * 2048);
    if constexpr (DUAL) {
#pragma unroll
      for (int j = 0; j < NI; j++)
        gload16(gB2 + (size_t)(j * 32) * K + kk, Bs2 + w * 512 + j * 2048);
    }
    __syncthreads();
#pragma unroll
    for (int ks = 0; ks < 2; ks++) {
      const int co = ((ks * 4 + lg) ^ swz) << 3;
      bf16x8 af[4], b1[NI], b2v[NI];
#pragma unroll
      for (int i = 0; i < 4; i++) af[i] = ld_bf8(As + (wr * 64 + i * 16 + lr) * 64 + co);
#pragma unroll
      for (int i = 0; i < NI; i++) {
        b1[i] = ld_bf8(Bs + (wc * (BN / 2) + i * 16 + lr) * 64 + co);
        if constexpr (DUAL) b2v[i] = ld_bf8(Bs2 + (wc * (BN / 2) + i * 16 + lr) * 64 + co);
      }
#pragma unroll
      for (int mi = 0; mi < 4; mi++)
#pragma unroll
        for (int ni = 0; ni < NI; ni++) {
          mfma_bf16(acc[mi][ni], af[mi], b1[ni]);
          if constexpr (DUAL) mfma_bf16(acc2[mi][ni], af[mi], b2v[ni]);
        }
    }
    __syncthreads();
  }
  // epilogue: final bf16 into chunk-swizzled LDS tile, then coalesced us8 out
#pragma unroll
  for (int mi = 0; mi < 4; mi++)
#pragma unroll
    for (int ni = 0; ni < NI; ni++)
#pragma unroll
      for (int r = 0; r < 4; r++) {
        int rowl = wr * 64 + mi * 16 + lg * 4 + r;
        int col = wc * (BN / 2) + ni * 16 + lr;
        size_t grow = m_base + rowl;
        int gcol = (int)n_base + col;
        float v = acc[mi][ni][r] + bias[gcol];
        unsigned short res;
        if constexpr (EP == 1) {
          res = f2b(v);
        } else if constexpr (EP == 4) {
          float vk = acc2[mi][ni][r] + bias[gcol + 256];
          res = f2b(sigm(v) * b2f(lnq[grow * 256 + gcol]) + vk);
        } else {  // EP5
          float v2 = acc2[mi][ni][r] + bias[gcol + 512];
          res = f2b(v * sigm(v) * v2);
        }
        S[rowl * BN + (((col >> 3) ^ (rowl & 7)) << 3) + (col & 7)] = res;
      }
  __syncthreads();
  constexpr int CH = BN / 8;
#pragma unroll
  for (int p = 0; p < BN / 16; p++) {
    int rowl = p * (256 / CH) + tid / CH;
    int chunk = tid % CH;
    us8 v = *(const us8*)(S + rowl * BN + ((chunk ^ (rowl & 7)) << 3));
    *(us8*)(out + (m_base + rowl) * NOUT + n_base + chunk * 8) = v;
  }
}

// ---------------- residual GEMM + fused LayerNorm -----------------
// qf[row] += (GATED? sigmoid(gate[row,col]) : 1) * (A@Wt^T)[row,col]
// then lnout[row] = LN(qf[row]) (optionally affine lng/lnb). 64x256 tile.
template <int K, bool GATED>
__global__ __launch_bounds__(512) void gemmln_k(
    const unsigned short* __restrict__ A, const unsigned short* __restrict__ Wt,
    float* __restrict__ qf, const unsigned short* __restrict__ gate,
    unsigned short* __restrict__ lnout, const float* __restrict__ lng,
    const float* __restrict__ lnb) {
  __shared__ __align__(16) unsigned short S[64 * 64 + 256 * 64];  // stage; rep 64x256
  unsigned short* As = S;
  unsigned short* Bs = S + 64 * 64;
  const int tid = threadIdx.x;
  const int lane = tid & 63, w = tid >> 6;  // 8 waves
  const int lg = lane >> 4, lr = lane & 15;
  const size_t m_base = (size_t)blockIdx.x * 64;
  const int srow = lane >> 3;
  const int scol = ((lane & 7) ^ srow) * 8;
  const unsigned short* gA = A + (m_base + w * 8 + srow) * K + scol;
  const unsigned short* gB = Wt + (w * 32 + srow) * K + scol;
  f32x4 acc[4][2] = {};
  const int swz = lr & 7;
  for (int kk = 0; kk < K; kk += 64) {
    gload16(gA + kk, As + w * 512);
#pragma unroll
    for (int j = 0; j < 4; j++)
      gload16(gB + (size_t)(j * 8) * K + kk, Bs + w * 2048 + j * 512);
    __syncthreads();
#pragma unroll
    for (int ks = 0; ks < 2; ks++) {
      const int co = ((ks * 4 + lg) ^ swz) << 3;
      bf16x8 af[4], bf1[2];
#pragma unroll
      for (int i = 0; i < 4; i++) af[i] = ld_bf8(As + (i * 16 + lr) * 64 + co);
#pragma unroll
      for (int i = 0; i < 2; i++) bf1[i] = ld_bf8(Bs + (w * 32 + i * 16 + lr) * 64 + co);
#pragma unroll
      for (int mi = 0; mi < 4; mi++)
#pragma unroll
        for (int ni = 0; ni < 2; ni++) mfma_bf16(acc[mi][ni], af[mi], bf1[ni]);
    }
    __syncthreads();
  }
  // epilogue: qf RMW + stash bf16(qf) swizzled in S
#pragma unroll
  for (int mi = 0; mi < 4; mi++)
#pragma unroll
    for (int ni = 0; ni < 2; ni++)
#pragma unroll
      for (int r = 0; r < 4; r++) {
        int rowl = mi * 16 + lg * 4 + r;
        int col = w * 32 + ni * 16 + lr;
        size_t grow = m_base + rowl;
        float v = acc[mi][ni][r];
        if constexpr (GATED) v *= sigm(b2f(gate[grow * 256 + col]));
        float nq = qf[grow * 256 + col] + v;
        qf[grow * 256 + col] = nq;
        S[rowl * 256 + (((col >> 3) ^ (rowl & 7)) << 3) + (col & 7)] = f2b(nq);
      }
  __syncthreads();
  float gv[4], bv[4];
  if (lng) {
#pragma unroll
    for (int j = 0; j < 4; j++) {
      gv[j] = lng[lane * 4 + j];
      bv[j] = lnb[lane * 4 + j];
    }
  }
  const int rchunk = ((lane >> 1)) ;   // (lane*4)>>3
  const int rsub = (lane & 1) << 2;    // (lane*4)&7
  for (int rr = 0; rr < 8; rr++) {
    int rowl = w * 8 + rr;
    us4 vv = *(const us4*)(S + rowl * 256 + ((rchunk ^ (rowl & 7)) << 3) + rsub);
    float x[4];
#pragma unroll
    for (int j = 0; j < 4; j++) x[j] = b2f(vv[j]);
    float s = x[0] + x[1] + x[2] + x[3];
    float sq = x[0] * x[0] + x[1] * x[1] + x[2] * x[2] + x[3] * x[3];
#pragma unroll
    for (int o = 1; o < 64; o <<= 1) {
      s += __shfl_xor(s, o);
      sq += __shfl_xor(sq, o);
    }
    float mu = s * 0.00390625f;
    float rs = rsqrtf(sq * 0.00390625f - mu * mu + 1e-5f);
    us4 r;
#pragma unroll
    for (int j = 0; j < 4; j++) {
      float y = (x[j] - mu) * rs;
      if (lng) y = y * gv[j] + bv[j];
      r[j] = f2b(y);
    }
    *(us4*)(lnout + (m_base + rowl) * 256 + lane * 4) = r;
  }
}

// ---------------- windowed spatial attention ----------------
__global__ __launch_bounds__(256) void attn_k(const unsigned short* __restrict__ big1,
                                              const unsigned short* __restrict__ biasb,
                                              unsigned short* __restrict__ o, int layer) {
  __shared__ __align__(16) unsigned short pl_s[4][32 * 128];
  __shared__ __align__(16) unsigned short vt_s[4][32 * 128];
  const int w = blockIdx.x, bt = blockIdx.y, hg = blockIdx.z;
  const int tid = threadIdx.x, wid = tid >> 6, lane = tid & 63;
  const int lg = lane >> 4, lr = lane & 15;
  const int h = hg * 4 + wid;
  unsigned short* pl = pl_s[wid];
  unsigned short* vt = vt_s[wid];
  const size_t base = (size_t)bt * M_;
  const float inv_s = 0.17677669529663687f;

  {
    const int chunk = lane & 3;
    const int krow = lane >> 2;
#pragma unroll
    for (int it = 0; it < 8; it++) {
      int key = it * 16 + krow;
      int ak = w * 32 - SIDE_ + key;
      int akc = ak < 0 ? 0 : (ak > M_ - 1 ? M_ - 1 : ak);
      us8 v = *(const us8*)(big1 + (base + akc) * 1024 + 512 + h * 32 + chunk * 8);
#pragma unroll
      for (int e = 0; e < 8; e++) {
        int d = chunk * 8 + e;
        vt[d * 128 + (key ^ ((d & 7) << 3))] = v[e];
      }
    }
  }
  bf16x8 aq[2];
#pragma unroll
  for (int mi = 0; mi < 2; mi++)
    aq[mi] = ld_bf8(big1 + (base + w * 32 + mi * 16 + lr) * 1024 + h * 32 + lg * 8);
  f32x4 lac[2][8] = {};
#pragma unroll
  for (int ni = 0; ni < 8; ni++) {
    int kidx = ni * 16 + lr;
    int ak = w * 32 - SIDE_ + kidx;
    int akc = ak < 0 ? 0 : (ak > M_ - 1 ? M_ - 1 : ak);
    bf16x8 bk = ld_bf8(big1 + (base + akc) * 1024 + 256 + h * 32 + lg * 8);
    mfma_bf16(lac[0][ni], aq[0], bk);
    mfma_bf16(lac[1][ni], aq[1], bk);
  }
  const unsigned short* brow0 =
      biasb + (((size_t)(layer * 8 + h)) * 4096 + w * 32) * 128;
#pragma unroll
  for (int mi = 0; mi < 2; mi++)
#pragma unroll
    for (int r = 0; r < 4; r++) {
      int qrow = mi * 16 + lg * 4 + r;
      const unsigned short* brow = brow0 + (size_t)qrow * 128;
      float lv[8];
      float mx = -3e38f;
#pragma unroll
      for (int ni = 0; ni < 8; ni++) {
        int kidx = ni * 16 + lr;
        int ak = w * 32 - SIDE_ + kidx;
        float x = lac[mi][ni][r] * inv_s + b2f(brow[kidx]) +
                  ((unsigned)ak < (unsigned)M_ ? 0.f : -1e9f);
        lv[ni] = x;
        mx = fmaxf(mx, x);
      }
#pragma unroll
      for (int off = 1; off < 16; off <<= 1) mx = fmaxf(mx, __shfl_xor(mx, off));
      float sum = 0.f;
#pragma unroll
      for (int ni = 0; ni < 8; ni++) {
        float e = __expf(lv[ni] - mx);
        lv[ni] = e;
        sum += e;
      }
#pragma unroll
      for (int off = 1; off < 16; off <<= 1) sum += __shfl_xor(sum, off);
      float inv = 1.f / sum;
      int sw = (qrow & 7) << 3;
#pragma unroll
      for (int ni = 0; ni < 8; ni++)
        pl[qrow * 128 + ((ni * 16 + lr) ^ sw)] = f2b(lv[ni] * inv);
    }
  f32x4 oc[2][2] = {};
#pragma unroll
  for (int ks = 0; ks < 4; ks++) {
    int kbase = ks * 32 + lg * 8;
    int kswz = kbase ^ ((lr & 7) << 3);
    bf16x8 ap0 = ld_bf8(pl + lr * 128 + kswz);
    bf16x8 ap1 = ld_bf8(pl + (16 + lr) * 128 + kswz);
    bf16x8 bv0 = ld_bf8(vt + lr * 128 + kswz);
    bf16x8 bv1 = ld_bf8(vt + (16 + lr) * 128 + kswz);
    mfma_bf16(oc[0][0], ap0, bv0);
    mfma_bf16(oc[0][1], ap0, bv1);
    mfma_bf16(oc[1][0], ap1, bv0);
    mfma_bf16(oc[1][1], ap1, bv1);
  }
#pragma unroll
  for (int mi = 0; mi < 2; mi++)
#pragma unroll
    for (int nd = 0; nd < 2; nd++)
#pragma unroll
      for (int r = 0; r < 4; r++) {
        int qrow = mi * 16 + lg * 4 + r;
        int d = nd * 16 + lr;
        size_t rowi = base + w * 32 + qrow;
        float gv = sigm(b2f(big1[rowi * 1024 + 768 + h * 32 + d]));
        o[rowi * 256 + h * 32 + d] = f2b(oc[mi][nd][r] * gv);
      }
}

// ---------------- temporal attention (T=8 per atom) ----------------
__global__ __launch_bounds__(256) void tattn_k(const unsigned short* __restrict__ big1,
                                               const float* __restrict__ ts,
                                               const float* __restrict__ tdec,
                                               unsigned short* __restrict__ o, int layer) {
  __shared__ __align__(16) unsigned short lds[4][8 * 768];
  int wid = threadIdx.x >> 6, lane = threadIdx.x & 63;
  int m = blockIdx.x * 4 + wid;
  unsigned short* Lp = lds[wid];
  for (int it = 0; it < 12; it++) {
    int u = it * 64 + lane;
    int t = u / 96, pos = (u % 96) * 8;
    *(uint4*)(Lp + t * 768 + pos) =
        *(const uint4*)(big1 + ((size_t)(t * M_ + m)) * 1024 + pos);
  }
  __syncthreads();
  int th = lane >> 3, qt = lane & 7;
  float decay = log1pf(__expf(tdec[layer * 8 + th]));
  float tsq = ts[qt];
  const float inv_t = 0.17677669529663687f;
  float tqv[32];
#pragma unroll
  for (int d = 0; d < 32; d++) tqv[d] = b2f(Lp[qt * 768 + th * 32 + d]);
  float lv[8];
  float mx = -3e38f;
#pragma unroll
  for (int kt = 0; kt < 8; kt++) {
    float dot = 0.f;
#pragma unroll
    for (int d = 0; d < 32; d++) dot += tqv[d] * b2f(Lp[kt * 768 + 256 + th * 32 + d]);
    float x = dot * inv_t - decay * fabsf(tsq - ts[kt]);
    lv[kt] = x;
    mx = fmaxf(mx, x);
  }
  float s = 0.f;
#pragma unroll
  for (int kt = 0; kt < 8; kt++) {
    float e = __expf(lv[kt] - mx);
    lv[kt] = e;
    s += e;
  }
  float inv = 1.f / s;
  float tov[32];
#pragma unroll
  for (int d = 0; d < 32; d++) tov[d] = 0.f;
#pragma unroll
  for (int kt = 0; kt < 8; kt++) {
    float p = lv[kt] * inv;
#pragma unroll
    for (int d = 0; d < 32; d++) tov[d] += p * b2f(Lp[kt * 768 + 512 + th * 32 + d]);
  }
  size_t orow = (size_t)qt * M_ + m;
#pragma unroll
  for (int d = 0; d < 32; d++) {
    float tg = sigm(b2f(big1[orow * 1024 + 768 + th * 32 + d]));
    o[orow * 256 + th * 32 + d] = f2b(tov[d] * tg);
  }
}

// ---------------- final: out = LN(qf, pos_g, pos_b) @ pos_w ----------------
__global__ __launch_bounds__(256) void final_k(const float* __restrict__ qf,
                                               const float* __restrict__ pg,
                                               const float* __restrict__ pb,
                                               const float* __restrict__ pw,
                                               float* __restrict__ out) {
  size_t row = (size_t)blockIdx.x * 4 + (threadIdx.x >> 6);
  int lane = threadIdx.x & 63;
  float4 v = ((const float4*)(qf + row * 256))[lane];
  float s = v.x + v.y + v.z + v.w;
#pragma unroll
  for (int o = 1; o < 64; o <<= 1) s += __shfl_xor(s, o);
  float mu = s * 0.00390625f;
  float dx = v.x - mu, dy = v.y - mu, dz = v.z - mu, dw = v.w - mu;
  float qv = dx * dx + dy * dy + dz * dz + dw * dw;
#pragma unroll
  for (int o = 1; o < 64; o <<= 1) qv += __shfl_xor(qv, o);
  float rs = rsqrtf(qv * 0.00390625f + 1e-5f);
  int d = lane * 4;
  float xn[4];
  xn[0] = dx * rs * pg[d] + pb[d];
  xn[1] = dy * rs * pg[d + 1] + pb[d + 1];
  xn[2] = dz * rs * pg[d + 2] + pb[d + 2];
  xn[3] = dw * rs * pg[d + 3] + pb[d + 3];
  float p0 = 0.f, p1 = 0.f, p2 = 0.f;
#pragma unroll
  for (int dd = 0; dd < 4; dd++) {
    const float* wr = pw + (size_t)(d + dd) * 3;
    p0 += xn[dd] * wr[0];
    p1 += xn[dd] * wr[1];
    p2 += xn[dd] * wr[2];
  }
#pragma unroll
  for (int o = 1; o < 64; o <<= 1) {
    p0 += __shfl_xor(p0, o);
    p1 += __shfl_xor(p1, o);
    p2 += __shfl_xor(p2, o);
  }
  if (lane == 0) {
    out[row * 3 + 0] = p0;
    out[row * 3 + 1] = p1;
    out[row * 3 + 2] = p2;
  }
}

extern "C" void kernel_launch(void* const* d_in, const int* in_sizes, int n_in,
                              void* d_out, int out_size, void* d_ws, size_t ws_size,
                              hipStream_t stream) {
  const float* a       = (const float*)d_in[0];
  const float* q_in    = (const float*)d_in[1];
  const float* c_in    = (const float*)d_in[2];
  const float* adb     = (const float*)d_in[3];
  const float* a2t     = (const float*)d_in[4];
  const float* ts      = (const float*)d_in[6];
  const float* W_a2q   = (const float*)d_in[7];
  const float* ada1_sw = (const float*)d_in[8];
  const float* ada1_sb = (const float*)d_in[9];
  const float* ada1_kw = (const float*)d_in[10];
  const float* attn_wq = (const float*)d_in[11];
  const float* attn_bq = (const float*)d_in[12];
  const float* attn_wk = (const float*)d_in[13];
  const float* attn_wv = (const float*)d_in[14];
  const float* attn_wg = (const float*)d_in[15];
  const float* attn_wo = (const float*)d_in[16];
  const float* og_w    = (const float*)d_in[17];
  const float* og_b    = (const float*)d_in[18];
  const float* ada2_sw = (const float*)d_in[19];
  const float* ada2_sb = (const float*)d_in[20];
  const float* ada2_kw = (const float*)d_in[21];
  const float* tr_w1   = (const float*)d_in[22];
  const float* tr_w2   = (const float*)d_in[23];
  const float* tr_w3   = (const float*)d_in[24];
  const float* tr_gw   = (const float*)d_in[25];
  const float* tr_gb   = (const float*)d_in[26];
  const float* t_ln_g  = (const float*)d_in[27];
  const float* t_ln_b  = (const float*)d_in[28];
  const float* t_wq    = (const float*)d_in[29];
  const float* t_wk    = (const float*)d_in[30];
  const float* t_wv    = (const float*)d_in[31];
  const float* t_wg    = (const float*)d_in[32];
  const float* t_wo    = (const float*)d_in[33];
  const float* t_dec   = (const float*)d_in[34];
  const float* pos_g   = (const float*)d_in[35];
  const float* pos_b   = (const float*)d_in[36];
  const float* pos_w   = (const float*)d_in[37];

  // ---- workspace layout, ~225 MB ----
  char* base = (char*)d_ws;
  size_t off = 0;
  auto alloc = [&](size_t bytes) {
    void* p = base + off;
    off += (bytes + 255) & ~(size_t)255;
    return p;
  };
  float* qf            = (float*)alloc(Fq * 4);              // 32 MiB
  unsigned short* lncb = (unsigned short*)alloc(Fq * 2);     // 16 MiB
  unsigned short* lnqb = (unsigned short*)alloc(Fq * 2);     // 16 MiB
  unsigned short* obuf = (unsigned short*)alloc(Fq * 2);     // 16 MiB
  unsigned short* big1 = (unsigned short*)alloc(Fq * 8);     // 64 MiB (xbuf/abf/tokf alias)
  unsigned short* bbuf = (unsigned short*)alloc(Fq * 2);     // 16 MiB
  unsigned short* ggate= (unsigned short*)alloc(Fq * 2);     // 16 MiB
  unsigned short* cbf  = (unsigned short*)alloc(Fq * 2);     // 16 MiB
  unsigned short* biasb= (unsigned short*)alloc((size_t)24 * 4096 * 128 * 2);  // 24 MiB
  unsigned short* wbf  = (unsigned short*)alloc((size_t)4718592 * 2);          // 9 MiB
  float* biasr         = (float*)alloc(8704 * 4);
  int* tokidx          = (int*)alloc(4096 * 4);

  unsigned short* xbuf = big1;               // R*512 (dead between attn and t-qkvg)
  unsigned short* abf  = big1;               // 8192*1536 (dead before layer 0)
  unsigned short* tokf = big1 + 2 * Fq;      // 8192*256

  // ---- weight transpose-convert descriptors ----
  ConvArgs ca;
  int ne = 0;
  auto add = [&](const float* s, size_t doff, int K, int N) {
    ca.src[ne] = s; ca.doff[ne] = (int)doff; ca.Kd[ne] = K; ca.Nd[ne] = N; ne++;
  };
  constexpr size_t LW = 1441792;
  for (int i = 0; i < 3; i++) {
    size_t LB = (size_t)i * LW;
    add(ada1_sw + i * 65536, LB + 0, 256, 256);
    add(ada1_kw + i * 65536, LB + 65536, 256, 256);
    add(attn_wq + i * 65536, LB + 131072, 256, 256);
    add(attn_wk + i * 65536, LB + 196608, 256, 256);
    add(attn_wv + i * 65536, LB + 262144, 256, 256);
    add(attn_wg + i * 65536, LB + 327680, 256, 256);
    add(attn_wo + i * 65536, LB + 393216, 256, 256);
    add(og_w + i * 65536, LB + 458752, 256, 256);
    add(tr_gw + i * 65536, LB + 524288, 256, 256);
    add(ada2_sw + i * 65536, LB + 589824, 256, 256);
    add(ada2_kw + i * 65536, LB + 655360, 256, 256);
    add(tr_w1 + i * 131072, LB + 720896, 256, 512);
    add(tr_w2 + i * 131072, LB + 851968, 256, 512);
    add(tr_w3 + i * 131072, LB + 983040, 512, 256);
    add(t_wq + i * 65536, LB + 1114112, 256, 256);
    add(t_wk + i * 65536, LB + 1179648, 256, 256);
    add(t_wv + i * 65536, LB + 1245184, 256, 256);
    add(t_wg + i * 65536, LB + 1310720, 256, 256);
    add(t_wo + i * 65536, LB + 1376256, 256, 256);
  }
  add(W_a2q, 3 * LW, 1536, 256);
  ca.n = ne;

  conv_k<<<dim3(ne, 96), 256, 0, stream>>>(ca, wbf);
  bias_prep_k<<<1, 256, 0, stream>>>(attn_bq, ada1_sb, ada2_sb, og_b, tr_gb, biasr);
  tokidx_k<<<1024, 256, 0, stream>>>(a2t, tokidx);
  biasb_k<<<4096, 256, 0, stream>>>(adb, biasb);
  cvt_k<<<6144, 256, 0, stream>>>(a, abf, 1572864);
  cvt_k<<<4096, 256, 0, stream>>>(c_in, cbf, 1048576);
  gemm3_k<1536, 1, 2><<<dim3(64, 4), 256, 0, stream>>>(
      abf, wbf + 3 * LW, biasr, tokf, nullptr, 256);
  qfinitln_k<<<8192, 256, 0, stream>>>(q_in, tokf, tokidx, qf, lnqb);
  ln_k<<<8192, 256, 0, stream>>>(c_in, lncb);

  for (int i = 0; i < 3; i++) {
    size_t LB = (size_t)i * LW;
    const float* b_attn = biasr + 1024 + (size_t)i * 2560;
    const float* b_ada1 = b_attn + 1024;
    const float* b_ada2 = b_attn + 1536;
    const float* b_ogtr = b_attn + 2048;

    // adaLN 1 (fused combine with lnqb)
    gemm3_k<256, 4, 4><<<dim3(256, 2), 256, 0, stream>>>(
        lncb, wbf + LB, b_ada1, bbuf, lnqb, 256);
    // qkvg projections + spatial attention
    gemm3_k<256, 1, 4><<<dim3(256, 8), 256, 0, stream>>>(
        bbuf, wbf + LB + 131072, b_attn, big1, nullptr, 1024);
    attn_k<<<dim3(128, 8, 2), 256, 0, stream>>>(big1, biasb, obuf, i);
    // og gate, then qf += sigmoid(og)*(o@wo) with fused LN -> lnqb
    gemm3_k<256, 1, 4><<<dim3(256, 2), 256, 0, stream>>>(
        cbf, wbf + LB + 458752, b_ogtr, ggate, nullptr, 256);
    gemmln_k<256, true><<<512, 512, 0, stream>>>(
        obuf, wbf + LB + 393216, qf, ggate, lnqb, nullptr, nullptr);
    // adaLN 2
    gemm3_k<256, 4, 4><<<dim3(256, 2), 256, 0, stream>>>(
        lncb, wbf + LB + 589824, b_ada2, bbuf, lnqb, 256);
    // transition: x = silu(t@w1)*(t@w2); trg gate; qf += sig(trg)*(x@w3) + LN(t_ln)
    gemm3_k<256, 5, 4><<<dim3(256, 4), 256, 0, stream>>>(
        bbuf, wbf + LB + 720896, biasr, xbuf, nullptr, 512);
    gemm3_k<256, 1, 4><<<dim3(256, 2), 256, 0, stream>>>(
        cbf, wbf + LB + 524288, b_ogtr + 256, ggate, nullptr, 256);
    gemmln_k<512, true><<<512, 512, 0, stream>>>(
        xbuf, wbf + LB + 983040, qf, ggate, lnqb,
        t_ln_g + (size_t)i * 256, t_ln_b + (size_t)i * 256);
    // temporal attention
    gemm3_k<256, 1, 4><<<dim3(256, 8), 256, 0, stream>>>(
        lnqb, wbf + LB + 1114112, biasr, big1, nullptr, 1024);
    tattn_k<<<1024, 256, 0, stream>>>(big1, ts, t_dec, obuf, i);
    gemmln_k<256, false><<<512, 512, 0, stream>>>(
        obuf, wbf + LB + 1376256, qf, nullptr, lnqb, nullptr, nullptr);
  }
  final_k<<<8192, 256, 0, stream>>>(qf, pos_g, pos_b, pos_w, (float*)d_out);
}

// Round 5
// 1152.707 us; speedup vs baseline: 3.3961x; 1.1441x over previous
//
#include <hip/hip_runtime.h>
#include <cstddef>
#include <cstdint>

#define DEVI __device__ __forceinline__

typedef __attribute__((ext_vector_type(8))) __bf16 bf16x8;
typedef __attribute__((ext_vector_type(8))) unsigned short us8;
typedef __attribute__((ext_vector_type(4))) unsigned short us4;
typedef __attribute__((ext_vector_type(4))) float f32x4;

constexpr int B0_ = 1, T_ = 8, N_ = 1024, M_ = 4096, D_ = 256;
constexpr int BT_ = 8, NW_ = 128, WQ_ = 32, HK_ = 128, SIDE_ = 48;
constexpr int R_ = BT_ * M_;          // 32768 rows
constexpr size_t Fq = 8388608;        // R_*256 elements

DEVI unsigned short f2b(float f) {
  return __builtin_bit_cast(unsigned short, static_cast<__bf16>(f));
}
DEVI float b2f(unsigned short s) { return __uint_as_float(((unsigned)s) << 16); }
DEVI float sigm(float x) { return 1.0f / (1.0f + __expf(-x)); }
DEVI bf16x8 ld_bf8(const unsigned short* p) {
  return __builtin_bit_cast(bf16x8, *(const us8*)p);
}
DEVI bf16x8 pack_f8(float4 v0, float4 v1) {
  bf16x8 r;
  r[0] = (__bf16)v0.x; r[1] = (__bf16)v0.y; r[2] = (__bf16)v0.z; r[3] = (__bf16)v0.w;
  r[4] = (__bf16)v1.x; r[5] = (__bf16)v1.y; r[6] = (__bf16)v1.z; r[7] = (__bf16)v1.w;
  return r;
}
DEVI void mfma_bf16(f32x4& c, bf16x8 a, bf16x8 b) {
  c = __builtin_amdgcn_mfma_f32_16x16x32_bf16(a, b, c, 0, 0, 0);
}
// async global->LDS, 16B per lane; lds dest = wave-uniform base + lane*16
DEVI void gload16(const void* g, void* l) {
  __builtin_amdgcn_global_load_lds((__attribute__((address_space(1))) void*)g,
                                   (__attribute__((address_space(3))) void*)l, 16, 0, 0);
}

// ---------------- weight transpose-convert (fp32 [K][N] -> bf16 Wt[N][K]) ----
struct ConvArgs {
  const float* src[64];
  int doff[64];
  int Kd[64];
  int Nd[64];
  int n;
};

__global__ __launch_bounds__(256) void conv_k(ConvArgs ca, unsigned short* __restrict__ wbf) {
  int e = blockIdx.x;
  int K = ca.Kd[e], N = ca.Nd[e];
  int nx = N >> 6, nk = K >> 6;
  int t = blockIdx.y;
  if (t >= nx * nk) return;
  int tx = t % nx, tk = t / nx;
  const float* s = ca.src[e];
  unsigned short* d = wbf + ca.doff[e];
  int n = tx * 64 + (threadIdx.x & 63);
  int k0 = tk * 64 + (threadIdx.x >> 6) * 16;
  for (int r = 0; r < 16; r++) {
    int k = k0 + r;
    d[(size_t)n * K + k] = f2b(s[(size_t)k * N + n]);
  }
}

// ---------------- fp32 -> bf16 flat convert ----------------
__global__ __launch_bounds__(256) void cvt_k(const float* __restrict__ s,
                                             unsigned short* __restrict__ d, int n8) {
  int i = blockIdx.x * 256 + threadIdx.x;
  if (i >= n8) return;
  float4 v0 = *(const float4*)(s + (size_t)i * 8);
  float4 v1 = *(const float4*)(s + (size_t)i * 8 + 4);
  *(us8*)(d + (size_t)i * 8) = __builtin_bit_cast(us8, pack_f8(v0, v1));
}

// ---------------- bias concat prep ----------------
__global__ __launch_bounds__(256) void bias_prep_k(
    const float* __restrict__ bq, const float* __restrict__ sb1,
    const float* __restrict__ sb2, const float* __restrict__ ogb,
    const float* __restrict__ trb, float* __restrict__ bias) {
  int t = threadIdx.x;
  for (int i = t; i < 1024 + 3 * 2560; i += 256) bias[i] = 0.f;
  __syncthreads();
  for (int i = 0; i < 3; i++) {
    float* B = bias + 1024 + i * 2560;
    B[t]        = bq[i * 256 + t];
    B[1024 + t] = sb1[i * 256 + t];
    B[1536 + t] = sb2[i * 256 + t];
    B[2048 + t] = ogb[i * 256 + t];
    B[2304 + t] = trb[i * 256 + t];
  }
}

// ---------------- attn bias relayout -> biasb[(l*8+h)][row][k] bf16 ----------
__global__ __launch_bounds__(256) void biasb_k(const float* __restrict__ adb,
                                               unsigned short* __restrict__ biasb) {
  __shared__ float ld[3072];
  int rq = blockIdx.x;  // 0..4095
  int t = threadIdx.x;
  const float* src = adb + (size_t)rq * 3072;
  for (int i = t; i < 3072; i += 256) ld[i] = src[i];
  __syncthreads();
  int k = t & 127;
  for (int lh = t >> 7; lh < 24; lh += 2)
    biasb[((size_t)lh * 4096 + rq) * 128 + k] = f2b(ld[k * 24 + lh]);
}

// ---------------- tok idx from one-hot ----------------
__global__ __launch_bounds__(256) void tokidx_k(const float* __restrict__ a2t,
                                                int* __restrict__ idx) {
  int m = blockIdx.x * 4 + (threadIdx.x >> 6);
  int lane = threadIdx.x & 63;
  int best = -1;
  for (int j = 0; j < 16; j++) {
    int col = lane * 16 + j;
    if (a2t[(size_t)m * 1024 + col] > 0.5f) best = col;
  }
#pragma unroll
  for (int off = 1; off < 64; off <<= 1) best = max(best, __shfl_xor(best, off));
  if (lane == 0) idx[m] = best;
}

// ---------------- qf = q + tokfeat[gather], fused LN -> lnqb ----------------
__global__ __launch_bounds__(256) void qfinitln_k(const float* __restrict__ q,
                                                  const unsigned short* __restrict__ tokf,
                                                  const int* __restrict__ idx,
                                                  float* __restrict__ qf,
                                                  unsigned short* __restrict__ lnout) {
  int wid = threadIdx.x >> 6, lane = threadIdx.x & 63;
  size_t row = (size_t)blockIdx.x * 4 + wid;
  int m = (int)(row & 4095);
  int bt = (int)(row >> 12);
  float4 qv = *(const float4*)(q + row * 256 + lane * 4);
  us4 tv = *(const us4*)(tokf + ((size_t)bt * 1024 + idx[m]) * 256 + lane * 4);
  float x[4];
  x[0] = qv.x + b2f(tv[0]); x[1] = qv.y + b2f(tv[1]);
  x[2] = qv.z + b2f(tv[2]); x[3] = qv.w + b2f(tv[3]);
  *(float4*)(qf + row * 256 + lane * 4) = make_float4(x[0], x[1], x[2], x[3]);
  float s = x[0] + x[1] + x[2] + x[3];
  float sq = x[0] * x[0] + x[1] * x[1] + x[2] * x[2] + x[3] * x[3];
#pragma unroll
  for (int o = 1; o < 64; o <<= 1) {
    s += __shfl_xor(s, o);
    sq += __shfl_xor(sq, o);
  }
  float mu = s * 0.00390625f;
  float rs = rsqrtf(sq * 0.00390625f - mu * mu + 1e-5f);
  us4 r;
#pragma unroll
  for (int j = 0; j < 4; j++) r[j] = f2b((x[j] - mu) * rs);
  *(us4*)(lnout + row * 256 + lane * 4) = r;
}

// ---------------- rowwise LayerNorm over 256, fp32 in -> bf16 out ----------
__global__ __launch_bounds__(256) void ln_k(const float* __restrict__ src,
                                            unsigned short* __restrict__ dst) {
  size_t row = (size_t)blockIdx.x * 4 + (threadIdx.x >> 6);
  int lane = threadIdx.x & 63;
  float4 v = ((const float4*)(src + row * 256))[lane];
  float s = v.x + v.y + v.z + v.w;
#pragma unroll
  for (int o = 1; o < 64; o <<= 1) s += __shfl_xor(s, o);
  float mu = s * 0.00390625f;
  float dx = v.x - mu, dy = v.y - mu, dz = v.z - mu, dw = v.w - mu;
  float qv = dx * dx + dy * dy + dz * dz + dw * dw;
#pragma unroll
  for (int o = 1; o < 64; o <<= 1) qv += __shfl_xor(qv, o);
  float rs = rsqrtf(qv * 0.00390625f + 1e-5f);
  us4 r;
  r[0] = f2b(dx * rs); r[1] = f2b(dy * rs); r[2] = f2b(dz * rs); r[3] = f2b(dw * rs);
  *(us4*)(dst + row * 256 + lane * 4) = r;
}

// ---------------- pipelined dual GEMM: BM=128, BN=64(main)+64(pair) ----------
// 2-phase T3-lite: stage(next) || compute(cur); one barrier/iter (vmcnt in flight).
// EP1: store both halves (cols n_base.. and n_base+PAIR..), NOUT wide
// EP4: out = sigmoid(main+bias)*lnq + (pair+bias[+PAIR])   (adaLN), NOUT=256
// EP5: out = silu(main+bias)*(pair+bias[+PAIR])            (SwiGLU), NOUT=512
template <int K, int EP, int PAIR>
__global__ __launch_bounds__(256) void gemm4_k(
    const unsigned short* __restrict__ A, const unsigned short* __restrict__ Wt,
    const float* __restrict__ bias, unsigned short* __restrict__ out,
    const unsigned short* __restrict__ lnq, int NOUT) {
  constexpr int NT = K / 64;
  __shared__ __align__(16) unsigned short S[2][16384];  // per buf: A 8192 | B1 4096 | B2 4096
  const int tid = threadIdx.x;
  const int lane = tid & 63, w = tid >> 6;
  const int lg = lane >> 4, lr = lane & 15;
  const int wr = w >> 1, wc = w & 1;
  const size_t m_base = (size_t)blockIdx.x * 128;
  const size_t n_base = (size_t)blockIdx.y * 64;
  const int srow = w * 8 + (lane >> 3);
  const int scol = ((lane & 7) ^ (lane >> 3)) * 8;  // pre-swizzled global col
  const unsigned short* gA = A + (m_base + srow) * K + scol;
  const unsigned short* gB = Wt + (n_base + srow) * K + scol;
  const unsigned short* gB2 = Wt + (n_base + PAIR + srow) * K + scol;
  f32x4 acc[4][2] = {};
  f32x4 acc2[4][2] = {};
  const int swz = lr & 7;

  auto stage = [&](int buf, int t) {
    unsigned short* Sb = S[buf];
    const int kk = t * 64;
#pragma unroll
    for (int j = 0; j < 4; j++)
      gload16(gA + (size_t)(j * 32) * K + kk, Sb + w * 512 + j * 2048);
#pragma unroll
    for (int j = 0; j < 2; j++)
      gload16(gB + (size_t)(j * 32) * K + kk, Sb + 8192 + w * 512 + j * 2048);
#pragma unroll
    for (int j = 0; j < 2; j++)
      gload16(gB2 + (size_t)(j * 32) * K + kk, Sb + 12288 + w * 512 + j * 2048);
  };
  auto compute = [&](int buf) {
    const unsigned short* Sb = S[buf];
#pragma unroll
    for (int ks = 0; ks < 2; ks++) {
      const int co = ((ks * 4 + lg) ^ swz) << 3;
      bf16x8 af[4], b1[2], b2[2];
#pragma unroll
      for (int i = 0; i < 4; i++)
        af[i] = ld_bf8(Sb + (wr * 64 + i * 16 + lr) * 64 + co);
#pragma unroll
      for (int i = 0; i < 2; i++) {
        b1[i] = ld_bf8(Sb + 8192 + (wc * 32 + i * 16 + lr) * 64 + co);
        b2[i] = ld_bf8(Sb + 12288 + (wc * 32 + i * 16 + lr) * 64 + co);
      }
#pragma unroll
      for (int mi = 0; mi < 4; mi++)
#pragma unroll
        for (int ni = 0; ni < 2; ni++) {
          mfma_bf16(acc[mi][ni], af[mi], b1[ni]);
          mfma_bf16(acc2[mi][ni], af[mi], b2[ni]);
        }
    }
  };

  stage(0, 0);
  __syncthreads();
  int cur = 0;
  for (int t = 0; t < NT - 1; t++) {
    stage(cur ^ 1, t + 1);   // loads in flight under compute
    compute(cur);
    __syncthreads();         // drains vmcnt -> next buf ready; protects reuse
    cur ^= 1;
  }
  compute(cur);
  __syncthreads();

  unsigned short* St = S[0];
  if constexpr (EP == 1) {
#pragma unroll
    for (int half = 0; half < 2; half++) {
      int cbase = (int)n_base + half * PAIR;
#pragma unroll
      for (int mi = 0; mi < 4; mi++)
#pragma unroll
        for (int ni = 0; ni < 2; ni++)
#pragma unroll
          for (int r = 0; r < 4; r++) {
            int rowl = wr * 64 + mi * 16 + lg * 4 + r;
            int cl = wc * 32 + ni * 16 + lr;
            float v = (half ? acc2[mi][ni][r] : acc[mi][ni][r]) + bias[cbase + cl];
            St[rowl * 64 + (((cl >> 3) ^ (rowl & 7)) << 3) + (cl & 7)] = f2b(v);
          }
      __syncthreads();
#pragma unroll
      for (int p = 0; p < 4; p++) {
        int rowl = p * 32 + (tid >> 3);
        int chunk = tid & 7;
        us8 v = *(const us8*)(St + rowl * 64 + ((chunk ^ (rowl & 7)) << 3));
        *(us8*)(out + (m_base + rowl) * NOUT + cbase + chunk * 8) = v;
      }
      __syncthreads();
    }
  } else {
#pragma unroll
    for (int mi = 0; mi < 4; mi++)
#pragma unroll
      for (int ni = 0; ni < 2; ni++)
#pragma unroll
        for (int r = 0; r < 4; r++) {
          int rowl = wr * 64 + mi * 16 + lg * 4 + r;
          int cl = wc * 32 + ni * 16 + lr;
          size_t grow = m_base + rowl;
          int gcol = (int)n_base + cl;
          float v = acc[mi][ni][r] + bias[gcol];
          float v2 = acc2[mi][ni][r] + bias[gcol + PAIR];
          unsigned short res;
          if constexpr (EP == 4) {
            res = f2b(sigm(v) * b2f(lnq[grow * 256 + gcol]) + v2);
          } else {  // EP5
            res = f2b(v * sigm(v) * v2);
          }
          St[rowl * 64 + (((cl >> 3) ^ (rowl & 7)) << 3) + (cl & 7)] = res;
        }
    __syncthreads();
#pragma unroll
    for (int p = 0; p < 4; p++) {
      int rowl = p * 32 + (tid >> 3);
      int chunk = tid & 7;
      us8 v = *(const us8*)(St + rowl * 64 + ((chunk ^ (rowl & 7)) << 3));
      *(us8*)(out + (m_base + rowl) * NOUT + n_base + chunk * 8) = v;
    }
  }
}

// ---------------- residual GEMM + fused LayerNorm (pipelined) ---------------
// qf[row] += (GATED? sigmoid(gate[row*512+goff+col]) : 1) * (A@Wt^T)[row,col]
// then lnout[row] = LN(qf[row]) (optional affine). 64x256 tile, 8 waves.
template <int K, bool GATED>
__global__ __launch_bounds__(512) void gemmln_k(
    const unsigned short* __restrict__ A, const unsigned short* __restrict__ Wt,
    float* __restrict__ qf, const unsigned short* __restrict__ gate, int goff,
    unsigned short* __restrict__ lnout, const float* __restrict__ lng,
    const float* __restrict__ lnb) {
  constexpr int NT = K / 64;
  __shared__ __align__(16) unsigned short S[2][20480];  // per buf: A 4096 | B 16384
  const int tid = threadIdx.x;
  const int lane = tid & 63, w = tid >> 6;  // 8 waves
  const int lg = lane >> 4, lr = lane & 15;
  const size_t m_base = (size_t)blockIdx.x * 64;
  const int srow = lane >> 3;
  const int scol = ((lane & 7) ^ srow) * 8;
  const unsigned short* gA = A + (m_base + w * 8 + srow) * K + scol;
  const unsigned short* gB = Wt + (w * 32 + srow) * K + scol;
  f32x4 acc[4][2] = {};
  const int swz = lr & 7;

  auto stage = [&](int buf, int t) {
    unsigned short* Sb = S[buf];
    const int kk = t * 64;
    gload16(gA + kk, Sb + w * 512);
#pragma unroll
    for (int j = 0; j < 4; j++)
      gload16(gB + (size_t)(j * 8) * K + kk, Sb + 4096 + w * 2048 + j * 512);
  };
  auto compute = [&](int buf) {
    const unsigned short* Sb = S[buf];
#pragma unroll
    for (int ks = 0; ks < 2; ks++) {
      const int co = ((ks * 4 + lg) ^ swz) << 3;
      bf16x8 af[4], bf1[2];
#pragma unroll
      for (int i = 0; i < 4; i++) af[i] = ld_bf8(Sb + (i * 16 + lr) * 64 + co);
#pragma unroll
      for (int i = 0; i < 2; i++)
        bf1[i] = ld_bf8(Sb + 4096 + (w * 32 + i * 16 + lr) * 64 + co);
#pragma unroll
      for (int mi = 0; mi < 4; mi++)
#pragma unroll
        for (int ni = 0; ni < 2; ni++) mfma_bf16(acc[mi][ni], af[mi], bf1[ni]);
    }
  };

  stage(0, 0);
  __syncthreads();
  int cur = 0;
  for (int t = 0; t < NT - 1; t++) {
    stage(cur ^ 1, t + 1);
    compute(cur);
    __syncthreads();
    cur ^= 1;
  }
  compute(cur);
  __syncthreads();

  // epilogue: qf RMW + stash bf16(qf) swizzled in S[0]
  unsigned short* St = S[0];
#pragma unroll
  for (int mi = 0; mi < 4; mi++)
#pragma unroll
    for (int ni = 0; ni < 2; ni++)
#pragma unroll
      for (int r = 0; r < 4; r++) {
        int rowl = mi * 16 + lg * 4 + r;
        int col = w * 32 + ni * 16 + lr;
        size_t grow = m_base + rowl;
        float v = acc[mi][ni][r];
        if constexpr (GATED) v *= sigm(b2f(gate[grow * 512 + goff + col]));
        float nq = qf[grow * 256 + col] + v;
        qf[grow * 256 + col] = nq;
        St[rowl * 256 + (((col >> 3) ^ (rowl & 7)) << 3) + (col & 7)] = f2b(nq);
      }
  __syncthreads();
  float gv[4], bv[4];
  if (lng) {
#pragma unroll
    for (int j = 0; j < 4; j++) {
      gv[j] = lng[lane * 4 + j];
      bv[j] = lnb[lane * 4 + j];
    }
  }
  const int rchunk = lane >> 1;
  const int rsub = (lane & 1) << 2;
  for (int rr = 0; rr < 8; rr++) {
    int rowl = w * 8 + rr;
    us4 vv = *(const us4*)(St + rowl * 256 + ((rchunk ^ (rowl & 7)) << 3) + rsub);
    float x[4];
#pragma unroll
    for (int j = 0; j < 4; j++) x[j] = b2f(vv[j]);
    float s = x[0] + x[1] + x[2] + x[3];
    float sq = x[0] * x[0] + x[1] * x[1] + x[2] * x[2] + x[3] * x[3];
#pragma unroll
    for (int o = 1; o < 64; o <<= 1) {
      s += __shfl_xor(s, o);
      sq += __shfl_xor(sq, o);
    }
    float mu = s * 0.00390625f;
    float rs = rsqrtf(sq * 0.00390625f - mu * mu + 1e-5f);
    us4 r;
#pragma unroll
    for (int j = 0; j < 4; j++) {
      float y = (x[j] - mu) * rs;
      if (lng) y = y * gv[j] + bv[j];
      r[j] = f2b(y);
    }
    *(us4*)(lnout + (m_base + rowl) * 256 + lane * 4) = r;
  }
}

// ---------------- windowed spatial attention ----------------
__global__ __launch_bounds__(256) void attn_k(const unsigned short* __restrict__ big1,
                                              const unsigned short* __restrict__ biasb,
                                              unsigned short* __restrict__ o, int layer) {
  __shared__ __align__(16) unsigned short pl_s[4][32 * 128];
  __shared__ __align__(16) unsigned short vt_s[4][32 * 128];
  const int w = blockIdx.x, bt = blockIdx.y, hg = blockIdx.z;
  const int tid = threadIdx.x, wid = tid >> 6, lane = tid & 63;
  const int lg = lane >> 4, lr = lane & 15;
  const int h = hg * 4 + wid;
  unsigned short* pl = pl_s[wid];
  unsigned short* vt = vt_s[wid];
  const size_t base = (size_t)bt * M_;
  const float inv_s = 0.17677669529663687f;

  {
    const int chunk = lane & 3;
    const int krow = lane >> 2;
#pragma unroll
    for (int it = 0; it < 8; it++) {
      int key = it * 16 + krow;
      int ak = w * 32 - SIDE_ + key;
      int akc = ak < 0 ? 0 : (ak > M_ - 1 ? M_ - 1 : ak);
      us8 v = *(const us8*)(big1 + (base + akc) * 1024 + 512 + h * 32 + chunk * 8);
#pragma unroll
      for (int e = 0; e < 8; e++) {
        int d = chunk * 8 + e;
        vt[d * 128 + (key ^ ((d & 7) << 3))] = v[e];
      }
    }
  }
  bf16x8 aq[2];
#pragma unroll
  for (int mi = 0; mi < 2; mi++)
    aq[mi] = ld_bf8(big1 + (base + w * 32 + mi * 16 + lr) * 1024 + h * 32 + lg * 8);
  f32x4 lac[2][8] = {};
#pragma unroll
  for (int ni = 0; ni < 8; ni++) {
    int kidx = ni * 16 + lr;
    int ak = w * 32 - SIDE_ + kidx;
    int akc = ak < 0 ? 0 : (ak > M_ - 1 ? M_ - 1 : ak);
    bf16x8 bk = ld_bf8(big1 + (base + akc) * 1024 + 256 + h * 32 + lg * 8);
    mfma_bf16(lac[0][ni], aq[0], bk);
    mfma_bf16(lac[1][ni], aq[1], bk);
  }
  const unsigned short* brow0 =
      biasb + (((size_t)(layer * 8 + h)) * 4096 + w * 32) * 128;
#pragma unroll
  for (int mi = 0; mi < 2; mi++)
#pragma unroll
    for (int r = 0; r < 4; r++) {
      int qrow = mi * 16 + lg * 4 + r;
      const unsigned short* brow = brow0 + (size_t)qrow * 128;
      float lv[8];
      float mx = -3e38f;
#pragma unroll
      for (int ni = 0; ni < 8; ni++) {
        int kidx = ni * 16 + lr;
        int ak = w * 32 - SIDE_ + kidx;
        float x = lac[mi][ni][r] * inv_s + b2f(brow[kidx]) +
                  ((unsigned)ak < (unsigned)M_ ? 0.f : -1e9f);
        lv[ni] = x;
        mx = fmaxf(mx, x);
      }
#pragma unroll
      for (int off = 1; off < 16; off <<= 1) mx = fmaxf(mx, __shfl_xor(mx, off));
      float sum = 0.f;
#pragma unroll
      for (int ni = 0; ni < 8; ni++) {
        float e = __expf(lv[ni] - mx);
        lv[ni] = e;
        sum += e;
      }
#pragma unroll
      for (int off = 1; off < 16; off <<= 1) sum += __shfl_xor(sum, off);
      float inv = 1.f / sum;
      int sw = (qrow & 7) << 3;
#pragma unroll
      for (int ni = 0; ni < 8; ni++)
        pl[qrow * 128 + ((ni * 16 + lr) ^ sw)] = f2b(lv[ni] * inv);
    }
  f32x4 oc[2][2] = {};
#pragma unroll
  for (int ks = 0; ks < 4; ks++) {
    int kbase = ks * 32 + lg * 8;
    int kswz = kbase ^ ((lr & 7) << 3);
    bf16x8 ap0 = ld_bf8(pl + lr * 128 + kswz);
    bf16x8 ap1 = ld_bf8(pl + (16 + lr) * 128 + kswz);
    bf16x8 bv0 = ld_bf8(vt + lr * 128 + kswz);
    bf16x8 bv1 = ld_bf8(vt + (16 + lr) * 128 + kswz);
    mfma_bf16(oc[0][0], ap0, bv0);
    mfma_bf16(oc[0][1], ap0, bv1);
    mfma_bf16(oc[1][0], ap1, bv0);
    mfma_bf16(oc[1][1], ap1, bv1);
  }
#pragma unroll
  for (int mi = 0; mi < 2; mi++)
#pragma unroll
    for (int nd = 0; nd < 2; nd++)
#pragma unroll
      for (int r = 0; r < 4; r++) {
        int qrow = mi * 16 + lg * 4 + r;
        int d = nd * 16 + lr;
        size_t rowi = base + w * 32 + qrow;
        float gv = sigm(b2f(big1[rowi * 1024 + 768 + h * 32 + d]));
        o[rowi * 256 + h * 32 + d] = f2b(oc[mi][nd][r] * gv);
      }
}

// ---------------- temporal attention (T=8 per atom) ----------------
__global__ __launch_bounds__(256) void tattn_k(const unsigned short* __restrict__ big1,
                                               const float* __restrict__ ts,
                                               const float* __restrict__ tdec,
                                               unsigned short* __restrict__ o, int layer) {
  __shared__ __align__(16) unsigned short lds[4][8 * 768];
  int wid = threadIdx.x >> 6, lane = threadIdx.x & 63;
  int m = blockIdx.x * 4 + wid;
  unsigned short* Lp = lds[wid];
  for (int it = 0; it < 12; it++) {
    int u = it * 64 + lane;
    int t = u / 96, pos = (u % 96) * 8;
    *(uint4*)(Lp + t * 768 + pos) =
        *(const uint4*)(big1 + ((size_t)(t * M_ + m)) * 1024 + pos);
  }
  __syncthreads();
  int th = lane >> 3, qt = lane & 7;
  float decay = log1pf(__expf(tdec[layer * 8 + th]));
  float tsq = ts[qt];
  const float inv_t = 0.17677669529663687f;
  float tqv[32];
#pragma unroll
  for (int d = 0; d < 32; d++) tqv[d] = b2f(Lp[qt * 768 + th * 32 + d]);
  float lv[8];
  float mx = -3e38f;
#pragma unroll
  for (int kt = 0; kt < 8; kt++) {
    float dot = 0.f;
#pragma unroll
    for (int d = 0; d < 32; d++) dot += tqv[d] * b2f(Lp[kt * 768 + 256 + th * 32 + d]);
    float x = dot * inv_t - decay * fabsf(tsq - ts[kt]);
    lv[kt] = x;
    mx = fmaxf(mx, x);
  }
  float s = 0.f;
#pragma unroll
  for (int kt = 0; kt < 8; kt++) {
    float e = __expf(lv[kt] - mx);
    lv[kt] = e;
    s += e;
  }
  float inv = 1.f / s;
  float tov[32];
#pragma unroll
  for (int d = 0; d < 32; d++) tov[d] = 0.f;
#pragma unroll
  for (int kt = 0; kt < 8; kt++) {
    float p = lv[kt] * inv;
#pragma unroll
    for (int d = 0; d < 32; d++) tov[d] += p * b2f(Lp[kt * 768 + 512 + th * 32 + d]);
  }
  size_t orow = (size_t)qt * M_ + m;
#pragma unroll
  for (int d = 0; d < 32; d++) {
    float tg = sigm(b2f(big1[orow * 1024 + 768 + th * 32 + d]));
    o[orow * 256 + th * 32 + d] = f2b(tov[d] * tg);
  }
}

// ---------------- final: out = LN(qf, pos_g, pos_b) @ pos_w ----------------
__global__ __launch_bounds__(256) void final_k(const float* __restrict__ qf,
                                               const float* __restrict__ pg,
                                               const float* __restrict__ pb,
                                               const float* __restrict__ pw,
                                               float* __restrict__ out) {
  size_t row = (size_t)blockIdx.x * 4 + (threadIdx.x >> 6);
  int lane = threadIdx.x & 63;
  float4 v = ((const float4*)(qf + row * 256))[lane];
  float s = v.x + v.y + v.z + v.w;
#pragma unroll
  for (int o = 1; o < 64; o <<= 1) s += __shfl_xor(s, o);
  float mu = s * 0.00390625f;
  float dx = v.x - mu, dy = v.y - mu, dz = v.z - mu, dw = v.w - mu;
  float qv = dx * dx + dy * dy + dz * dz + dw * dw;
#pragma unroll
  for (int o = 1; o < 64; o <<= 1) qv += __shfl_xor(qv, o);
  float rs = rsqrtf(qv * 0.00390625f + 1e-5f);
  int d = lane * 4;
  float xn[4];
  xn[0] = dx * rs * pg[d] + pb[d];
  xn[1] = dy * rs * pg[d + 1] + pb[d + 1];
  xn[2] = dz * rs * pg[d + 2] + pb[d + 2];
  xn[3] = dw * rs * pg[d + 3] + pb[d + 3];
  float p0 = 0.f, p1 = 0.f, p2 = 0.f;
#pragma unroll
  for (int dd = 0; dd < 4; dd++) {
    const float* wr = pw + (size_t)(d + dd) * 3;
    p0 += xn[dd] * wr[0];
    p1 += xn[dd] * wr[1];
    p2 += xn[dd] * wr[2];
  }
#pragma unroll
  for (int o = 1; o < 64; o <<= 1) {
    p0 += __shfl_xor(p0, o);
    p1 += __shfl_xor(p1, o);
    p2 += __shfl_xor(p2, o);
  }
  if (lane == 0) {
    out[row * 3 + 0] = p0;
    out[row * 3 + 1] = p1;
    out[row * 3 + 2] = p2;
  }
}

extern "C" void kernel_launch(void* const* d_in, const int* in_sizes, int n_in,
                              void* d_out, int out_size, void* d_ws, size_t ws_size,
                              hipStream_t stream) {
  const float* a       = (const float*)d_in[0];
  const float* q_in    = (const float*)d_in[1];
  const float* c_in    = (const float*)d_in[2];
  const float* adb     = (const float*)d_in[3];
  const float* a2t     = (const float*)d_in[4];
  const float* ts      = (const float*)d_in[6];
  const float* W_a2q   = (const float*)d_in[7];
  const float* ada1_sw = (const float*)d_in[8];
  const float* ada1_sb = (const float*)d_in[9];
  const float* ada1_kw = (const float*)d_in[10];
  const float* attn_wq = (const float*)d_in[11];
  const float* attn_bq = (const float*)d_in[12];
  const float* attn_wk = (const float*)d_in[13];
  const float* attn_wv = (const float*)d_in[14];
  const float* attn_wg = (const float*)d_in[15];
  const float* attn_wo = (const float*)d_in[16];
  const float* og_w    = (const float*)d_in[17];
  const float* og_b    = (const float*)d_in[18];
  const float* ada2_sw = (const float*)d_in[19];
  const float* ada2_sb = (const float*)d_in[20];
  const float* ada2_kw = (const float*)d_in[21];
  const float* tr_w1   = (const float*)d_in[22];
  const float* tr_w2   = (const float*)d_in[23];
  const float* tr_w3   = (const float*)d_in[24];
  const float* tr_gw   = (const float*)d_in[25];
  const float* tr_gb   = (const float*)d_in[26];
  const float* t_ln_g  = (const float*)d_in[27];
  const float* t_ln_b  = (const float*)d_in[28];
  const float* t_wq    = (const float*)d_in[29];
  const float* t_wk    = (const float*)d_in[30];
  const float* t_wv    = (const float*)d_in[31];
  const float* t_wg    = (const float*)d_in[32];
  const float* t_wo    = (const float*)d_in[33];
  const float* t_dec   = (const float*)d_in[34];
  const float* pos_g   = (const float*)d_in[35];
  const float* pos_b   = (const float*)d_in[36];
  const float* pos_w   = (const float*)d_in[37];

  // ---- workspace layout, ~209 MB ----
  char* base = (char*)d_ws;
  size_t off = 0;
  auto alloc = [&](size_t bytes) {
    void* p = base + off;
    off += (bytes + 255) & ~(size_t)255;
    return p;
  };
  float* qf            = (float*)alloc(Fq * 4);              // 32 MiB
  unsigned short* lncb = (unsigned short*)alloc(Fq * 2);     // 16 MiB
  unsigned short* lnqb = (unsigned short*)alloc(Fq * 2);     // 16 MiB
  unsigned short* obuf = (unsigned short*)alloc(Fq * 2);     // 16 MiB
  unsigned short* big1 = (unsigned short*)alloc(Fq * 8);     // 64 MiB (xbuf/ggate/abf/tokf alias)
  unsigned short* bbuf = (unsigned short*)alloc(Fq * 2);     // 16 MiB
  unsigned short* cbf  = (unsigned short*)alloc(Fq * 2);     // 16 MiB
  unsigned short* biasb= (unsigned short*)alloc((size_t)24 * 4096 * 128 * 2);  // 24 MiB
  unsigned short* wbf  = (unsigned short*)alloc((size_t)4718592 * 2);          // 9 MiB
  float* biasr         = (float*)alloc(8704 * 4);
  int* tokidx          = (int*)alloc(4096 * 4);

  unsigned short* xbuf  = big1;                     // R*512, lower half
  unsigned short* ggate = big1 + (size_t)R_ * 512;  // R*512, upper half (dead window)
  unsigned short* abf   = big1;                     // 8192*1536 (dead before layer 0)
  unsigned short* tokf  = big1 + 2 * Fq;            // 8192*256

  // ---- weight transpose-convert descriptors ----
  ConvArgs ca;
  int ne = 0;
  auto add = [&](const float* s, size_t doff, int K, int N) {
    ca.src[ne] = s; ca.doff[ne] = (int)doff; ca.Kd[ne] = K; ca.Nd[ne] = N; ne++;
  };
  constexpr size_t LW = 1441792;
  for (int i = 0; i < 3; i++) {
    size_t LB = (size_t)i * LW;
    add(ada1_sw + i * 65536, LB + 0, 256, 256);
    add(ada1_kw + i * 65536, LB + 65536, 256, 256);
    add(attn_wq + i * 65536, LB + 131072, 256, 256);
    add(attn_wk + i * 65536, LB + 196608, 256, 256);
    add(attn_wv + i * 65536, LB + 262144, 256, 256);
    add(attn_wg + i * 65536, LB + 327680, 256, 256);
    add(attn_wo + i * 65536, LB + 393216, 256, 256);
    add(og_w + i * 65536, LB + 458752, 256, 256);
    add(tr_gw + i * 65536, LB + 524288, 256, 256);
    add(ada2_sw + i * 65536, LB + 589824, 256, 256);
    add(ada2_kw + i * 65536, LB + 655360, 256, 256);
    add(tr_w1 + i * 131072, LB + 720896, 256, 512);
    add(tr_w2 + i * 131072, LB + 851968, 256, 512);
    add(tr_w3 + i * 131072, LB + 983040, 512, 256);
    add(t_wq + i * 65536, LB + 1114112, 256, 256);
    add(t_wk + i * 65536, LB + 1179648, 256, 256);
    add(t_wv + i * 65536, LB + 1245184, 256, 256);
    add(t_wg + i * 65536, LB + 1310720, 256, 256);
    add(t_wo + i * 65536, LB + 1376256, 256, 256);
  }
  add(W_a2q, 3 * LW, 1536, 256);
  ca.n = ne;

  conv_k<<<dim3(ne, 96), 256, 0, stream>>>(ca, wbf);
  bias_prep_k<<<1, 256, 0, stream>>>(attn_bq, ada1_sb, ada2_sb, og_b, tr_gb, biasr);
  tokidx_k<<<1024, 256, 0, stream>>>(a2t, tokidx);
  biasb_k<<<4096, 256, 0, stream>>>(adb, biasb);
  cvt_k<<<6144, 256, 0, stream>>>(a, abf, 1572864);
  cvt_k<<<4096, 256, 0, stream>>>(c_in, cbf, 1048576);
  gemm4_k<1536, 1, 128><<<dim3(64, 2), 256, 0, stream>>>(
      abf, wbf + 3 * LW, biasr, tokf, nullptr, 256);
  qfinitln_k<<<8192, 256, 0, stream>>>(q_in, tokf, tokidx, qf, lnqb);
  ln_k<<<8192, 256, 0, stream>>>(c_in, lncb);

  for (int i = 0; i < 3; i++) {
    size_t LB = (size_t)i * LW;
    const float* b_attn = biasr + 1024 + (size_t)i * 2560;
    const float* b_ada1 = b_attn + 1024;
    const float* b_ada2 = b_attn + 1536;
    const float* b_ogtr = b_attn + 2048;

    // adaLN 1 (fused combine with lnqb) -> bbuf
    gemm4_k<256, 4, 256><<<dim3(256, 4), 256, 0, stream>>>(
        lncb, wbf + LB, b_ada1, bbuf, lnqb, 256);
    // qkvg projections + spatial attention
    gemm4_k<256, 1, 512><<<dim3(256, 8), 256, 0, stream>>>(
        bbuf, wbf + LB + 131072, b_attn, big1, nullptr, 1024);
    attn_k<<<dim3(128, 8, 2), 256, 0, stream>>>(big1, biasb, obuf, i);
    // gates: [og | trg] = c @ [og_w | tr_gw] (pre-sigmoid), one dual dispatch
    gemm4_k<256, 1, 256><<<dim3(256, 4), 256, 0, stream>>>(
        cbf, wbf + LB + 458752, b_ogtr, ggate, nullptr, 512);
    // qf += sigmoid(og)*(o@wo), fused LN -> lnqb
    gemmln_k<256, true><<<512, 512, 0, stream>>>(
        obuf, wbf + LB + 393216, qf, ggate, 0, lnqb, nullptr, nullptr);
    // adaLN 2 -> bbuf
    gemm4_k<256, 4, 256><<<dim3(256, 4), 256, 0, stream>>>(
        lncb, wbf + LB + 589824, b_ada2, bbuf, lnqb, 256);
    // transition: xbuf = silu(t@w1)*(t@w2); qf += sig(trg)*(x@w3), LN(t_ln)
    gemm4_k<256, 5, 512><<<dim3(256, 8), 256, 0, stream>>>(
        bbuf, wbf + LB + 720896, biasr, xbuf, nullptr, 512);
    gemmln_k<512, true><<<512, 512, 0, stream>>>(
        xbuf, wbf + LB + 983040, qf, ggate, 256, lnqb,
        t_ln_g + (size_t)i * 256, t_ln_b + (size_t)i * 256);
    // temporal attention
    gemm4_k<256, 1, 512><<<dim3(256, 8), 256, 0, stream>>>(
        lnqb, wbf + LB + 1114112, biasr, big1, nullptr, 1024);
    tattn_k<<<1024, 256, 0, stream>>>(big1, ts, t_dec, obuf, i);
    gemmln_k<256, false><<<512, 512, 0, stream>>>(
        obuf, wbf + LB + 1376256, qf, nullptr, 0, lnqb, nullptr, nullptr);
  }
  final_k<<<8192, 256, 0, stream>>>(qf, pos_g, pos_b, pos_w, (float*)d_out);
}

// Round 6
// 1143.869 us; speedup vs baseline: 3.4224x; 1.0077x over previous
//
#include <hip/hip_runtime.h>
#include <cstddef>
#include <cstdint>

#define DEVI __device__ __forceinline__

typedef __attribute__((ext_vector_type(8))) __bf16 bf16x8;
typedef __attribute__((ext_vector_type(8))) unsigned short us8;
typedef __attribute__((ext_vector_type(4))) unsigned short us4;
typedef __attribute__((ext_vector_type(4))) float f32x4;

constexpr int B0_ = 1, T_ = 8, N_ = 1024, M_ = 4096, D_ = 256;
constexpr int BT_ = 8, NW_ = 128, WQ_ = 32, HK_ = 128, SIDE_ = 48;
constexpr int R_ = BT_ * M_;          // 32768 rows
constexpr size_t Fq = 8388608;        // R_*256 elements

DEVI unsigned short f2b(float f) {
  return __builtin_bit_cast(unsigned short, static_cast<__bf16>(f));
}
DEVI float b2f(unsigned short s) { return __uint_as_float(((unsigned)s) << 16); }
DEVI float sigm(float x) { return 1.0f / (1.0f + __expf(-x)); }
DEVI bf16x8 ld_bf8(const unsigned short* p) {
  return __builtin_bit_cast(bf16x8, *(const us8*)p);
}
DEVI bf16x8 pack_f8(float4 v0, float4 v1) {
  bf16x8 r;
  r[0] = (__bf16)v0.x; r[1] = (__bf16)v0.y; r[2] = (__bf16)v0.z; r[3] = (__bf16)v0.w;
  r[4] = (__bf16)v1.x; r[5] = (__bf16)v1.y; r[6] = (__bf16)v1.z; r[7] = (__bf16)v1.w;
  return r;
}
DEVI void mfma_bf16(f32x4& c, bf16x8 a, bf16x8 b) {
  c = __builtin_amdgcn_mfma_f32_16x16x32_bf16(a, b, c, 0, 0, 0);
}
// async global->LDS, 16B per lane; lds dest = wave-uniform base + lane*16
DEVI void gload16(const void* g, void* l) {
  __builtin_amdgcn_global_load_lds((__attribute__((address_space(1))) void*)g,
                                   (__attribute__((address_space(3))) void*)l, 16, 0, 0);
}

// ---------------- weight transpose-convert (fp32 [K][N] -> bf16 Wt[N][K]) ----
struct ConvArgs {
  const float* src[64];
  int doff[64];
  int Kd[64];
  int Nd[64];
  int n;
};

__global__ __launch_bounds__(256) void conv_k(ConvArgs ca, unsigned short* __restrict__ wbf) {
  int e = blockIdx.x;
  int K = ca.Kd[e], N = ca.Nd[e];
  int nx = N >> 6, nk = K >> 6;
  int t = blockIdx.y;
  if (t >= nx * nk) return;
  int tx = t % nx, tk = t / nx;
  const float* s = ca.src[e];
  unsigned short* d = wbf + ca.doff[e];
  int n = tx * 64 + (threadIdx.x & 63);
  int k0 = tk * 64 + (threadIdx.x >> 6) * 16;
  for (int r = 0; r < 16; r++) {
    int k = k0 + r;
    d[(size_t)n * K + k] = f2b(s[(size_t)k * N + n]);
  }
}

// ---------------- fp32 -> bf16 flat convert ----------------
__global__ __launch_bounds__(256) void cvt_k(const float* __restrict__ s,
                                             unsigned short* __restrict__ d, int n8) {
  int i = blockIdx.x * 256 + threadIdx.x;
  if (i >= n8) return;
  float4 v0 = *(const float4*)(s + (size_t)i * 8);
  float4 v1 = *(const float4*)(s + (size_t)i * 8 + 4);
  *(us8*)(d + (size_t)i * 8) = __builtin_bit_cast(us8, pack_f8(v0, v1));
}

// ---------------- bias concat prep ----------------
__global__ __launch_bounds__(256) void bias_prep_k(
    const float* __restrict__ bq, const float* __restrict__ sb1,
    const float* __restrict__ sb2, const float* __restrict__ ogb,
    const float* __restrict__ trb, float* __restrict__ bias) {
  int t = threadIdx.x;
  for (int i = t; i < 1024 + 3 * 2560; i += 256) bias[i] = 0.f;
  __syncthreads();
  for (int i = 0; i < 3; i++) {
    float* B = bias + 1024 + i * 2560;
    B[t]        = bq[i * 256 + t];
    B[1024 + t] = sb1[i * 256 + t];
    B[1536 + t] = sb2[i * 256 + t];
    B[2048 + t] = ogb[i * 256 + t];
    B[2304 + t] = trb[i * 256 + t];
  }
}

// ---- attn bias relayout -> biasb[(l*8+h)][row][lr(16)][ni(8)] bf16 (k = ni*16+lr)
__global__ __launch_bounds__(256) void biasb_k(const float* __restrict__ adb,
                                               unsigned short* __restrict__ biasb) {
  __shared__ float ld[3072];
  int rq = blockIdx.x;  // 0..4095
  int t = threadIdx.x;
  const float* src = adb + (size_t)rq * 3072;
  for (int i = t; i < 3072; i += 256) ld[i] = src[i];
  __syncthreads();
  int k = t & 127;
  int pk = (k & 15) * 8 + (k >> 4);   // fragment-layout permutation
  for (int lh = t >> 7; lh < 24; lh += 2)
    biasb[((size_t)lh * 4096 + rq) * 128 + pk] = f2b(ld[k * 24 + lh]);
}

// ---------------- tok idx from one-hot ----------------
__global__ __launch_bounds__(256) void tokidx_k(const float* __restrict__ a2t,
                                                int* __restrict__ idx) {
  int m = blockIdx.x * 4 + (threadIdx.x >> 6);
  int lane = threadIdx.x & 63;
  int best = -1;
  for (int j = 0; j < 16; j++) {
    int col = lane * 16 + j;
    if (a2t[(size_t)m * 1024 + col] > 0.5f) best = col;
  }
#pragma unroll
  for (int off = 1; off < 64; off <<= 1) best = max(best, __shfl_xor(best, off));
  if (lane == 0) idx[m] = best;
}

// ---------------- qf = q + tokfeat[gather], fused LN -> lnqb ----------------
__global__ __launch_bounds__(256) void qfinitln_k(const float* __restrict__ q,
                                                  const unsigned short* __restrict__ tokf,
                                                  const int* __restrict__ idx,
                                                  float* __restrict__ qf,
                                                  unsigned short* __restrict__ lnout) {
  int wid = threadIdx.x >> 6, lane = threadIdx.x & 63;
  size_t row = (size_t)blockIdx.x * 4 + wid;
  int m = (int)(row & 4095);
  int bt = (int)(row >> 12);
  float4 qv = *(const float4*)(q + row * 256 + lane * 4);
  us4 tv = *(const us4*)(tokf + ((size_t)bt * 1024 + idx[m]) * 256 + lane * 4);
  float x[4];
  x[0] = qv.x + b2f(tv[0]); x[1] = qv.y + b2f(tv[1]);
  x[2] = qv.z + b2f(tv[2]); x[3] = qv.w + b2f(tv[3]);
  *(float4*)(qf + row * 256 + lane * 4) = make_float4(x[0], x[1], x[2], x[3]);
  float s = x[0] + x[1] + x[2] + x[3];
  float sq = x[0] * x[0] + x[1] * x[1] + x[2] * x[2] + x[3] * x[3];
#pragma unroll
  for (int o = 1; o < 64; o <<= 1) {
    s += __shfl_xor(s, o);
    sq += __shfl_xor(sq, o);
  }
  float mu = s * 0.00390625f;
  float rs = rsqrtf(sq * 0.00390625f - mu * mu + 1e-5f);
  us4 r;
#pragma unroll
  for (int j = 0; j < 4; j++) r[j] = f2b((x[j] - mu) * rs);
  *(us4*)(lnout + row * 256 + lane * 4) = r;
}

// ---------------- rowwise LayerNorm over 256, fp32 in -> bf16 out ----------
__global__ __launch_bounds__(256) void ln_k(const float* __restrict__ src,
                                            unsigned short* __restrict__ dst) {
  size_t row = (size_t)blockIdx.x * 4 + (threadIdx.x >> 6);
  int lane = threadIdx.x & 63;
  float4 v = ((const float4*)(src + row * 256))[lane];
  float s = v.x + v.y + v.z + v.w;
#pragma unroll
  for (int o = 1; o < 64; o <<= 1) s += __shfl_xor(s, o);
  float mu = s * 0.00390625f;
  float dx = v.x - mu, dy = v.y - mu, dz = v.z - mu, dw = v.w - mu;
  float qv = dx * dx + dy * dy + dz * dz + dw * dw;
#pragma unroll
  for (int o = 1; o < 64; o <<= 1) qv += __shfl_xor(qv, o);
  float rs = rsqrtf(qv * 0.00390625f + 1e-5f);
  us4 r;
  r[0] = f2b(dx * rs); r[1] = f2b(dy * rs); r[2] = f2b(dz * rs); r[3] = f2b(dw * rs);
  *(us4*)(dst + row * 256 + lane * 4) = r;
}

// ---------------- pipelined dual GEMM: BM=128, BN=64(main)+64(pair) ----------
// EP1: store both halves; EP4: adaLN combine; EP5: SwiGLU combine
// EP6 (qkvg): main -> out; pair: n_base<256 -> TRANSPOSED store to vtb (v cols),
//             else normal store to out at +512 (g cols)
template <int K, int EP, int PAIR>
__global__ __launch_bounds__(256) void gemm4_k(
    const unsigned short* __restrict__ A, const unsigned short* __restrict__ Wt,
    const float* __restrict__ bias, unsigned short* __restrict__ out,
    const unsigned short* __restrict__ lnq, unsigned short* __restrict__ vtb,
    int NOUT) {
  constexpr int NT = K / 64;
  __shared__ __align__(16) unsigned short S[2][16384];  // per buf: A 8192 | B1 4096 | B2 4096
  const int tid = threadIdx.x;
  const int lane = tid & 63, w = tid >> 6;
  const int lg = lane >> 4, lr = lane & 15;
  const int wr = w >> 1, wc = w & 1;
  const size_t m_base = (size_t)blockIdx.x * 128;
  const size_t n_base = (size_t)blockIdx.y * 64;
  const int srow = w * 8 + (lane >> 3);
  const int scol = ((lane & 7) ^ (lane >> 3)) * 8;  // pre-swizzled global col
  const unsigned short* gA = A + (m_base + srow) * K + scol;
  const unsigned short* gB = Wt + (n_base + srow) * K + scol;
  const unsigned short* gB2 = Wt + (n_base + PAIR + srow) * K + scol;
  f32x4 acc[4][2] = {};
  f32x4 acc2[4][2] = {};
  const int swz = lr & 7;

  auto stage = [&](int buf, int t) {
    unsigned short* Sb = S[buf];
    const int kk = t * 64;
#pragma unroll
    for (int j = 0; j < 4; j++)
      gload16(gA + (size_t)(j * 32) * K + kk, Sb + w * 512 + j * 2048);
#pragma unroll
    for (int j = 0; j < 2; j++)
      gload16(gB + (size_t)(j * 32) * K + kk, Sb + 8192 + w * 512 + j * 2048);
#pragma unroll
    for (int j = 0; j < 2; j++)
      gload16(gB2 + (size_t)(j * 32) * K + kk, Sb + 12288 + w * 512 + j * 2048);
  };
  auto compute = [&](int buf) {
    const unsigned short* Sb = S[buf];
#pragma unroll
    for (int ks = 0; ks < 2; ks++) {
      const int co = ((ks * 4 + lg) ^ swz) << 3;
      bf16x8 af[4], b1[2], b2[2];
#pragma unroll
      for (int i = 0; i < 4; i++)
        af[i] = ld_bf8(Sb + (wr * 64 + i * 16 + lr) * 64 + co);
#pragma unroll
      for (int i = 0; i < 2; i++) {
        b1[i] = ld_bf8(Sb + 8192 + (wc * 32 + i * 16 + lr) * 64 + co);
        b2[i] = ld_bf8(Sb + 12288 + (wc * 32 + i * 16 + lr) * 64 + co);
      }
#pragma unroll
      for (int mi = 0; mi < 4; mi++)
#pragma unroll
        for (int ni = 0; ni < 2; ni++) {
          mfma_bf16(acc[mi][ni], af[mi], b1[ni]);
          mfma_bf16(acc2[mi][ni], af[mi], b2[ni]);
        }
    }
  };

  stage(0, 0);
  __syncthreads();
  int cur = 0;
  for (int t = 0; t < NT - 1; t++) {
    stage(cur ^ 1, t + 1);   // loads in flight under compute
    compute(cur);
    __syncthreads();
    cur ^= 1;
  }
  compute(cur);
  __syncthreads();

  unsigned short* St = S[0];
  auto emit_half = [&](int cbase, bool second) {
#pragma unroll
    for (int mi = 0; mi < 4; mi++)
#pragma unroll
      for (int ni = 0; ni < 2; ni++)
#pragma unroll
        for (int r = 0; r < 4; r++) {
          int rowl = wr * 64 + mi * 16 + lg * 4 + r;
          int cl = wc * 32 + ni * 16 + lr;
          float v = (second ? acc2[mi][ni][r] : acc[mi][ni][r]) + bias[cbase + cl];
          St[rowl * 64 + (((cl >> 3) ^ (rowl & 7)) << 3) + (cl & 7)] = f2b(v);
        }
    __syncthreads();
#pragma unroll
    for (int p = 0; p < 4; p++) {
      int rowl = p * 32 + (tid >> 3);
      int chunk = tid & 7;
      us8 v = *(const us8*)(St + rowl * 64 + ((chunk ^ (rowl & 7)) << 3));
      *(us8*)(out + (m_base + rowl) * NOUT + cbase + chunk * 8) = v;
    }
    __syncthreads();
  };

  if constexpr (EP == 1) {
    emit_half((int)n_base, false);
    emit_half((int)n_base + PAIR, true);
  } else if constexpr (EP == 6) {
    emit_half((int)n_base, false);
    if ((int)n_base < 256) {
      // v columns: transposed store into vtb[(bt*256 + hd)][atom]
      const int bt = (int)(m_base >> 12);
      const int m0 = (int)(m_base & 4095);
#pragma unroll
      for (int mi = 0; mi < 4; mi++)
#pragma unroll
        for (int ni = 0; ni < 2; ni++) {
          int cl = wc * 32 + ni * 16 + lr;
          int rowb = wr * 64 + mi * 16 + lg * 4;
          us4 val;
#pragma unroll
          for (int r = 0; r < 4; r++)
            val[r] = f2b(acc2[mi][ni][r] + bias[(int)n_base + cl + 512]);
          *(us4*)(St + cl * 128 + (((rowb >> 3) ^ (cl & 7)) << 3) + (rowb & 7)) = val;
        }
      __syncthreads();
#pragma unroll
      for (int p = 0; p < 4; p++) {
        int cl = tid >> 2;
        int rc = (tid & 3) + p * 4;
        us8 v = *(const us8*)(St + cl * 128 + ((rc ^ (cl & 7)) << 3));
        *(us8*)(vtb + ((size_t)bt * 256 + n_base + cl) * 4096 + m0 + rc * 8) = v;
      }
    } else {
      emit_half((int)n_base + 512, true);
    }
  } else {
#pragma unroll
    for (int mi = 0; mi < 4; mi++)
#pragma unroll
      for (int ni = 0; ni < 2; ni++)
#pragma unroll
        for (int r = 0; r < 4; r++) {
          int rowl = wr * 64 + mi * 16 + lg * 4 + r;
          int cl = wc * 32 + ni * 16 + lr;
          size_t grow = m_base + rowl;
          int gcol = (int)n_base + cl;
          float v = acc[mi][ni][r] + bias[gcol];
          float v2 = acc2[mi][ni][r] + bias[gcol + PAIR];
          unsigned short res;
          if constexpr (EP == 4) {
            res = f2b(sigm(v) * b2f(lnq[grow * 256 + gcol]) + v2);
          } else {  // EP5
            res = f2b(v * sigm(v) * v2);
          }
          St[rowl * 64 + (((cl >> 3) ^ (rowl & 7)) << 3) + (cl & 7)] = res;
        }
    __syncthreads();
#pragma unroll
    for (int p = 0; p < 4; p++) {
      int rowl = p * 32 + (tid >> 3);
      int chunk = tid & 7;
      us8 v = *(const us8*)(St + rowl * 64 + ((chunk ^ (rowl & 7)) << 3));
      *(us8*)(out + (m_base + rowl) * NOUT + n_base + chunk * 8) = v;
    }
  }
}

// ---------------- residual GEMM + fused LayerNorm (pipelined) ---------------
template <int K, bool GATED>
__global__ __launch_bounds__(512) void gemmln_k(
    const unsigned short* __restrict__ A, const unsigned short* __restrict__ Wt,
    float* __restrict__ qf, const unsigned short* __restrict__ gate, int goff,
    unsigned short* __restrict__ lnout, const float* __restrict__ lng,
    const float* __restrict__ lnb) {
  constexpr int NT = K / 64;
  __shared__ __align__(16) unsigned short S[2][20480];  // per buf: A 4096 | B 16384
  const int tid = threadIdx.x;
  const int lane = tid & 63, w = tid >> 6;  // 8 waves
  const int lg = lane >> 4, lr = lane & 15;
  const size_t m_base = (size_t)blockIdx.x * 64;
  const int srow = lane >> 3;
  const int scol = ((lane & 7) ^ srow) * 8;
  const unsigned short* gA = A + (m_base + w * 8 + srow) * K + scol;
  const unsigned short* gB = Wt + (w * 32 + srow) * K + scol;
  f32x4 acc[4][2] = {};
  const int swz = lr & 7;

  auto stage = [&](int buf, int t) {
    unsigned short* Sb = S[buf];
    const int kk = t * 64;
    gload16(gA + kk, Sb + w * 512);
#pragma unroll
    for (int j = 0; j < 4; j++)
      gload16(gB + (size_t)(j * 8) * K + kk, Sb + 4096 + w * 2048 + j * 512);
  };
  auto compute = [&](int buf) {
    const unsigned short* Sb = S[buf];
#pragma unroll
    for (int ks = 0; ks < 2; ks++) {
      const int co = ((ks * 4 + lg) ^ swz) << 3;
      bf16x8 af[4], bf1[2];
#pragma unroll
      for (int i = 0; i < 4; i++) af[i] = ld_bf8(Sb + (i * 16 + lr) * 64 + co);
#pragma unroll
      for (int i = 0; i < 2; i++)
        bf1[i] = ld_bf8(Sb + 4096 + (w * 32 + i * 16 + lr) * 64 + co);
#pragma unroll
      for (int mi = 0; mi < 4; mi++)
#pragma unroll
        for (int ni = 0; ni < 2; ni++) mfma_bf16(acc[mi][ni], af[mi], bf1[ni]);
    }
  };

  stage(0, 0);
  __syncthreads();
  int cur = 0;
  for (int t = 0; t < NT - 1; t++) {
    stage(cur ^ 1, t + 1);
    compute(cur);
    __syncthreads();
    cur ^= 1;
  }
  compute(cur);
  __syncthreads();

  unsigned short* St = S[0];
#pragma unroll
  for (int mi = 0; mi < 4; mi++)
#pragma unroll
    for (int ni = 0; ni < 2; ni++)
#pragma unroll
      for (int r = 0; r < 4; r++) {
        int rowl = mi * 16 + lg * 4 + r;
        int col = w * 32 + ni * 16 + lr;
        size_t grow = m_base + rowl;
        float v = acc[mi][ni][r];
        if constexpr (GATED) v *= sigm(b2f(gate[grow * 512 + goff + col]));
        float nq = qf[grow * 256 + col] + v;
        qf[grow * 256 + col] = nq;
        St[rowl * 256 + (((col >> 3) ^ (rowl & 7)) << 3) + (col & 7)] = f2b(nq);
      }
  __syncthreads();
  float gv[4], bv[4];
  if (lng) {
#pragma unroll
    for (int j = 0; j < 4; j++) {
      gv[j] = lng[lane * 4 + j];
      bv[j] = lnb[lane * 4 + j];
    }
  }
  const int rchunk = lane >> 1;
  const int rsub = (lane & 1) << 2;
  for (int rr = 0; rr < 8; rr++) {
    int rowl = w * 8 + rr;
    us4 vv = *(const us4*)(St + rowl * 256 + ((rchunk ^ (rowl & 7)) << 3) + rsub);
    float x[4];
#pragma unroll
    for (int j = 0; j < 4; j++) x[j] = b2f(vv[j]);
    float s = x[0] + x[1] + x[2] + x[3];
    float sq = x[0] * x[0] + x[1] * x[1] + x[2] * x[2] + x[3] * x[3];
#pragma unroll
    for (int o = 1; o < 64; o <<= 1) {
      s += __shfl_xor(s, o);
      sq += __shfl_xor(sq, o);
    }
    float mu = s * 0.00390625f;
    float rs = rsqrtf(sq * 0.00390625f - mu * mu + 1e-5f);
    us4 r;
#pragma unroll
    for (int j = 0; j < 4; j++) {
      float y = (x[j] - mu) * rs;
      if (lng) y = y * gv[j] + bv[j];
      r[j] = f2b(y);
    }
    *(us4*)(lnout + (m_base + rowl) * 256 + lane * 4) = r;
  }
}

// ---------------- windowed spatial attention (vectorized, XCD-chunked) ------
__global__ __launch_bounds__(256) void attn_k(const unsigned short* __restrict__ big1,
                                              const unsigned short* __restrict__ vtbuf,
                                              const unsigned short* __restrict__ biasb,
                                              unsigned short* __restrict__ o, int layer) {
  __shared__ __align__(16) unsigned short pl_s[4][32 * 128];
  __shared__ __align__(16) unsigned short vt_s[4][32 * 128];
  const int bid = blockIdx.x;
  const int nid = (bid & 7) * 256 + (bid >> 3);  // XCD-chunked remap
  const int w = nid & 127, bt = (nid >> 7) & 7, hg = nid >> 10;
  const int tid = threadIdx.x, wid = tid >> 6, lane = tid & 63;
  const int lg = lane >> 4, lr = lane & 15;
  const int h = hg * 4 + wid;
  unsigned short* pl = pl_s[wid];
  unsigned short* vt = vt_s[wid];
  const size_t base = (size_t)bt * M_;
  const float inv_s = 0.17677669529663687f;

  // stage V^T from vtbuf: us8 loads + us8 chunk-swizzled LDS writes
  {
    const int d = lane >> 1, half = lane & 1;
    const unsigned short* src = vtbuf + ((size_t)bt * 256 + h * 32 + d) * 4096;
    const int k0 = w * 32 - SIDE_ + half * 64;
    unsigned short* dst = vt + d * 128;
#pragma unroll
    for (int c = 0; c < 8; c++) {
      int ak = k0 + c * 8;
      ak = ak < 0 ? 0 : (ak > M_ - 8 ? M_ - 8 : ak);  // OOB keys masked later
      us8 v = *(const us8*)(src + ak);
      const int chunk = half * 8 + c;
      *(us8*)(dst + ((chunk ^ (d & 7)) << 3)) = v;
    }
  }
  // QK^T via MFMA (K-dim = dh = 32)
  bf16x8 aq[2];
#pragma unroll
  for (int mi = 0; mi < 2; mi++)
    aq[mi] = ld_bf8(big1 + (base + w * 32 + mi * 16 + lr) * 1024 + h * 32 + lg * 8);
  f32x4 lac[2][8] = {};
#pragma unroll
  for (int ni = 0; ni < 8; ni++) {
    int kidx = ni * 16 + lr;
    int ak = w * 32 - SIDE_ + kidx;
    int akc = ak < 0 ? 0 : (ak > M_ - 1 ? M_ - 1 : ak);
    bf16x8 bk = ld_bf8(big1 + (base + akc) * 1024 + 256 + h * 32 + lg * 8);
    mfma_bf16(lac[0][ni], aq[0], bk);
    mfma_bf16(lac[1][ni], aq[1], bk);
  }
  // bias (us8, fragment-permuted layout) + mask + softmax; p -> swizzled LDS
  const unsigned short* bb0 =
      biasb + (((size_t)(layer * 8 + h)) * 4096 + w * 32) * 128 + lr * 8;
#pragma unroll
  for (int mi = 0; mi < 2; mi++)
#pragma unroll
    for (int r = 0; r < 4; r++) {
      int qrow = mi * 16 + lg * 4 + r;
      us8 bb = *(const us8*)(bb0 + (size_t)qrow * 128);
      float lv[8];
      float mx = -3e38f;
#pragma unroll
      for (int ni = 0; ni < 8; ni++) {
        int ak = w * 32 - SIDE_ + ni * 16 + lr;
        float x = lac[mi][ni][r] * inv_s + b2f(bb[ni]) +
                  ((unsigned)ak < (unsigned)M_ ? 0.f : -1e9f);
        lv[ni] = x;
        mx = fmaxf(mx, x);
      }
#pragma unroll
      for (int off = 1; off < 16; off <<= 1) mx = fmaxf(mx, __shfl_xor(mx, off));
      float sum = 0.f;
#pragma unroll
      for (int ni = 0; ni < 8; ni++) {
        float e = __expf(lv[ni] - mx);
        lv[ni] = e;
        sum += e;
      }
#pragma unroll
      for (int off = 1; off < 16; off <<= 1) sum += __shfl_xor(sum, off);
      float inv = 1.f / sum;
      int sw = (qrow & 7) << 3;
#pragma unroll
      for (int ni = 0; ni < 8; ni++)
        pl[qrow * 128 + ((ni * 16 + lr) ^ sw)] = f2b(lv[ni] * inv);
    }
  // PV via MFMA over 128 keys (wave-private LDS: no barrier needed)
  f32x4 oc[2][2] = {};
#pragma unroll
  for (int ks = 0; ks < 4; ks++) {
    int kbase = ks * 32 + lg * 8;
    int kswz = kbase ^ ((lr & 7) << 3);
    bf16x8 ap0 = ld_bf8(pl + lr * 128 + kswz);
    bf16x8 ap1 = ld_bf8(pl + (16 + lr) * 128 + kswz);
    bf16x8 bv0 = ld_bf8(vt + lr * 128 + kswz);
    bf16x8 bv1 = ld_bf8(vt + (16 + lr) * 128 + kswz);
    mfma_bf16(oc[0][0], ap0, bv0);
    mfma_bf16(oc[0][1], ap0, bv1);
    mfma_bf16(oc[1][0], ap1, bv0);
    mfma_bf16(oc[1][1], ap1, bv1);
  }
#pragma unroll
  for (int mi = 0; mi < 2; mi++)
#pragma unroll
    for (int nd = 0; nd < 2; nd++)
#pragma unroll
      for (int r = 0; r < 4; r++) {
        int qrow = mi * 16 + lg * 4 + r;
        int d = nd * 16 + lr;
        size_t rowi = base + w * 32 + qrow;
        float gv = sigm(b2f(big1[rowi * 1024 + 768 + h * 32 + d]));
        o[rowi * 256 + h * 32 + d] = f2b(oc[mi][nd][r] * gv);
      }
}

// ---------------- temporal attention (T=8 per atom) ----------------
__global__ __launch_bounds__(256) void tattn_k(const unsigned short* __restrict__ big1,
                                               const float* __restrict__ ts,
                                               const float* __restrict__ tdec,
                                               unsigned short* __restrict__ o, int layer) {
  __shared__ __align__(16) unsigned short lds[4][8 * 768];
  int wid = threadIdx.x >> 6, lane = threadIdx.x & 63;
  int m = blockIdx.x * 4 + wid;
  unsigned short* Lp = lds[wid];
  for (int it = 0; it < 12; it++) {
    int u = it * 64 + lane;
    int t = u / 96, pos = (u % 96) * 8;
    *(uint4*)(Lp + t * 768 + pos) =
        *(const uint4*)(big1 + ((size_t)(t * M_ + m)) * 1024 + pos);
  }
  __syncthreads();
  int th = lane >> 3, qt = lane & 7;
  float decay = log1pf(__expf(tdec[layer * 8 + th]));
  float tsq = ts[qt];
  const float inv_t = 0.17677669529663687f;
  float tqv[32];
#pragma unroll
  for (int d = 0; d < 32; d++) tqv[d] = b2f(Lp[qt * 768 + th * 32 + d]);
  float lv[8];
  float mx = -3e38f;
#pragma unroll
  for (int kt = 0; kt < 8; kt++) {
    float dot = 0.f;
#pragma unroll
    for (int d = 0; d < 32; d++) dot += tqv[d] * b2f(Lp[kt * 768 + 256 + th * 32 + d]);
    float x = dot * inv_t - decay * fabsf(tsq - ts[kt]);
    lv[kt] = x;
    mx = fmaxf(mx, x);
  }
  float s = 0.f;
#pragma unroll
  for (int kt = 0; kt < 8; kt++) {
    float e = __expf(lv[kt] - mx);
    lv[kt] = e;
    s += e;
  }
  float inv = 1.f / s;
  float tov[32];
#pragma unroll
  for (int d = 0; d < 32; d++) tov[d] = 0.f;
#pragma unroll
  for (int kt = 0; kt < 8; kt++) {
    float p = lv[kt] * inv;
#pragma unroll
    for (int d = 0; d < 32; d++) tov[d] += p * b2f(Lp[kt * 768 + 512 + th * 32 + d]);
  }
  size_t orow = (size_t)qt * M_ + m;
#pragma unroll
  for (int d = 0; d < 32; d++) {
    float tg = sigm(b2f(big1[orow * 1024 + 768 + th * 32 + d]));
    o[orow * 256 + th * 32 + d] = f2b(tov[d] * tg);
  }
}

// ---------------- final: out = LN(qf, pos_g, pos_b) @ pos_w ----------------
__global__ __launch_bounds__(256) void final_k(const float* __restrict__ qf,
                                               const float* __restrict__ pg,
                                               const float* __restrict__ pb,
                                               const float* __restrict__ pw,
                                               float* __restrict__ out) {
  size_t row = (size_t)blockIdx.x * 4 + (threadIdx.x >> 6);
  int lane = threadIdx.x & 63;
  float4 v = ((const float4*)(qf + row * 256))[lane];
  float s = v.x + v.y + v.z + v.w;
#pragma unroll
  for (int o = 1; o < 64; o <<= 1) s += __shfl_xor(s, o);
  float mu = s * 0.00390625f;
  float dx = v.x - mu, dy = v.y - mu, dz = v.z - mu, dw = v.w - mu;
  float qv = dx * dx + dy * dy + dz * dz + dw * dw;
#pragma unroll
  for (int o = 1; o < 64; o <<= 1) qv += __shfl_xor(qv, o);
  float rs = rsqrtf(qv * 0.00390625f + 1e-5f);
  int d = lane * 4;
  float xn[4];
  xn[0] = dx * rs * pg[d] + pb[d];
  xn[1] = dy * rs * pg[d + 1] + pb[d + 1];
  xn[2] = dz * rs * pg[d + 2] + pb[d + 2];
  xn[3] = dw * rs * pg[d + 3] + pb[d + 3];
  float p0 = 0.f, p1 = 0.f, p2 = 0.f;
#pragma unroll
  for (int dd = 0; dd < 4; dd++) {
    const float* wr = pw + (size_t)(d + dd) * 3;
    p0 += xn[dd] * wr[0];
    p1 += xn[dd] * wr[1];
    p2 += xn[dd] * wr[2];
  }
#pragma unroll
  for (int o = 1; o < 64; o <<= 1) {
    p0 += __shfl_xor(p0, o);
    p1 += __shfl_xor(p1, o);
    p2 += __shfl_xor(p2, o);
  }
  if (lane == 0) {
    out[row * 3 + 0] = p0;
    out[row * 3 + 1] = p1;
    out[row * 3 + 2] = p2;
  }
}

extern "C" void kernel_launch(void* const* d_in, const int* in_sizes, int n_in,
                              void* d_out, int out_size, void* d_ws, size_t ws_size,
                              hipStream_t stream) {
  const float* a       = (const float*)d_in[0];
  const float* q_in    = (const float*)d_in[1];
  const float* c_in    = (const float*)d_in[2];
  const float* adb     = (const float*)d_in[3];
  const float* a2t     = (const float*)d_in[4];
  const float* ts      = (const float*)d_in[6];
  const float* W_a2q   = (const float*)d_in[7];
  const float* ada1_sw = (const float*)d_in[8];
  const float* ada1_sb = (const float*)d_in[9];
  const float* ada1_kw = (const float*)d_in[10];
  const float* attn_wq = (const float*)d_in[11];
  const float* attn_bq = (const float*)d_in[12];
  const float* attn_wk = (const float*)d_in[13];
  const float* attn_wv = (const float*)d_in[14];
  const float* attn_wg = (const float*)d_in[15];
  const float* attn_wo = (const float*)d_in[16];
  const float* og_w    = (const float*)d_in[17];
  const float* og_b    = (const float*)d_in[18];
  const float* ada2_sw = (const float*)d_in[19];
  const float* ada2_sb = (const float*)d_in[20];
  const float* ada2_kw = (const float*)d_in[21];
  const float* tr_w1   = (const float*)d_in[22];
  const float* tr_w2   = (const float*)d_in[23];
  const float* tr_w3   = (const float*)d_in[24];
  const float* tr_gw   = (const float*)d_in[25];
  const float* tr_gb   = (const float*)d_in[26];
  const float* t_ln_g  = (const float*)d_in[27];
  const float* t_ln_b  = (const float*)d_in[28];
  const float* t_wq    = (const float*)d_in[29];
  const float* t_wk    = (const float*)d_in[30];
  const float* t_wv    = (const float*)d_in[31];
  const float* t_wg    = (const float*)d_in[32];
  const float* t_wo    = (const float*)d_in[33];
  const float* t_dec   = (const float*)d_in[34];
  const float* pos_g   = (const float*)d_in[35];
  const float* pos_b   = (const float*)d_in[36];
  const float* pos_w   = (const float*)d_in[37];

  // ---- workspace layout, ~225 MB ----
  char* base = (char*)d_ws;
  size_t off = 0;
  auto alloc = [&](size_t bytes) {
    void* p = base + off;
    off += (bytes + 255) & ~(size_t)255;
    return p;
  };
  float* qf            = (float*)alloc(Fq * 4);              // 32 MiB
  unsigned short* lncb = (unsigned short*)alloc(Fq * 2);     // 16 MiB
  unsigned short* lnqb = (unsigned short*)alloc(Fq * 2);     // 16 MiB
  unsigned short* obuf = (unsigned short*)alloc(Fq * 2);     // 16 MiB
  unsigned short* big1 = (unsigned short*)alloc(Fq * 8);     // 64 MiB (xbuf/ggate/abf/tokf alias)
  unsigned short* bbuf = (unsigned short*)alloc(Fq * 2);     // 16 MiB
  unsigned short* cbf  = (unsigned short*)alloc(Fq * 2);     // 16 MiB
  unsigned short* vtbuf= (unsigned short*)alloc(Fq * 2);     // 16 MiB V^T
  unsigned short* biasb= (unsigned short*)alloc((size_t)24 * 4096 * 128 * 2);  // 24 MiB
  unsigned short* wbf  = (unsigned short*)alloc((size_t)4718592 * 2);          // 9 MiB
  float* biasr         = (float*)alloc(8704 * 4);
  int* tokidx          = (int*)alloc(4096 * 4);

  unsigned short* xbuf  = big1;                     // R*512, lower half
  unsigned short* ggate = big1 + (size_t)R_ * 512;  // R*512, upper half (dead window)
  unsigned short* abf   = big1;                     // 8192*1536 (dead before layer 0)
  unsigned short* tokf  = big1 + 2 * Fq;            // 8192*256

  // ---- weight transpose-convert descriptors ----
  ConvArgs ca;
  int ne = 0;
  auto add = [&](const float* s, size_t doff, int K, int N) {
    ca.src[ne] = s; ca.doff[ne] = (int)doff; ca.Kd[ne] = K; ca.Nd[ne] = N; ne++;
  };
  constexpr size_t LW = 1441792;
  for (int i = 0; i < 3; i++) {
    size_t LB = (size_t)i * LW;
    add(ada1_sw + i * 65536, LB + 0, 256, 256);
    add(ada1_kw + i * 65536, LB + 65536, 256, 256);
    add(attn_wq + i * 65536, LB + 131072, 256, 256);
    add(attn_wk + i * 65536, LB + 196608, 256, 256);
    add(attn_wv + i * 65536, LB + 262144, 256, 256);
    add(attn_wg + i * 65536, LB + 327680, 256, 256);
    add(attn_wo + i * 65536, LB + 393216, 256, 256);
    add(og_w + i * 65536, LB + 458752, 256, 256);
    add(tr_gw + i * 65536, LB + 524288, 256, 256);
    add(ada2_sw + i * 65536, LB + 589824, 256, 256);
    add(ada2_kw + i * 65536, LB + 655360, 256, 256);
    add(tr_w1 + i * 131072, LB + 720896, 256, 512);
    add(tr_w2 + i * 131072, LB + 851968, 256, 512);
    add(tr_w3 + i * 131072, LB + 983040, 512, 256);
    add(t_wq + i * 65536, LB + 1114112, 256, 256);
    add(t_wk + i * 65536, LB + 1179648, 256, 256);
    add(t_wv + i * 65536, LB + 1245184, 256, 256);
    add(t_wg + i * 65536, LB + 1310720, 256, 256);
    add(t_wo + i * 65536, LB + 1376256, 256, 256);
  }
  add(W_a2q, 3 * LW, 1536, 256);
  ca.n = ne;

  conv_k<<<dim3(ne, 96), 256, 0, stream>>>(ca, wbf);
  bias_prep_k<<<1, 256, 0, stream>>>(attn_bq, ada1_sb, ada2_sb, og_b, tr_gb, biasr);
  tokidx_k<<<1024, 256, 0, stream>>>(a2t, tokidx);
  biasb_k<<<4096, 256, 0, stream>>>(adb, biasb);
  cvt_k<<<6144, 256, 0, stream>>>(a, abf, 1572864);
  cvt_k<<<4096, 256, 0, stream>>>(c_in, cbf, 1048576);
  gemm4_k<1536, 1, 128><<<dim3(64, 2), 256, 0, stream>>>(
      abf, wbf + 3 * LW, biasr, tokf, nullptr, nullptr, 256);
  qfinitln_k<<<8192, 256, 0, stream>>>(q_in, tokf, tokidx, qf, lnqb);
  ln_k<<<8192, 256, 0, stream>>>(c_in, lncb);

  for (int i = 0; i < 3; i++) {
    size_t LB = (size_t)i * LW;
    const float* b_attn = biasr + 1024 + (size_t)i * 2560;
    const float* b_ada1 = b_attn + 1024;
    const float* b_ada2 = b_attn + 1536;
    const float* b_ogtr = b_attn + 2048;

    // adaLN 1 (fused combine with lnqb) -> bbuf
    gemm4_k<256, 4, 256><<<dim3(256, 4), 256, 0, stream>>>(
        lncb, wbf + LB, b_ada1, bbuf, lnqb, nullptr, 256);
    // qkvg projections (v -> transposed vtbuf) + spatial attention
    gemm4_k<256, 6, 512><<<dim3(256, 8), 256, 0, stream>>>(
        bbuf, wbf + LB + 131072, b_attn, big1, nullptr, vtbuf, 1024);
    attn_k<<<2048, 256, 0, stream>>>(big1, vtbuf, biasb, obuf, i);
    // gates: [og | trg] = c @ [og_w | tr_gw] (pre-sigmoid), one dual dispatch
    gemm4_k<256, 1, 256><<<dim3(256, 4), 256, 0, stream>>>(
        cbf, wbf + LB + 458752, b_ogtr, ggate, nullptr, nullptr, 512);
    // qf += sigmoid(og)*(o@wo), fused LN -> lnqb
    gemmln_k<256, true><<<512, 512, 0, stream>>>(
        obuf, wbf + LB + 393216, qf, ggate, 0, lnqb, nullptr, nullptr);
    // adaLN 2 -> bbuf
    gemm4_k<256, 4, 256><<<dim3(256, 4), 256, 0, stream>>>(
        lncb, wbf + LB + 589824, b_ada2, bbuf, lnqb, nullptr, 256);
    // transition: xbuf = silu(t@w1)*(t@w2); qf += sig(trg)*(x@w3), LN(t_ln)
    gemm4_k<256, 5, 512><<<dim3(256, 8), 256, 0, stream>>>(
        bbuf, wbf + LB + 720896, biasr, xbuf, nullptr, nullptr, 512);
    gemmln_k<512, true><<<512, 512, 0, stream>>>(
        xbuf, wbf + LB + 983040, qf, ggate, 256, lnqb,
        t_ln_g + (size_t)i * 256, t_ln_b + (size_t)i * 256);
    // temporal attention
    gemm4_k<256, 1, 512><<<dim3(256, 8), 256, 0, stream>>>(
        lnqb, wbf + LB + 1114112, biasr, big1, nullptr, nullptr, 1024);
    tattn_k<<<1024, 256, 0, stream>>>(big1, ts, t_dec, obuf, i);
    gemmln_k<256, false><<<512, 512, 0, stream>>>(
        obuf, wbf + LB + 1376256, qf, nullptr, 0, lnqb, nullptr, nullptr);
  }
  final_k<<<8192, 256, 0, stream>>>(qf, pos_g, pos_b, pos_w, (float*)d_out);
}

// Round 7
// 1123.198 us; speedup vs baseline: 3.4853x; 1.0184x over previous
//
#include <hip/hip_runtime.h>
#include <cstddef>
#include <cstdint>

#define DEVI __device__ __forceinline__

typedef __attribute__((ext_vector_type(8))) __bf16 bf16x8;
typedef __attribute__((ext_vector_type(8))) unsigned short us8;
typedef __attribute__((ext_vector_type(4))) unsigned short us4;
typedef __attribute__((ext_vector_type(4))) float f32x4;

constexpr int B0_ = 1, T_ = 8, N_ = 1024, M_ = 4096, D_ = 256;
constexpr int BT_ = 8, NW_ = 128, WQ_ = 32, HK_ = 128, SIDE_ = 48;
constexpr int R_ = BT_ * M_;          // 32768 rows
constexpr size_t Fq = 8388608;        // R_*256 elements

DEVI unsigned short f2b(float f) {
  return __builtin_bit_cast(unsigned short, static_cast<__bf16>(f));
}
DEVI float b2f(unsigned short s) { return __uint_as_float(((unsigned)s) << 16); }
DEVI float sigm(float x) { return 1.0f / (1.0f + __expf(-x)); }
DEVI bf16x8 ld_bf8(const unsigned short* p) {
  return __builtin_bit_cast(bf16x8, *(const us8*)p);
}
DEVI bf16x8 pack_f8(float4 v0, float4 v1) {
  bf16x8 r;
  r[0] = (__bf16)v0.x; r[1] = (__bf16)v0.y; r[2] = (__bf16)v0.z; r[3] = (__bf16)v0.w;
  r[4] = (__bf16)v1.x; r[5] = (__bf16)v1.y; r[6] = (__bf16)v1.z; r[7] = (__bf16)v1.w;
  return r;
}
DEVI void mfma_bf16(f32x4& c, bf16x8 a, bf16x8 b) {
  c = __builtin_amdgcn_mfma_f32_16x16x32_bf16(a, b, c, 0, 0, 0);
}
// async global->LDS, 16B per lane; lds dest = wave-uniform base + lane*16
DEVI void gload16(const void* g, void* l) {
  __builtin_amdgcn_global_load_lds((__attribute__((address_space(1))) void*)g,
                                   (__attribute__((address_space(3))) void*)l, 16, 0, 0);
}

// ---------------- weight transpose-convert (fp32 [K][N] -> bf16 Wt[N][K]) ----
struct ConvArgs {
  const float* src[64];
  int doff[64];
  int Kd[64];
  int Nd[64];
  float scale[64];
  int n;
};

__global__ __launch_bounds__(256) void conv_k(ConvArgs ca, unsigned short* __restrict__ wbf) {
  int e = blockIdx.x;
  int K = ca.Kd[e], N = ca.Nd[e];
  int nx = N >> 6, nk = K >> 6;
  int t = blockIdx.y;
  if (t >= nx * nk) return;
  int tx = t % nx, tk = t / nx;
  const float* s = ca.src[e];
  float sc = ca.scale[e];
  unsigned short* d = wbf + ca.doff[e];
  int n = tx * 64 + (threadIdx.x & 63);
  int k0 = tk * 64 + (threadIdx.x >> 6) * 16;
  for (int r = 0; r < 16; r++) {
    int k = k0 + r;
    d[(size_t)n * K + k] = f2b(s[(size_t)k * N + n] * sc);
  }
}

// ---------------- fp32 -> bf16 flat convert ----------------
__global__ __launch_bounds__(256) void cvt_k(const float* __restrict__ s,
                                             unsigned short* __restrict__ d, int n8) {
  int i = blockIdx.x * 256 + threadIdx.x;
  if (i >= n8) return;
  float4 v0 = *(const float4*)(s + (size_t)i * 8);
  float4 v1 = *(const float4*)(s + (size_t)i * 8 + 4);
  *(us8*)(d + (size_t)i * 8) = __builtin_bit_cast(us8, pack_f8(v0, v1));
}

// ---------------- bias concat prep ----------------
__global__ __launch_bounds__(256) void bias_prep_k(
    const float* __restrict__ bq, const float* __restrict__ sb1,
    const float* __restrict__ sb2, const float* __restrict__ ogb,
    const float* __restrict__ trb, float* __restrict__ bias) {
  int t = threadIdx.x;
  const float inv_s = 0.17677669529663687f;
  for (int i = t; i < 1024 + 3 * 2560; i += 256) bias[i] = 0.f;
  __syncthreads();
  for (int i = 0; i < 3; i++) {
    float* B = bias + 1024 + i * 2560;
    B[t]        = bq[i * 256 + t] * inv_s;   // q pre-scaled
    B[1024 + t] = sb1[i * 256 + t];
    B[1536 + t] = sb2[i * 256 + t];
    B[2048 + t] = ogb[i * 256 + t];
    B[2304 + t] = trb[i * 256 + t];
  }
}

// ---- attn bias relayout -> biasb[(l*8+h)][row][lr(16)][ni(8)] bf16, mask baked
__global__ __launch_bounds__(256) void biasb_k(const float* __restrict__ adb,
                                               unsigned short* __restrict__ biasb) {
  __shared__ float ld[3072];
  int rq = blockIdx.x;  // 0..4095 (= w*32 + q)
  int t = threadIdx.x;
  const float* src = adb + (size_t)rq * 3072;
  for (int i = t; i < 3072; i += 256) ld[i] = src[i];
  __syncthreads();
  int k = t & 127;
  int pk = (k & 15) * 8 + (k >> 4);   // fragment-layout permutation
  int ak = (rq >> 5) * 32 - SIDE_ + k;
  float maskv = ((unsigned)ak < (unsigned)M_) ? 0.f : -1e9f;
  for (int lh = t >> 7; lh < 24; lh += 2)
    biasb[((size_t)lh * 4096 + rq) * 128 + pk] = f2b(ld[k * 24 + lh] + maskv);
}

// ---------------- tok idx from one-hot ----------------
__global__ __launch_bounds__(256) void tokidx_k(const float* __restrict__ a2t,
                                                int* __restrict__ idx) {
  int m = blockIdx.x * 4 + (threadIdx.x >> 6);
  int lane = threadIdx.x & 63;
  int best = -1;
  for (int j = 0; j < 16; j++) {
    int col = lane * 16 + j;
    if (a2t[(size_t)m * 1024 + col] > 0.5f) best = col;
  }
#pragma unroll
  for (int off = 1; off < 64; off <<= 1) best = max(best, __shfl_xor(best, off));
  if (lane == 0) idx[m] = best;
}

// ---------------- qf = q + tokfeat[gather], fused LN -> lnqb ----------------
__global__ __launch_bounds__(256) void qfinitln_k(const float* __restrict__ q,
                                                  const unsigned short* __restrict__ tokf,
                                                  const int* __restrict__ idx,
                                                  float* __restrict__ qf,
                                                  unsigned short* __restrict__ lnout) {
  int wid = threadIdx.x >> 6, lane = threadIdx.x & 63;
  size_t row = (size_t)blockIdx.x * 4 + wid;
  int m = (int)(row & 4095);
  int bt = (int)(row >> 12);
  float4 qv = *(const float4*)(q + row * 256 + lane * 4);
  us4 tv = *(const us4*)(tokf + ((size_t)bt * 1024 + idx[m]) * 256 + lane * 4);
  float x[4];
  x[0] = qv.x + b2f(tv[0]); x[1] = qv.y + b2f(tv[1]);
  x[2] = qv.z + b2f(tv[2]); x[3] = qv.w + b2f(tv[3]);
  *(float4*)(qf + row * 256 + lane * 4) = make_float4(x[0], x[1], x[2], x[3]);
  float s = x[0] + x[1] + x[2] + x[3];
  float sq = x[0] * x[0] + x[1] * x[1] + x[2] * x[2] + x[3] * x[3];
#pragma unroll
  for (int o = 1; o < 64; o <<= 1) {
    s += __shfl_xor(s, o);
    sq += __shfl_xor(sq, o);
  }
  float mu = s * 0.00390625f;
  float rs = rsqrtf(sq * 0.00390625f - mu * mu + 1e-5f);
  us4 r;
#pragma unroll
  for (int j = 0; j < 4; j++) r[j] = f2b((x[j] - mu) * rs);
  *(us4*)(lnout + row * 256 + lane * 4) = r;
}

// ---------------- rowwise LayerNorm over 256, fp32 in -> bf16 out ----------
__global__ __launch_bounds__(256) void ln_k(const float* __restrict__ src,
                                            unsigned short* __restrict__ dst) {
  size_t row = (size_t)blockIdx.x * 4 + (threadIdx.x >> 6);
  int lane = threadIdx.x & 63;
  float4 v = ((const float4*)(src + row * 256))[lane];
  float s = v.x + v.y + v.z + v.w;
#pragma unroll
  for (int o = 1; o < 64; o <<= 1) s += __shfl_xor(s, o);
  float mu = s * 0.00390625f;
  float dx = v.x - mu, dy = v.y - mu, dz = v.z - mu, dw = v.w - mu;
  float qv = dx * dx + dy * dy + dz * dz + dw * dw;
#pragma unroll
  for (int o = 1; o < 64; o <<= 1) qv += __shfl_xor(qv, o);
  float rs = rsqrtf(qv * 0.00390625f + 1e-5f);
  us4 r;
  r[0] = f2b(dx * rs); r[1] = f2b(dy * rs); r[2] = f2b(dz * rs); r[3] = f2b(dw * rs);
  *(us4*)(dst + row * 256 + lane * 4) = r;
}

// ---------------- pipelined dual GEMM: BM=128, BN=64(main)+64(pair) ----------
// EP1: store both halves; EP4: adaLN combine; EP5: SwiGLU combine
// EP6 (qkvg): main -> out; pair: n_base<256 -> TRANSPOSED store to vtb (v cols),
//             else normal store to out at +512 (g cols)
template <int K, int EP, int PAIR>
__global__ __launch_bounds__(256) void gemm4_k(
    const unsigned short* __restrict__ A, const unsigned short* __restrict__ Wt,
    const float* __restrict__ bias, unsigned short* __restrict__ out,
    const unsigned short* __restrict__ lnq, unsigned short* __restrict__ vtb,
    int NOUT) {
  constexpr int NT = K / 64;
  __shared__ __align__(16) unsigned short S[2][16384];  // per buf: A 8192 | B1 4096 | B2 4096
  const int tid = threadIdx.x;
  const int lane = tid & 63, w = tid >> 6;
  const int lg = lane >> 4, lr = lane & 15;
  const int wr = w >> 1, wc = w & 1;
  const size_t m_base = (size_t)blockIdx.x * 128;
  const size_t n_base = (size_t)blockIdx.y * 64;
  const int srow = w * 8 + (lane >> 3);
  const int scol = ((lane & 7) ^ (lane >> 3)) * 8;  // pre-swizzled global col
  const unsigned short* gA = A + (m_base + srow) * K + scol;
  const unsigned short* gB = Wt + (n_base + srow) * K + scol;
  const unsigned short* gB2 = Wt + (n_base + PAIR + srow) * K + scol;
  f32x4 acc[4][2] = {};
  f32x4 acc2[4][2] = {};
  const int swz = lr & 7;

  auto stage = [&](int buf, int t) {
    unsigned short* Sb = S[buf];
    const int kk = t * 64;
#pragma unroll
    for (int j = 0; j < 4; j++)
      gload16(gA + (size_t)(j * 32) * K + kk, Sb + w * 512 + j * 2048);
#pragma unroll
    for (int j = 0; j < 2; j++)
      gload16(gB + (size_t)(j * 32) * K + kk, Sb + 8192 + w * 512 + j * 2048);
#pragma unroll
    for (int j = 0; j < 2; j++)
      gload16(gB2 + (size_t)(j * 32) * K + kk, Sb + 12288 + w * 512 + j * 2048);
  };
  auto compute = [&](int buf) {
    const unsigned short* Sb = S[buf];
#pragma unroll
    for (int ks = 0; ks < 2; ks++) {
      const int co = ((ks * 4 + lg) ^ swz) << 3;
      bf16x8 af[4], b1[2], b2[2];
#pragma unroll
      for (int i = 0; i < 4; i++)
        af[i] = ld_bf8(Sb + (wr * 64 + i * 16 + lr) * 64 + co);
#pragma unroll
      for (int i = 0; i < 2; i++) {
        b1[i] = ld_bf8(Sb + 8192 + (wc * 32 + i * 16 + lr) * 64 + co);
        b2[i] = ld_bf8(Sb + 12288 + (wc * 32 + i * 16 + lr) * 64 + co);
      }
      __builtin_amdgcn_s_setprio(1);
#pragma unroll
      for (int mi = 0; mi < 4; mi++)
#pragma unroll
        for (int ni = 0; ni < 2; ni++) {
          mfma_bf16(acc[mi][ni], af[mi], b1[ni]);
          mfma_bf16(acc2[mi][ni], af[mi], b2[ni]);
        }
      __builtin_amdgcn_s_setprio(0);
    }
  };

  stage(0, 0);
  __syncthreads();
  int cur = 0;
  for (int t = 0; t < NT - 1; t++) {
    stage(cur ^ 1, t + 1);   // loads in flight under compute
    compute(cur);
    __syncthreads();         // drains vmcnt -> next buf ready; protects reuse
    cur ^= 1;
  }
  compute(cur);
  __syncthreads();

  unsigned short* St = S[0];
  auto emit_half = [&](int cbase, bool second) {
#pragma unroll
    for (int mi = 0; mi < 4; mi++)
#pragma unroll
      for (int ni = 0; ni < 2; ni++)
#pragma unroll
        for (int r = 0; r < 4; r++) {
          int rowl = wr * 64 + mi * 16 + lg * 4 + r;
          int cl = wc * 32 + ni * 16 + lr;
          float v = (second ? acc2[mi][ni][r] : acc[mi][ni][r]) + bias[cbase + cl];
          St[rowl * 64 + (((cl >> 3) ^ (rowl & 7)) << 3) + (cl & 7)] = f2b(v);
        }
    __syncthreads();
#pragma unroll
    for (int p = 0; p < 4; p++) {
      int rowl = p * 32 + (tid >> 3);
      int chunk = tid & 7;
      us8 v = *(const us8*)(St + rowl * 64 + ((chunk ^ (rowl & 7)) << 3));
      *(us8*)(out + (m_base + rowl) * NOUT + cbase + chunk * 8) = v;
    }
    __syncthreads();
  };

  if constexpr (EP == 1) {
    emit_half((int)n_base, false);
    emit_half((int)n_base + PAIR, true);
  } else if constexpr (EP == 6) {
    emit_half((int)n_base, false);
    if ((int)n_base < 256) {
      // v columns: transposed store into vtb[(bt*256 + hd)][atom]
      const int bt = (int)(m_base >> 12);
      const int m0 = (int)(m_base & 4095);
#pragma unroll
      for (int mi = 0; mi < 4; mi++)
#pragma unroll
        for (int ni = 0; ni < 2; ni++) {
          int cl = wc * 32 + ni * 16 + lr;
          int rowb = wr * 64 + mi * 16 + lg * 4;
          us4 val;
#pragma unroll
          for (int r = 0; r < 4; r++)
            val[r] = f2b(acc2[mi][ni][r] + bias[(int)n_base + cl + 512]);
          *(us4*)(St + cl * 128 + (((rowb >> 3) ^ (cl & 7)) << 3) + (rowb & 7)) = val;
        }
      __syncthreads();
#pragma unroll
      for (int p = 0; p < 4; p++) {
        int cl = tid >> 2;
        int rc = (tid & 3) + p * 4;
        us8 v = *(const us8*)(St + cl * 128 + ((rc ^ (cl & 7)) << 3));
        *(us8*)(vtb + ((size_t)bt * 256 + n_base + cl) * 4096 + m0 + rc * 8) = v;
      }
    } else {
      emit_half((int)n_base + 512, true);
    }
  } else {
#pragma unroll
    for (int mi = 0; mi < 4; mi++)
#pragma unroll
      for (int ni = 0; ni < 2; ni++)
#pragma unroll
        for (int r = 0; r < 4; r++) {
          int rowl = wr * 64 + mi * 16 + lg * 4 + r;
          int cl = wc * 32 + ni * 16 + lr;
          size_t grow = m_base + rowl;
          int gcol = (int)n_base + cl;
          float v = acc[mi][ni][r] + bias[gcol];
          float v2 = acc2[mi][ni][r] + bias[gcol + PAIR];
          unsigned short res;
          if constexpr (EP == 4) {
            res = f2b(sigm(v) * b2f(lnq[grow * 256 + gcol]) + v2);
          } else {  // EP5
            res = f2b(v * sigm(v) * v2);
          }
          St[rowl * 64 + (((cl >> 3) ^ (rowl & 7)) << 3) + (cl & 7)] = res;
        }
    __syncthreads();
#pragma unroll
    for (int p = 0; p < 4; p++) {
      int rowl = p * 32 + (tid >> 3);
      int chunk = tid & 7;
      us8 v = *(const us8*)(St + rowl * 64 + ((chunk ^ (rowl & 7)) << 3));
      *(us8*)(out + (m_base + rowl) * NOUT + n_base + chunk * 8) = v;
    }
  }
}

// ---------------- residual GEMM + fused LayerNorm (pipelined) ---------------
template <int K, bool GATED>
__global__ __launch_bounds__(512) void gemmln_k(
    const unsigned short* __restrict__ A, const unsigned short* __restrict__ Wt,
    float* __restrict__ qf, const unsigned short* __restrict__ gate, int goff,
    unsigned short* __restrict__ lnout, const float* __restrict__ lng,
    const float* __restrict__ lnb) {
  constexpr int NT = K / 64;
  __shared__ __align__(16) unsigned short S[2][20480];  // per buf: A 4096 | B 16384
  const int tid = threadIdx.x;
  const int lane = tid & 63, w = tid >> 6;  // 8 waves
  const int lg = lane >> 4, lr = lane & 15;
  const size_t m_base = (size_t)blockIdx.x * 64;
  const int srow = lane >> 3;
  const int scol = ((lane & 7) ^ srow) * 8;
  const unsigned short* gA = A + (m_base + w * 8 + srow) * K + scol;
  const unsigned short* gB = Wt + (w * 32 + srow) * K + scol;
  f32x4 acc[4][2] = {};
  const int swz = lr & 7;

  auto stage = [&](int buf, int t) {
    unsigned short* Sb = S[buf];
    const int kk = t * 64;
    gload16(gA + kk, Sb + w * 512);
#pragma unroll
    for (int j = 0; j < 4; j++)
      gload16(gB + (size_t)(j * 8) * K + kk, Sb + 4096 + w * 2048 + j * 512);
  };
  auto compute = [&](int buf) {
    const unsigned short* Sb = S[buf];
#pragma unroll
    for (int ks = 0; ks < 2; ks++) {
      const int co = ((ks * 4 + lg) ^ swz) << 3;
      bf16x8 af[4], bf1[2];
#pragma unroll
      for (int i = 0; i < 4; i++) af[i] = ld_bf8(Sb + (i * 16 + lr) * 64 + co);
#pragma unroll
      for (int i = 0; i < 2; i++)
        bf1[i] = ld_bf8(Sb + 4096 + (w * 32 + i * 16 + lr) * 64 + co);
      __builtin_amdgcn_s_setprio(1);
#pragma unroll
      for (int mi = 0; mi < 4; mi++)
#pragma unroll
        for (int ni = 0; ni < 2; ni++) mfma_bf16(acc[mi][ni], af[mi], bf1[ni]);
      __builtin_amdgcn_s_setprio(0);
    }
  };

  stage(0, 0);
  __syncthreads();
  int cur = 0;
  for (int t = 0; t < NT - 1; t++) {
    stage(cur ^ 1, t + 1);
    compute(cur);
    __syncthreads();
    cur ^= 1;
  }
  compute(cur);
  __syncthreads();

  unsigned short* St = S[0];
#pragma unroll
  for (int mi = 0; mi < 4; mi++)
#pragma unroll
    for (int ni = 0; ni < 2; ni++)
#pragma unroll
      for (int r = 0; r < 4; r++) {
        int rowl = mi * 16 + lg * 4 + r;
        int col = w * 32 + ni * 16 + lr;
        size_t grow = m_base + rowl;
        float v = acc[mi][ni][r];
        if constexpr (GATED) v *= sigm(b2f(gate[grow * 512 + goff + col]));
        float nq = qf[grow * 256 + col] + v;
        qf[grow * 256 + col] = nq;
        St[rowl * 256 + (((col >> 3) ^ (rowl & 7)) << 3) + (col & 7)] = f2b(nq);
      }
  __syncthreads();
  float gv[4], bv[4];
  if (lng) {
#pragma unroll
    for (int j = 0; j < 4; j++) {
      gv[j] = lng[lane * 4 + j];
      bv[j] = lnb[lane * 4 + j];
    }
  }
  const int rchunk = lane >> 1;
  const int rsub = (lane & 1) << 2;
  for (int rr = 0; rr < 8; rr++) {
    int rowl = w * 8 + rr;
    us4 vv = *(const us4*)(St + rowl * 256 + ((rchunk ^ (rowl & 7)) << 3) + rsub);
    float x[4];
#pragma unroll
    for (int j = 0; j < 4; j++) x[j] = b2f(vv[j]);
    float s = x[0] + x[1] + x[2] + x[3];
    float sq = x[0] * x[0] + x[1] * x[1] + x[2] * x[2] + x[3] * x[3];
#pragma unroll
    for (int o = 1; o < 64; o <<= 1) {
      s += __shfl_xor(s, o);
      sq += __shfl_xor(sq, o);
    }
    float mu = s * 0.00390625f;
    float rs = rsqrtf(sq * 0.00390625f - mu * mu + 1e-5f);
    us4 r;
#pragma unroll
    for (int j = 0; j < 4; j++) {
      float y = (x[j] - mu) * rs;
      if (lng) y = y * gv[j] + bv[j];
      r[j] = f2b(y);
    }
    *(us4*)(lnout + (m_base + rowl) * 256 + lane * 4) = r;
  }
}

// ---------------- windowed spatial attention (lean-VALU, 32KB LDS) ----------
__global__ __launch_bounds__(256) void attn_k(const unsigned short* __restrict__ big1,
                                              const unsigned short* __restrict__ vtbuf,
                                              const unsigned short* __restrict__ biasb,
                                              unsigned short* __restrict__ o, int layer) {
  __shared__ __align__(16) unsigned short pl_s[4][32 * 128];
  const int bid = blockIdx.x;
  const int nid = (bid & 7) * 256 + (bid >> 3);  // XCD-chunked remap
  const int w = nid & 127, bt = (nid >> 7) & 7, hg = nid >> 10;
  const int tid = threadIdx.x, wid = tid >> 6, lane = tid & 63;
  const int lg = lane >> 4, lr = lane & 15;
  const int h = hg * 4 + wid;
  unsigned short* pl = pl_s[wid];
  const size_t base = (size_t)bt * M_;

  // QK^T via MFMA (q pre-scaled by 1/sqrt(dh))
  bf16x8 aq[2];
#pragma unroll
  for (int mi = 0; mi < 2; mi++)
    aq[mi] = ld_bf8(big1 + (base + w * 32 + mi * 16 + lr) * 1024 + h * 32 + lg * 8);
  f32x4 lac[2][8] = {};
#pragma unroll
  for (int ni = 0; ni < 8; ni++) {
    int kidx = ni * 16 + lr;
    int ak = w * 32 - SIDE_ + kidx;
    int akc = ak < 0 ? 0 : (ak > M_ - 1 ? M_ - 1 : ak);
    bf16x8 bk = ld_bf8(big1 + (base + akc) * 1024 + 256 + h * 32 + lg * 8);
    __builtin_amdgcn_s_setprio(1);
    mfma_bf16(lac[0][ni], aq[0], bk);
    mfma_bf16(lac[1][ni], aq[1], bk);
    __builtin_amdgcn_s_setprio(0);
  }
  // bias (mask baked in) + softmax; P unnormalized -> swizzled LDS; 1/sum kept
  const unsigned short* bb0 =
      biasb + (((size_t)(layer * 8 + h)) * 4096 + w * 32) * 128 + lr * 8;
  float invs[2][4];
#pragma unroll
  for (int mi = 0; mi < 2; mi++)
#pragma unroll
    for (int r = 0; r < 4; r++) {
      int qrow = mi * 16 + lg * 4 + r;
      us8 bb = *(const us8*)(bb0 + (size_t)qrow * 128);
      float lv[8];
      float mx = -3e38f;
#pragma unroll
      for (int ni = 0; ni < 8; ni++) {
        float x = lac[mi][ni][r] + b2f(bb[ni]);
        lv[ni] = x;
        mx = fmaxf(mx, x);
      }
#pragma unroll
      for (int off = 1; off < 16; off <<= 1) mx = fmaxf(mx, __shfl_xor(mx, off));
      float sum = 0.f;
#pragma unroll
      for (int ni = 0; ni < 8; ni++) {
        float e = __expf(lv[ni] - mx);
        lv[ni] = e;
        sum += e;
      }
#pragma unroll
      for (int off = 1; off < 16; off <<= 1) sum += __shfl_xor(sum, off);
      invs[mi][r] = 1.f / sum;
      int sw = (qrow & 7) << 3;
#pragma unroll
      for (int ni = 0; ni < 8; ni++)
        pl[qrow * 128 + ((ni * 16 + lr) ^ sw)] = f2b(lv[ni]);
    }
  // PV via MFMA over 128 keys; V^T fragments direct from global (L2)
  const unsigned short* vrow0 = vtbuf + ((size_t)bt * 256 + h * 32 + lr) * 4096;
  const unsigned short* vrow1 = vrow0 + (size_t)16 * 4096;
  f32x4 oc[2][2] = {};
#pragma unroll
  for (int ks = 0; ks < 4; ks++) {
    int kcol = w * 32 - SIDE_ + ks * 32 + lg * 8;
    kcol = kcol < 0 ? 0 : (kcol > M_ - 8 ? M_ - 8 : kcol);  // P=0 masks OOB
    bf16x8 bv0 = ld_bf8(vrow0 + kcol);
    bf16x8 bv1 = ld_bf8(vrow1 + kcol);
    int kswz = (ks * 32 + lg * 8) ^ ((lr & 7) << 3);
    bf16x8 ap0 = ld_bf8(pl + lr * 128 + kswz);
    bf16x8 ap1 = ld_bf8(pl + (16 + lr) * 128 + kswz);
    __builtin_amdgcn_s_setprio(1);
    mfma_bf16(oc[0][0], ap0, bv0);
    mfma_bf16(oc[0][1], ap0, bv1);
    mfma_bf16(oc[1][0], ap1, bv0);
    mfma_bf16(oc[1][1], ap1, bv1);
    __builtin_amdgcn_s_setprio(0);
  }
#pragma unroll
  for (int mi = 0; mi < 2; mi++)
#pragma unroll
    for (int nd = 0; nd < 2; nd++)
#pragma unroll
      for (int r = 0; r < 4; r++) {
        int qrow = mi * 16 + lg * 4 + r;
        int d = nd * 16 + lr;
        size_t rowi = base + w * 32 + qrow;
        float gv = sigm(b2f(big1[rowi * 1024 + 768 + h * 32 + d]));
        o[rowi * 256 + h * 32 + d] = f2b(oc[mi][nd][r] * invs[mi][r] * gv);
      }
}

// ---------------- temporal attention (T=8 per atom) ----------------
__global__ __launch_bounds__(256) void tattn_k(const unsigned short* __restrict__ big1,
                                               const float* __restrict__ ts,
                                               const float* __restrict__ tdec,
                                               unsigned short* __restrict__ o, int layer) {
  __shared__ __align__(16) unsigned short lds[4][8 * 768];
  int wid = threadIdx.x >> 6, lane = threadIdx.x & 63;
  int m = blockIdx.x * 4 + wid;
  unsigned short* Lp = lds[wid];
  for (int it = 0; it < 12; it++) {
    int u = it * 64 + lane;
    int t = u / 96, pos = (u % 96) * 8;
    *(uint4*)(Lp + t * 768 + pos) =
        *(const uint4*)(big1 + ((size_t)(t * M_ + m)) * 1024 + pos);
  }
  __syncthreads();
  int th = lane >> 3, qt = lane & 7;
  float decay = log1pf(__expf(tdec[layer * 8 + th]));
  float tsq = ts[qt];
  const float inv_t = 0.17677669529663687f;
  float tqv[32];
#pragma unroll
  for (int d = 0; d < 32; d++) tqv[d] = b2f(Lp[qt * 768 + th * 32 + d]);
  float lv[8];
  float mx = -3e38f;
#pragma unroll
  for (int kt = 0; kt < 8; kt++) {
    float dot = 0.f;
#pragma unroll
    for (int d = 0; d < 32; d++) dot += tqv[d] * b2f(Lp[kt * 768 + 256 + th * 32 + d]);
    float x = dot * inv_t - decay * fabsf(tsq - ts[kt]);
    lv[kt] = x;
    mx = fmaxf(mx, x);
  }
  float s = 0.f;
#pragma unroll
  for (int kt = 0; kt < 8; kt++) {
    float e = __expf(lv[kt] - mx);
    lv[kt] = e;
    s += e;
  }
  float inv = 1.f / s;
  float tov[32];
#pragma unroll
  for (int d = 0; d < 32; d++) tov[d] = 0.f;
#pragma unroll
  for (int kt = 0; kt < 8; kt++) {
    float p = lv[kt] * inv;
#pragma unroll
    for (int d = 0; d < 32; d++) tov[d] += p * b2f(Lp[kt * 768 + 512 + th * 32 + d]);
  }
  size_t orow = (size_t)qt * M_ + m;
#pragma unroll
  for (int d = 0; d < 32; d++) {
    float tg = sigm(b2f(big1[orow * 1024 + 768 + th * 32 + d]));
    o[orow * 256 + th * 32 + d] = f2b(tov[d] * tg);
  }
}

// ---------------- final: out = LN(qf, pos_g, pos_b) @ pos_w ----------------
__global__ __launch_bounds__(256) void final_k(const float* __restrict__ qf,
                                               const float* __restrict__ pg,
                                               const float* __restrict__ pb,
                                               const float* __restrict__ pw,
                                               float* __restrict__ out) {
  size_t row = (size_t)blockIdx.x * 4 + (threadIdx.x >> 6);
  int lane = threadIdx.x & 63;
  float4 v = ((const float4*)(qf + row * 256))[lane];
  float s = v.x + v.y + v.z + v.w;
#pragma unroll
  for (int o = 1; o < 64; o <<= 1) s += __shfl_xor(s, o);
  float mu = s * 0.00390625f;
  float dx = v.x - mu, dy = v.y - mu, dz = v.z - mu, dw = v.w - mu;
  float qv = dx * dx + dy * dy + dz * dz + dw * dw;
#pragma unroll
  for (int o = 1; o < 64; o <<= 1) qv += __shfl_xor(qv, o);
  float rs = rsqrtf(qv * 0.00390625f + 1e-5f);
  int d = lane * 4;
  float xn[4];
  xn[0] = dx * rs * pg[d] + pb[d];
  xn[1] = dy * rs * pg[d + 1] + pb[d + 1];
  xn[2] = dz * rs * pg[d + 2] + pb[d + 2];
  xn[3] = dw * rs * pg[d + 3] + pb[d + 3];
  float p0 = 0.f, p1 = 0.f, p2 = 0.f;
#pragma unroll
  for (int dd = 0; dd < 4; dd++) {
    const float* wr = pw + (size_t)(d + dd) * 3;
    p0 += xn[dd] * wr[0];
    p1 += xn[dd] * wr[1];
    p2 += xn[dd] * wr[2];
  }
#pragma unroll
  for (int o = 1; o < 64; o <<= 1) {
    p0 += __shfl_xor(p0, o);
    p1 += __shfl_xor(p1, o);
    p2 += __shfl_xor(p2, o);
  }
  if (lane == 0) {
    out[row * 3 + 0] = p0;
    out[row * 3 + 1] = p1;
    out[row * 3 + 2] = p2;
  }
}

extern "C" void kernel_launch(void* const* d_in, const int* in_sizes, int n_in,
                              void* d_out, int out_size, void* d_ws, size_t ws_size,
                              hipStream_t stream) {
  const float* a       = (const float*)d_in[0];
  const float* q_in    = (const float*)d_in[1];
  const float* c_in    = (const float*)d_in[2];
  const float* adb     = (const float*)d_in[3];
  const float* a2t     = (const float*)d_in[4];
  const float* ts      = (const float*)d_in[6];
  const float* W_a2q   = (const float*)d_in[7];
  const float* ada1_sw = (const float*)d_in[8];
  const float* ada1_sb = (const float*)d_in[9];
  const float* ada1_kw = (const float*)d_in[10];
  const float* attn_wq = (const float*)d_in[11];
  const float* attn_bq = (const float*)d_in[12];
  const float* attn_wk = (const float*)d_in[13];
  const float* attn_wv = (const float*)d_in[14];
  const float* attn_wg = (const float*)d_in[15];
  const float* attn_wo = (const float*)d_in[16];
  const float* og_w    = (const float*)d_in[17];
  const float* og_b    = (const float*)d_in[18];
  const float* ada2_sw = (const float*)d_in[19];
  const float* ada2_sb = (const float*)d_in[20];
  const float* ada2_kw = (const float*)d_in[21];
  const float* tr_w1   = (const float*)d_in[22];
  const float* tr_w2   = (const float*)d_in[23];
  const float* tr_w3   = (const float*)d_in[24];
  const float* tr_gw   = (const float*)d_in[25];
  const float* tr_gb   = (const float*)d_in[26];
  const float* t_ln_g  = (const float*)d_in[27];
  const float* t_ln_b  = (const float*)d_in[28];
  const float* t_wq    = (const float*)d_in[29];
  const float* t_wk    = (const float*)d_in[30];
  const float* t_wv    = (const float*)d_in[31];
  const float* t_wg    = (const float*)d_in[32];
  const float* t_wo    = (const float*)d_in[33];
  const float* t_dec   = (const float*)d_in[34];
  const float* pos_g   = (const float*)d_in[35];
  const float* pos_b   = (const float*)d_in[36];
  const float* pos_w   = (const float*)d_in[37];

  // ---- workspace layout, ~225 MB ----
  char* base = (char*)d_ws;
  size_t off = 0;
  auto alloc = [&](size_t bytes) {
    void* p = base + off;
    off += (bytes + 255) & ~(size_t)255;
    return p;
  };
  float* qf            = (float*)alloc(Fq * 4);              // 32 MiB
  unsigned short* lncb = (unsigned short*)alloc(Fq * 2);     // 16 MiB
  unsigned short* lnqb = (unsigned short*)alloc(Fq * 2);     // 16 MiB
  unsigned short* obuf = (unsigned short*)alloc(Fq * 2);     // 16 MiB
  unsigned short* big1 = (unsigned short*)alloc(Fq * 8);     // 64 MiB (xbuf/ggate/abf/tokf alias)
  unsigned short* bbuf = (unsigned short*)alloc(Fq * 2);     // 16 MiB
  unsigned short* cbf  = (unsigned short*)alloc(Fq * 2);     // 16 MiB
  unsigned short* vtbuf= (unsigned short*)alloc(Fq * 2);     // 16 MiB V^T
  unsigned short* biasb= (unsigned short*)alloc((size_t)24 * 4096 * 128 * 2);  // 24 MiB
  unsigned short* wbf  = (unsigned short*)alloc((size_t)4718592 * 2);          // 9 MiB
  float* biasr         = (float*)alloc(8704 * 4);
  int* tokidx          = (int*)alloc(4096 * 4);

  unsigned short* xbuf  = big1;                     // R*512, lower half
  unsigned short* ggate = big1 + (size_t)R_ * 512;  // R*512, upper half (dead window)
  unsigned short* abf   = big1;                     // 8192*1536 (dead before layer 0)
  unsigned short* tokf  = big1 + 2 * Fq;            // 8192*256

  // ---- weight transpose-convert descriptors ----
  ConvArgs ca;
  int ne = 0;
  auto add = [&](const float* s, size_t doff, int K, int N, float sc) {
    ca.src[ne] = s; ca.doff[ne] = (int)doff; ca.Kd[ne] = K; ca.Nd[ne] = N;
    ca.scale[ne] = sc; ne++;
  };
  const float inv_s = 0.17677669529663687f;
  constexpr size_t LW = 1441792;
  for (int i = 0; i < 3; i++) {
    size_t LB = (size_t)i * LW;
    add(ada1_sw + i * 65536, LB + 0, 256, 256, 1.f);
    add(ada1_kw + i * 65536, LB + 65536, 256, 256, 1.f);
    add(attn_wq + i * 65536, LB + 131072, 256, 256, inv_s);   // q pre-scaled
    add(attn_wk + i * 65536, LB + 196608, 256, 256, 1.f);
    add(attn_wv + i * 65536, LB + 262144, 256, 256, 1.f);
    add(attn_wg + i * 65536, LB + 327680, 256, 256, 1.f);
    add(attn_wo + i * 65536, LB + 393216, 256, 256, 1.f);
    add(og_w + i * 65536, LB + 458752, 256, 256, 1.f);
    add(tr_gw + i * 65536, LB + 524288, 256, 256, 1.f);
    add(ada2_sw + i * 65536, LB + 589824, 256, 256, 1.f);
    add(ada2_kw + i * 65536, LB + 655360, 256, 256, 1.f);
    add(tr_w1 + i * 131072, LB + 720896, 256, 512, 1.f);
    add(tr_w2 + i * 131072, LB + 851968, 256, 512, 1.f);
    add(tr_w3 + i * 131072, LB + 983040, 512, 256, 1.f);
    add(t_wq + i * 65536, LB + 1114112, 256, 256, 1.f);
    add(t_wk + i * 65536, LB + 1179648, 256, 256, 1.f);
    add(t_wv + i * 65536, LB + 1245184, 256, 256, 1.f);
    add(t_wg + i * 65536, LB + 1310720, 256, 256, 1.f);
    add(t_wo + i * 65536, LB + 1376256, 256, 256, 1.f);
  }
  add(W_a2q, 3 * LW, 1536, 256, 1.f);
  ca.n = ne;

  conv_k<<<dim3(ne, 96), 256, 0, stream>>>(ca, wbf);
  bias_prep_k<<<1, 256, 0, stream>>>(attn_bq, ada1_sb, ada2_sb, og_b, tr_gb, biasr);
  tokidx_k<<<1024, 256, 0, stream>>>(a2t, tokidx);
  biasb_k<<<4096, 256, 0, stream>>>(adb, biasb);
  cvt_k<<<6144, 256, 0, stream>>>(a, abf, 1572864);
  cvt_k<<<4096, 256, 0, stream>>>(c_in, cbf, 1048576);
  gemm4_k<1536, 1, 128><<<dim3(64, 2), 256, 0, stream>>>(
      abf, wbf + 3 * LW, biasr, tokf, nullptr, nullptr, 256);
  qfinitln_k<<<8192, 256, 0, stream>>>(q_in, tokf, tokidx, qf, lnqb);
  ln_k<<<8192, 256, 0, stream>>>(c_in, lncb);

  for (int i = 0; i < 3; i++) {
    size_t LB = (size_t)i * LW;
    const float* b_attn = biasr + 1024 + (size_t)i * 2560;
    const float* b_ada1 = b_attn + 1024;
    const float* b_ada2 = b_attn + 1536;
    const float* b_ogtr = b_attn + 2048;

    // adaLN 1 (fused combine with lnqb) -> bbuf
    gemm4_k<256, 4, 256><<<dim3(256, 4), 256, 0, stream>>>(
        lncb, wbf + LB, b_ada1, bbuf, lnqb, nullptr, 256);
    // qkvg projections (v -> transposed vtbuf) + spatial attention
    gemm4_k<256, 6, 512><<<dim3(256, 8), 256, 0, stream>>>(
        bbuf, wbf + LB + 131072, b_attn, big1, nullptr, vtbuf, 1024);
    attn_k<<<2048, 256, 0, stream>>>(big1, vtbuf, biasb, obuf, i);
    // gates: [og | trg] = c @ [og_w | tr_gw] (pre-sigmoid), one dual dispatch
    gemm4_k<256, 1, 256><<<dim3(256, 4), 256, 0, stream>>>(
        cbf, wbf + LB + 458752, b_ogtr, ggate, nullptr, nullptr, 512);
    // qf += sigmoid(og)*(o@wo), fused LN -> lnqb
    gemmln_k<256, true><<<512, 512, 0, stream>>>(
        obuf, wbf + LB + 393216, qf, ggate, 0, lnqb, nullptr, nullptr);
    // adaLN 2 -> bbuf
    gemm4_k<256, 4, 256><<<dim3(256, 4), 256, 0, stream>>>(
        lncb, wbf + LB + 589824, b_ada2, bbuf, lnqb, nullptr, 256);
    // transition: xbuf = silu(t@w1)*(t@w2); qf += sig(trg)*(x@w3), LN(t_ln)
    gemm4_k<256, 5, 512><<<dim3(256, 8), 256, 0, stream>>>(
        bbuf, wbf + LB + 720896, biasr, xbuf, nullptr, nullptr, 512);
    gemmln_k<512, true><<<512, 512, 0, stream>>>(
        xbuf, wbf + LB + 983040, qf, ggate, 256, lnqb,
        t_ln_g + (size_t)i * 256, t_ln_b + (size_t)i * 256);
    // temporal attention
    gemm4_k<256, 1, 512><<<dim3(256, 8), 256, 0, stream>>>(
        lnqb, wbf + LB + 1114112, biasr, big1, nullptr, nullptr, 1024);
    tattn_k<<<1024, 256, 0, stream>>>(big1, ts, t_dec, obuf, i);
    gemmln_k<256, false><<<512, 512, 0, stream>>>(
        obuf, wbf + LB + 1376256, qf, nullptr, 0, lnqb, nullptr, nullptr);
  }
  final_k<<<8192, 256, 0, stream>>>(qf, pos_g, pos_b, pos_w, (float*)d_out);
}